// Round 5
// baseline (1817.101 us; speedup 1.0000x reference)
//
#include <hip/hip_runtime.h>
#include <hip/hip_fp16.h>

typedef _Float16 f16x8 __attribute__((ext_vector_type(8)));
typedef float f32x4 __attribute__((ext_vector_type(4)));
typedef unsigned char uchar;

// ---------------------------------------------------------------------------
// Pool: mean over spatial (S2 elements) per (b, ch)
// ---------------------------------------------------------------------------
template <int S2>
__global__ __launch_bounds__(256) void pool_kernel(const float* __restrict__ feat,
                                                   float* __restrict__ pooled, int total)
{
    int idx = blockIdx.x * 256 + threadIdx.x;
    if (idx >= total) return;
    const float4* p4 = (const float4*)(feat + (size_t)idx * S2);
    float s = 0.f;
#pragma unroll
    for (int i = 0; i < S2 / 4; ++i) {
        float4 v = p4[i];
        s += v.x + v.y + v.z + v.w;
    }
    pooled[idx] = s * (1.0f / S2);
}

// ---------------------------------------------------------------------------
// LS: emb = relu(pooled @ w + b), row-normalize -> fp16 N16 [4096,128]
// ---------------------------------------------------------------------------
__global__ __launch_bounds__(128) void ls_norm_kernel(const float* __restrict__ pooled,
                                                      const float* __restrict__ w,
                                                      const float* __restrict__ bias,
                                                      __half* __restrict__ n16, int K)
{
    __shared__ float pl[512];
    __shared__ float red2[2];
    const int b = blockIdx.x, t = threadIdx.x;
    for (int k = t; k < K; k += 128) pl[k] = pooled[(size_t)b * K + k];
    __syncthreads();
    float acc = bias[t];
    for (int k = 0; k < K; ++k) acc = fmaf(pl[k], w[(size_t)k * 128 + t], acc);
    float v = fmaxf(acc, 0.f);
    float ss = v * v;
    for (int off = 32; off > 0; off >>= 1) ss += __shfl_down(ss, off, 64);
    if ((t & 63) == 0) red2[t >> 6] = ss;
    __syncthreads();
    float inv = 1.0f / fmaxf(sqrtf(red2[0] + red2[1]), 1e-12f);
    n16[(size_t)b * 128 + t] = __float2half(v * inv);
}

// ---------------------------------------------------------------------------
// Normalize embedds rows (d=512) -> fp16 N16 [4096,512]
// ---------------------------------------------------------------------------
__global__ __launch_bounds__(256) void norm512_kernel(const float* __restrict__ E,
                                                      __half* __restrict__ n16)
{
    __shared__ float red4[4];
    const int b = blockIdx.x, t = threadIdx.x;
    float2 v = *(const float2*)(E + (size_t)b * 512 + t * 2);
    float ss = v.x * v.x + v.y * v.y;
    for (int off = 32; off > 0; off >>= 1) ss += __shfl_down(ss, off, 64);
    if ((t & 63) == 0) red4[t >> 6] = ss;
    __syncthreads();
    float inv = 1.0f / fmaxf(sqrtf(red4[0] + red4[1] + red4[2] + red4[3]), 1e-12f);
    __half2 o;
    o.x = __float2half(v.x * inv);
    o.y = __float2half(v.y * inv);
    *(__half2*)(n16 + (size_t)b * 512 + t * 2) = o;
}

// ---------------------------------------------------------------------------
// MFMA GEMM: A16 = fp16(clamp(N16 N16^T, 0, 1), diag=0), COALESCED via LDS
// transpose; fp32 block partial sums. 128x128 tile, 4 waves 2x2.
// ---------------------------------------------------------------------------
__global__ __launch_bounds__(256) void a_gemm_mfma(const __half* __restrict__ N16,
                                                   __half* __restrict__ A16,
                                                   float* __restrict__ partials, int K)
{
    __shared__ __half Cst[128 * 136];
    __shared__ float reds[4];
    const int t = threadIdx.x;
    const int lane = t & 63, wave = t >> 6;
    const int bx = blockIdx.x & 31, by = blockIdx.x >> 5;
    const int wr = wave >> 1, wc = wave & 1;
    const int r0 = by * 128 + wr * 64;
    const int c0 = bx * 128 + wc * 64;
    const int fr = lane & 15;
    const int fk = (lane >> 4) * 8;

    f32x4 acc[4][4];
#pragma unroll
    for (int i = 0; i < 4; ++i)
#pragma unroll
        for (int j = 0; j < 4; ++j) acc[i][j] = (f32x4){0.f, 0.f, 0.f, 0.f};

    const int nsteps = K >> 5;
    for (int s = 0; s < nsteps; ++s) {
        const int k = s * 32 + fk;
        f16x8 af[4], bf[4];
#pragma unroll
        for (int i = 0; i < 4; ++i) {
            af[i] = *(const f16x8*)(N16 + (size_t)(r0 + i * 16 + fr) * K + k);
            bf[i] = *(const f16x8*)(N16 + (size_t)(c0 + i * 16 + fr) * K + k);
        }
#pragma unroll
        for (int i = 0; i < 4; ++i)
#pragma unroll
            for (int j = 0; j < 4; ++j)
                acc[i][j] = __builtin_amdgcn_mfma_f32_16x16x32_f16(af[i], bf[j], acc[i][j], 0, 0, 0);
    }

    // epilogue: clamp, zero diag, stage fp16 into LDS (local [128][136])
    float lsum = 0.f;
    const int r4 = (lane >> 4) * 4;
#pragma unroll
    for (int i = 0; i < 4; ++i) {
#pragma unroll
        for (int q = 0; q < 4; ++q) {
            const int row = r0 + i * 16 + r4 + q;
#pragma unroll
            for (int j = 0; j < 4; ++j) {
                const int col = c0 + j * 16 + fr;
                float v = acc[i][j][q];
                v = fminf(fmaxf(v, 0.f), 1.f);
                if (row == col) v = 0.f;
                lsum += v;
                const int lr = wr * 64 + i * 16 + r4 + q;
                const int lc = wc * 64 + j * 16 + fr;
                Cst[lr * 136 + lc] = __float2half(v);
            }
        }
    }
    __syncthreads();

    // coalesced store: each thread 8 halves (16B) per pass, 8 passes
    {
        const int lr0 = t >> 4;
        const int lc = (t & 15) * 8;
#pragma unroll
        for (int pass = 0; pass < 8; ++pass) {
            const int lr = pass * 16 + lr0;
            uint4 v = *(const uint4*)&Cst[lr * 136 + lc];
            *(uint4*)(A16 + (size_t)(by * 128 + lr) * 4096 + bx * 128 + lc) = v;
        }
    }

    for (int off = 32; off > 0; off >>= 1) lsum += __shfl_down(lsum, off, 64);
    if (lane == 0) reds[wave] = lsum;
    __syncthreads();
    if (t == 0) partials[blockIdx.x] = reds[0] + reds[1] + reds[2] + reds[3];
}

// ---------------------------------------------------------------------------
// mean of A from per-block partials
// ---------------------------------------------------------------------------
__global__ __launch_bounds__(256) void mean_kernel(const float* __restrict__ partials,
                                                   float* __restrict__ scal)
{
    __shared__ float red[4];
    const int t = threadIdx.x;
    float s = 0.f;
    for (int i = t; i < 1024; i += 256) s += partials[i];
    for (int off = 32; off > 0; off >>= 1) s += __shfl_down(s, off, 64);
    if ((t & 63) == 0) red[t >> 6] = s;
    __syncthreads();
    if (t == 0) scal[0] = (red[0] + red[1] + red[2] + red[3]) * (1.0f / 16777216.0f);
}

// ---------------------------------------------------------------------------
// A8' = fp8_e4m3( a >= mean ? a : 0 )   (fp16 raw in, fp8 out)
// Decomposition: Abar = 1 - A8', so Y = colsum(X) - A8'@X.
// ---------------------------------------------------------------------------
__global__ __launch_bounds__(256) void abar8_kernel(const __half* __restrict__ raw,
                                                    uchar* __restrict__ a8,
                                                    const float* __restrict__ scal)
{
    const float mean = scal[0];
    const size_t i = ((size_t)blockIdx.x * 256 + threadIdx.x) * 8;
    uint4 u = *(const uint4*)(raw + i);
    __half hin[8]; *(uint4*)hin = u;
    float v[8];
#pragma unroll
    for (int k = 0; k < 8; ++k) {
        float a = __half2float(hin[k]);
        v[k] = (a < mean) ? 0.f : a;
    }
    unsigned lo = __builtin_amdgcn_cvt_pk_fp8_f32(v[0], v[1], 0, false);
    lo = __builtin_amdgcn_cvt_pk_fp8_f32(v[2], v[3], (int)lo, true);
    unsigned hi = __builtin_amdgcn_cvt_pk_fp8_f32(v[4], v[5], 0, false);
    hi = __builtin_amdgcn_cvt_pk_fp8_f32(v[6], v[7], (int)hi, true);
    uint2 o; o.x = lo; o.y = hi;
    *(uint2*)(a8 + i) = o;
}

// ---------------------------------------------------------------------------
// Scol[0][p][c] = #{labels[0..2047]==c} + 204.8 ; (Scol[1..30] pre-zeroed)
// ---------------------------------------------------------------------------
__global__ __launch_bounds__(256) void scol0_kernel(const int* __restrict__ labels,
                                                    float* __restrict__ Scol)
{
    __shared__ int hist[16];
    const int t = threadIdx.x;
    if (t < 16) hist[t] = 0;
    __syncthreads();
    for (int i = t; i < 2048; i += 256) atomicAdd(&hist[labels[i]], 1);
    __syncthreads();
    if (t < 80) {
        const int p = t >> 4, c = t & 15;
        Scol[p * 16 + c] = (c < 10) ? ((float)hist[c] + 204.8f) : 0.f;
    }
}

// ---------------------------------------------------------------------------
// X0 init: X32 buf0 (fp32 [p][4096][10]), Xt8 buf0 (fp8 [p][16][4096]),
// pad classes of buf1 zeroed.
// ---------------------------------------------------------------------------
__global__ __launch_bounds__(256) void init_kernel(const int* __restrict__ labels,
                                                   uchar* __restrict__ Xt8_0,
                                                   uchar* __restrict__ Xt8_1,
                                                   float* __restrict__ X32)
{
    const int idx = blockIdx.x * 256 + threadIdx.x;   // 5*16*4096 = 327680
    const int p = idx >> 16;
    const int rem = idx & 65535;
    const int c = rem >> 12, row = rem & 4095;
    float v;
    if (c >= 10) v = 0.f;
    else if (row < 2048) v = (labels[row] == c) ? 1.0f : 0.0f;
    else v = 0.1f;
    unsigned pk = __builtin_amdgcn_cvt_pk_fp8_f32(v, v, 0, false);
    Xt8_0[idx] = (uchar)(pk & 0xff);
    if (c >= 10) Xt8_1[idx] = 0;
    if (c < 10) X32[((size_t)p * 4096 + row) * 10 + c] = v;
}

// ---------------------------------------------------------------------------
// One GTG iteration via fp8 MFMA. Block: 256 threads (4 waves), 16 rows of
// one problem; wave w covers k-quarter. T = A8'@X8; Y = Scol[it] - T.
// Epilogue: replicator update, Scol[it+1] accumulation (block atomicAdd).
// p<4: Xs trajectory; p==4: entropy.
// ---------------------------------------------------------------------------
__global__ __launch_bounds__(256) void gtg8_kernel(
    const uchar* __restrict__ A8,
    const uchar* __restrict__ X8i, uchar* __restrict__ X8o,
    const float* __restrict__ X32i, float* __restrict__ X32o,
    float* __restrict__ Xs, float* __restrict__ ytacc,
    float* __restrict__ Scol, int it, int pbase)
{
    __shared__ float yred[4][256];
    const int t = threadIdx.x;
    const int lane = t & 63, wave = t >> 6;
    const int p = pbase + (blockIdx.x >> 8);
    const int pl = p - pbase;
    const int row0 = (blockIdx.x & 255) * 16;
    const int fr = lane & 15;
    const int g = lane >> 4;

    const uchar* Ab = A8 + (size_t)pl * 16777216 + (size_t)(row0 + fr) * 4096;
    const uchar* Xb = X8i + (size_t)p * 65536 + (size_t)fr * 4096;

    f32x4 acc0 = {0.f, 0.f, 0.f, 0.f};
    f32x4 acc1 = {0.f, 0.f, 0.f, 0.f};
    const int k0 = wave * 1024 + g * 8;
#pragma unroll 8
    for (int s = 0; s < 16; ++s) {
        const int ka = k0 + s * 64;
        const int kb = ka + 32;
        long long a0 = __builtin_bit_cast(long long, *(const uint2*)(Ab + ka));
        long long b0 = __builtin_bit_cast(long long, *(const uint2*)(Xb + ka));
        long long a1 = __builtin_bit_cast(long long, *(const uint2*)(Ab + kb));
        long long b1 = __builtin_bit_cast(long long, *(const uint2*)(Xb + kb));
        acc0 = __builtin_amdgcn_mfma_f32_16x16x32_fp8_fp8(a0, b0, acc0, 0, 0, 0);
        acc1 = __builtin_amdgcn_mfma_f32_16x16x32_fp8_fp8(a1, b1, acc1, 0, 0, 0);
    }
    {
        const int r4 = g * 4;
#pragma unroll
        for (int q = 0; q < 4; ++q)
            yred[wave][(r4 + q) * 16 + fr] = acc0[q] + acc1[q];
    }
    __syncthreads();

    // update phase: thread t -> row r=t>>4, class c=t&15
    const int r = t >> 4, c = t & 15;
    const int row = row0 + r;
    const float T = yred[0][t] + yred[1][t] + yred[2][t] + yred[3][t];
    const float y = Scol[it * 80 + p * 16 + c] - T;
    const float x = (c < 10) ? X32i[((size_t)p * 4096 + row) * 10 + c] : 0.f;
    const float m = x * y;
    float s = m;
    s += __shfl_xor(s, 1, 16);
    s += __shfl_xor(s, 2, 16);
    s += __shfl_xor(s, 4, 16);
    s += __shfl_xor(s, 8, 16);
    const float dv = m / (s + 1e-8f);
    const float xn = x + dv;
    if (c < 10) {
        X32o[((size_t)p * 4096 + row) * 10 + c] = xn;
        unsigned pk = __builtin_amdgcn_cvt_pk_fp8_f32(xn, xn, 0, false);
        X8o[(size_t)p * 65536 + c * 4096 + row] = (uchar)(pk & 0xff);
        if (p < 4) Xs[((size_t)p * 4096 + row) * 300 + c * 30 + it] = xn;
    }
    if (p == 4) {
        float e = (c < 10) ? (-dv * logf(dv + 1e-8f)) : 0.f;
        e += __shfl_xor(e, 1, 16);
        e += __shfl_xor(e, 2, 16);
        e += __shfl_xor(e, 4, 16);
        e += __shfl_xor(e, 8, 16);
        if (c == 0) {
            float prev = (it == 0) ? 0.f : ytacc[row];
            ytacc[row] = prev + e;
        }
    }

    // accumulate colsum for next iteration
    __syncthreads();
    yred[0][t] = (c < 10) ? xn : 0.f;
    __syncthreads();
    if (t < 10) {
        float sc = 0.f;
#pragma unroll
        for (int rr = 0; rr < 16; ++rr) sc += yred[0][t + rr * 16];
        atomicAdd(&Scol[(it + 1) * 80 + p * 16 + t], sc);
    }
}

// ---------------------------------------------------------------------------
// MLP layers 1+2 for one level
// ---------------------------------------------------------------------------
__global__ __launch_bounds__(256) void mlp12_kernel(const float* __restrict__ Xs,
                                                    const float* __restrict__ w1,
                                                    const float* __restrict__ b1,
                                                    const float* __restrict__ w2,
                                                    const float* __restrict__ b2,
                                                    float* __restrict__ H2, int lvl)
{
    __shared__ float xsh[8][300];
    __shared__ float h1[8][152];
    const int t = threadIdx.x;
    const size_t r0 = (size_t)blockIdx.x * 8;
    for (int i = t; i < 2400; i += 256) xsh[i / 300][i % 300] = Xs[r0 * 300 + i];
    __syncthreads();
    if (t < 150) {
        float acc[8];
#pragma unroll
        for (int r = 0; r < 8; ++r) acc[r] = b1[t];
        for (int k = 0; k < 300; ++k) {
            float wv = w1[(size_t)k * 150 + t];
#pragma unroll
            for (int r = 0; r < 8; ++r) acc[r] = fmaf(xsh[r][k], wv, acc[r]);
        }
#pragma unroll
        for (int r = 0; r < 8; ++r) h1[r][t] = fmaxf(acc[r], 0.f);
    }
    __syncthreads();
    if (t < 75) {
        float acc[8];
#pragma unroll
        for (int r = 0; r < 8; ++r) acc[r] = b2[t];
        for (int k = 0; k < 150; ++k) {
            float wv = w2[(size_t)k * 75 + t];
#pragma unroll
            for (int r = 0; r < 8; ++r) acc[r] = fmaf(h1[r][k], wv, acc[r]);
        }
#pragma unroll
        for (int r = 0; r < 8; ++r) H2[(r0 + r) * 300 + lvl * 75 + t] = fmaxf(acc[r], 0.f);
    }
}

// ---------------------------------------------------------------------------
// Final: y_pred = H2 @ w3 + b3; y_true = ytacc/30; labelled_mask
// ---------------------------------------------------------------------------
__global__ __launch_bounds__(256) void final_kernel(const float* __restrict__ H2,
                                                    const float* __restrict__ w3,
                                                    const float* __restrict__ b3,
                                                    const float* __restrict__ ytacc,
                                                    float* __restrict__ out)
{
    __shared__ float w[300];
    const int t = threadIdx.x;
    const int b = blockIdx.x * 256 + t;
    for (int i = t; i < 300; i += 256) w[i] = w3[i];
    __syncthreads();
    float acc = b3[0];
    const float4* row = (const float4*)(H2 + (size_t)b * 300);
    for (int k4 = 0; k4 < 75; ++k4) {
        float4 v = row[k4];
        acc += v.x * w[k4 * 4] + v.y * w[k4 * 4 + 1] + v.z * w[k4 * 4 + 2] + v.w * w[k4 * 4 + 3];
    }
    out[b] = acc;
    out[4096 + b] = ytacc[b] * (1.0f / 30.0f);
    out[2 * 4096 + b] = (b < 2048) ? 1.0f : 0.0f;
}

// ---------------------------------------------------------------------------
extern "C" void kernel_launch(void* const* d_in, const int* in_sizes, int n_in,
                              void* d_out, int out_size, void* d_ws, size_t ws_size,
                              hipStream_t stream)
{
    (void)in_sizes; (void)n_in; (void)out_size;

    const float* feats[4] = {(const float*)d_in[0], (const float*)d_in[1],
                             (const float*)d_in[2], (const float*)d_in[3]};
    const float* embedds = (const float*)d_in[4];
    const int* labels = (const int*)d_in[6];
    const float* lsw[4] = {(const float*)d_in[7], (const float*)d_in[9],
                           (const float*)d_in[11], (const float*)d_in[13]};
    const float* lsb[4] = {(const float*)d_in[8], (const float*)d_in[10],
                           (const float*)d_in[12], (const float*)d_in[14]};
    const float* w1 = (const float*)d_in[15];
    const float* b1 = (const float*)d_in[16];
    const float* w2 = (const float*)d_in[17];
    const float* b2 = (const float*)d_in[18];
    const float* w3 = (const float*)d_in[19];
    const float* b3 = (const float*)d_in[20];

    // fused path: 5 fp8 A' matrices resident (5*16MB); else 1 reused
    const bool fused = ws_size >= 156930304ULL;
    const size_t A8_BYTES = fused ? 83886080ULL : 16777216ULL;

    char* ws = (char*)d_ws;
    uchar* A8       = (uchar*)(ws);
    __half* A16     = (__half*)(ws + A8_BYTES);       // 33554432 (raw, reused)
    char* base      = ws + A8_BYTES + 33554432;
    float* pooled   = (float*)(base);                 //  8388608
    __half* N16     = (__half*)(base + 8388608);      //  4194304
    uchar* Xt8      = (uchar*)(base + 12582912);      //  2 x 327680
    float* X32      = (float*)(base + 13238272);      //  2 x 819200
    float* Xs       = (float*)(base + 14876672);      //  19660800 (4 problems)
    float* H2       = (float*)(base + 34537472);      //  4915200
    float* ytacc    = (float*)(base + 39452672);      //  16384
    float* partials = (float*)(base + 39469056);      //  4096
    float* scal     = (float*)(base + 39473152);      //  256
    float* Scol     = (float*)(base + 39473408);      //  16384 (31 x 5 x 16 fp32)

    uchar* Xt8b[2] = {Xt8, Xt8 + 327680};
    float* X32b[2] = {X32, X32 + 204800};
    float* out = (float*)d_out;

    const int Cs[4] = {64, 128, 256, 512};
    const int S2s[4] = {64, 64, 16, 16};

    auto run_iters = [&](const uchar* Ab8, int pbase, int nprob) {
        hipMemsetAsync(Scol, 0, 31 * 80 * sizeof(float), stream);
        scol0_kernel<<<1, 256, 0, stream>>>(labels, Scol);
        init_kernel<<<1280, 256, 0, stream>>>(labels, Xt8b[0], Xt8b[1], X32b[0]);
        for (int it = 0; it < 30; ++it) {
            const int i = it & 1, o = i ^ 1;
            gtg8_kernel<<<nprob * 256, 256, 0, stream>>>(
                Ab8, Xt8b[i], Xt8b[o], X32b[i], X32b[o], Xs, ytacc, Scol, it, pbase);
        }
    };

    for (int lvl = 0; lvl < 4; ++lvl) {
        const int c = Cs[lvl];
        const int total = 4096 * c;
        if (S2s[lvl] == 64)
            pool_kernel<64><<<total / 256, 256, 0, stream>>>(feats[lvl], pooled, total);
        else
            pool_kernel<16><<<total / 256, 256, 0, stream>>>(feats[lvl], pooled, total);
        ls_norm_kernel<<<4096, 128, 0, stream>>>(pooled, lsw[lvl], lsb[lvl], N16, c);
        a_gemm_mfma<<<1024, 256, 0, stream>>>(N16, A16, partials, 128);
        mean_kernel<<<1, 256, 0, stream>>>(partials, scal);
        uchar* Ab8 = A8 + (fused ? (size_t)lvl * 16777216 : 0);
        abar8_kernel<<<8192, 256, 0, stream>>>(A16, Ab8, scal);
        if (!fused) {
            run_iters(Ab8, lvl, 1);
            mlp12_kernel<<<512, 256, 0, stream>>>(Xs + (size_t)lvl * 1228800,
                                                  w1, b1, w2, b2, H2, lvl);
        }
    }

    // embeddings branch
    norm512_kernel<<<4096, 256, 0, stream>>>(embedds, N16);
    {
        a_gemm_mfma<<<1024, 256, 0, stream>>>(N16, A16, partials, 512);
        mean_kernel<<<1, 256, 0, stream>>>(partials, scal);
        uchar* Ab8 = A8 + (fused ? (size_t)4 * 16777216 : 0);
        abar8_kernel<<<8192, 256, 0, stream>>>(A16, Ab8, scal);
        if (!fused) run_iters(Ab8, 4, 1);
    }

    if (fused) {
        run_iters(A8, 0, 5);
        for (int lvl = 0; lvl < 4; ++lvl)
            mlp12_kernel<<<512, 256, 0, stream>>>(Xs + (size_t)lvl * 1228800,
                                                  w1, b1, w2, b2, H2, lvl);
    }

    final_kernel<<<16, 256, 0, stream>>>(H2, w3, b3, ytacc, out);
}

// Round 6
// 1551.587 us; speedup vs baseline: 1.1711x; 1.1711x over previous
//
#include <hip/hip_runtime.h>
#include <hip/hip_fp16.h>

typedef _Float16 f16x8 __attribute__((ext_vector_type(8)));
typedef float f32x4 __attribute__((ext_vector_type(4)));
typedef unsigned char uchar;

// ---------------------------------------------------------------------------
// Pool: mean over spatial (S2 elements) per (b, ch)
// ---------------------------------------------------------------------------
template <int S2>
__global__ __launch_bounds__(256) void pool_kernel(const float* __restrict__ feat,
                                                   float* __restrict__ pooled, int total)
{
    int idx = blockIdx.x * 256 + threadIdx.x;
    if (idx >= total) return;
    const float4* p4 = (const float4*)(feat + (size_t)idx * S2);
    float s = 0.f;
#pragma unroll
    for (int i = 0; i < S2 / 4; ++i) {
        float4 v = p4[i];
        s += v.x + v.y + v.z + v.w;
    }
    pooled[idx] = s * (1.0f / S2);
}

// ---------------------------------------------------------------------------
// LS: emb = relu(pooled @ w + b), row-normalize -> fp16 N16 [4096,128]
// ---------------------------------------------------------------------------
__global__ __launch_bounds__(128) void ls_norm_kernel(const float* __restrict__ pooled,
                                                      const float* __restrict__ w,
                                                      const float* __restrict__ bias,
                                                      __half* __restrict__ n16, int K)
{
    __shared__ float pl[512];
    __shared__ float red2[2];
    const int b = blockIdx.x, t = threadIdx.x;
    for (int k = t; k < K; k += 128) pl[k] = pooled[(size_t)b * K + k];
    __syncthreads();
    float acc = bias[t];
    for (int k = 0; k < K; ++k) acc = fmaf(pl[k], w[(size_t)k * 128 + t], acc);
    float v = fmaxf(acc, 0.f);
    float ss = v * v;
    for (int off = 32; off > 0; off >>= 1) ss += __shfl_down(ss, off, 64);
    if ((t & 63) == 0) red2[t >> 6] = ss;
    __syncthreads();
    float inv = 1.0f / fmaxf(sqrtf(red2[0] + red2[1]), 1e-12f);
    n16[(size_t)b * 128 + t] = __float2half(v * inv);
}

// ---------------------------------------------------------------------------
// Normalize embedds rows (d=512) -> fp16 N16 [4096,512]
// ---------------------------------------------------------------------------
__global__ __launch_bounds__(256) void norm512_kernel(const float* __restrict__ E,
                                                      __half* __restrict__ n16)
{
    __shared__ float red4[4];
    const int b = blockIdx.x, t = threadIdx.x;
    float2 v = *(const float2*)(E + (size_t)b * 512 + t * 2);
    float ss = v.x * v.x + v.y * v.y;
    for (int off = 32; off > 0; off >>= 1) ss += __shfl_down(ss, off, 64);
    if ((t & 63) == 0) red4[t >> 6] = ss;
    __syncthreads();
    float inv = 1.0f / fmaxf(sqrtf(red4[0] + red4[1] + red4[2] + red4[3]), 1e-12f);
    __half2 o;
    o.x = __float2half(v.x * inv);
    o.y = __float2half(v.y * inv);
    *(__half2*)(n16 + (size_t)b * 512 + t * 2) = o;
}

// ---------------------------------------------------------------------------
// LDS-staged MFMA GEMM core. 128x128 tile, BK=64, 4 waves 2x2.
// WRITE=false: only fp32 partial sums of clamp(nnT,0,1) w/ zero diag.
// WRITE=true : writes fp8 A' = (v<mean ? 0 : v) (16 MB), coalesced.
// LDS tiles XOR-swizzled: lds[r][byte] holds global[r][byte ^ ((r&7)<<4)].
// ---------------------------------------------------------------------------
template <int K, bool WRITE>
__global__ __launch_bounds__(256) void a_gemm_core(const __half* __restrict__ N16,
                                                   uchar* __restrict__ A8,
                                                   float* __restrict__ partials,
                                                   const float* __restrict__ scal)
{
    __shared__ __half As[128 * 64];
    __shared__ __half Bs[128 * 64];
    __shared__ float reds[4];
    const int t = threadIdx.x;
    const int lane = t & 63, wave = t >> 6;
    const int bx = blockIdx.x & 31, by = blockIdx.x >> 5;
    const int wr = wave >> 1, wc = wave & 1;
    const int fr = lane & 15;
    const int g = lane >> 4;
    const int r0 = by * 128, c0 = bx * 128;
    const int sr = t >> 3;   // staging row within 32-row group
    const int sc = t & 7;    // staging 16B-chunk 0..7

    f32x4 acc[4][4];
#pragma unroll
    for (int i = 0; i < 4; ++i)
#pragma unroll
        for (int j = 0; j < 4; ++j) acc[i][j] = (f32x4){0.f, 0.f, 0.f, 0.f};

    for (int kt = 0; kt < K / 64; ++kt) {
        const int kb = kt * 64;
        __syncthreads();
#pragma unroll
        for (int pp = 0; pp < 4; ++pp) {
            const int r = pp * 32 + sr;
            uint4 va = *(const uint4*)(N16 + (size_t)(r0 + r) * K + kb + sc * 8);
            uint4 vb = *(const uint4*)(N16 + (size_t)(c0 + r) * K + kb + sc * 8);
            const int d = r * 64 + ((((sc * 16) ^ ((r & 7) << 4))) >> 1);
            *(uint4*)&As[d] = va;
            *(uint4*)&Bs[d] = vb;
        }
        __syncthreads();
#pragma unroll
        for (int ks = 0; ks < 2; ++ks) {
            const int ko = ((ks * 64 + g * 16) ^ ((fr & 7) << 4)) >> 1;
            f16x8 af[4], bf[4];
#pragma unroll
            for (int i = 0; i < 4; ++i) {
                af[i] = *(const f16x8*)&As[(wr * 64 + i * 16 + fr) * 64 + ko];
                bf[i] = *(const f16x8*)&Bs[(wc * 64 + i * 16 + fr) * 64 + ko];
            }
#pragma unroll
            for (int i = 0; i < 4; ++i)
#pragma unroll
                for (int j = 0; j < 4; ++j)
                    acc[i][j] = __builtin_amdgcn_mfma_f32_16x16x32_f16(af[i], bf[j], acc[i][j], 0, 0, 0);
        }
    }
    __syncthreads();

    const int r4 = g * 4;
    if (!WRITE) {
        float lsum = 0.f;
#pragma unroll
        for (int i = 0; i < 4; ++i)
#pragma unroll
            for (int q = 0; q < 4; ++q) {
                const int row = r0 + i * 16 + r4 + q;
#pragma unroll
                for (int j = 0; j < 4; ++j) {
                    const int col = c0 + j * 16 + fr;
                    float v = fminf(fmaxf(acc[i][j][q], 0.f), 1.f);
                    if (row == col) v = 0.f;
                    lsum += v;
                }
            }
        for (int off = 32; off > 0; off >>= 1) lsum += __shfl_down(lsum, off, 64);
        if (lane == 0) reds[wave] = lsum;
        __syncthreads();
        if (t == 0) partials[blockIdx.x] = reds[0] + reds[1] + reds[2] + reds[3];
    } else {
        const float mean = scal[0];
        uchar* Cs8 = (uchar*)As;  // 128*144 = 18432 <= 32768
#pragma unroll
        for (int i = 0; i < 4; ++i)
#pragma unroll
            for (int q = 0; q < 4; ++q) {
                const int lr = wr * 64 + i * 16 + r4 + q;
                const int row = r0 + lr;
#pragma unroll
                for (int j = 0; j < 4; ++j) {
                    const int lc = wc * 64 + j * 16 + fr;
                    const int col = c0 + lc;
                    float v = fminf(fmaxf(acc[i][j][q], 0.f), 1.f);
                    if (row == col) v = 0.f;
                    if (v < mean) v = 0.f;
                    unsigned pk = __builtin_amdgcn_cvt_pk_fp8_f32(v, v, 0, false);
                    Cs8[lr * 144 + lc] = (uchar)(pk & 0xff);
                }
            }
        __syncthreads();
#pragma unroll
        for (int pp = 0; pp < 4; ++pp) {
            const int L = pp * 256 + t;
            const int lr = L >> 3, c = L & 7;
            uint4 v = *(const uint4*)&Cs8[lr * 144 + c * 16];
            *(uint4*)(A8 + (size_t)(by * 128 + lr) * 4096 + bx * 128 + c * 16) = v;
        }
    }
}

// ---------------------------------------------------------------------------
// mean of A from per-block partials
// ---------------------------------------------------------------------------
__global__ __launch_bounds__(256) void mean_kernel(const float* __restrict__ partials,
                                                   float* __restrict__ scal)
{
    __shared__ float red[4];
    const int t = threadIdx.x;
    float s = 0.f;
    for (int i = t; i < 1024; i += 256) s += partials[i];
    for (int off = 32; off > 0; off >>= 1) s += __shfl_down(s, off, 64);
    if ((t & 63) == 0) red[t >> 6] = s;
    __syncthreads();
    if (t == 0) scal[0] = (red[0] + red[1] + red[2] + red[3]) * (1.0f / 16777216.0f);
}

// ---------------------------------------------------------------------------
// Scol[0][p][c] = #{labels[0..2047]==c} + 204.8 ; rest zeroed by memset
// ---------------------------------------------------------------------------
__global__ __launch_bounds__(256) void scol0_kernel(const int* __restrict__ labels,
                                                    float* __restrict__ Scol)
{
    __shared__ int hist[16];
    const int t = threadIdx.x;
    if (t < 16) hist[t] = 0;
    __syncthreads();
    for (int i = t; i < 2048; i += 256) atomicAdd(&hist[labels[i]], 1);
    __syncthreads();
    if (t < 80) {
        const int p = t >> 4, c = t & 15;
        Scol[p * 16 + c] = (c < 10) ? ((float)hist[c] + 204.8f) : 0.f;
    }
}

// ---------------------------------------------------------------------------
// X0 init
// ---------------------------------------------------------------------------
__global__ __launch_bounds__(256) void init_kernel(const int* __restrict__ labels,
                                                   uchar* __restrict__ Xt8_0,
                                                   uchar* __restrict__ Xt8_1,
                                                   float* __restrict__ X32)
{
    const int idx = blockIdx.x * 256 + threadIdx.x;   // 5*16*4096 = 327680
    const int p = idx >> 16;
    const int rem = idx & 65535;
    const int c = rem >> 12, row = rem & 4095;
    float v;
    if (c >= 10) v = 0.f;
    else if (row < 2048) v = (labels[row] == c) ? 1.0f : 0.0f;
    else v = 0.1f;
    unsigned pk = __builtin_amdgcn_cvt_pk_fp8_f32(v, v, 0, false);
    Xt8_0[idx] = (uchar)(pk & 0xff);
    if (c >= 10) Xt8_1[idx] = 0;
    if (c < 10) X32[((size_t)p * 4096 + row) * 10 + c] = v;
}

// ---------------------------------------------------------------------------
// One GTG iteration via fp8 MFMA, A-slice staged in LDS (swizzled).
// Block: 256 threads (4 waves), 16 rows of one problem; wave w = k-quarter.
// T = A8'@X8; Y = Scol[it] - T. Then replicator update + next colsum.
// ---------------------------------------------------------------------------
__global__ __launch_bounds__(256, 2) void gtg8_kernel(
    const uchar* __restrict__ A8,
    const uchar* __restrict__ X8i, uchar* __restrict__ X8o,
    const float* __restrict__ X32i, float* __restrict__ X32o,
    float* __restrict__ Xs, float* __restrict__ ytacc,
    float* __restrict__ Scol, int it, int pbase)
{
    __shared__ uchar Al[65536];        // [16 rows][4096 k] swizzled
    __shared__ float yred[4][256];
    const int t = threadIdx.x;
    const int lane = t & 63, wave = t >> 6;
    const int p = pbase + (blockIdx.x >> 8);
    const int pl = p - pbase;
    const int row0 = (blockIdx.x & 255) * 16;
    const int fr = lane & 15;
    const int g = lane >> 4;

    // ---- stage A-slice: wave w loads k-quarter of all 16 rows, coalesced
    {
        const uchar* src = A8 + (size_t)pl * 16777216 + (size_t)row0 * 4096
                         + wave * 1024 + lane * 16;
        uint4 tmp[16];
#pragma unroll
        for (int r = 0; r < 16; ++r) tmp[r] = *(const uint4*)(src + (size_t)r * 4096);
#pragma unroll
        for (int r = 0; r < 16; ++r)
            *(uint4*)&Al[r * 4096 + ((wave * 1024 + lane * 16) ^ ((r & 7) << 4))] = tmp[r];
    }

    const uchar* Xb = X8i + (size_t)p * 65536 + (size_t)fr * 4096;
    const int sfr = (fr & 7) << 4;
    const int k0 = wave * 1024 + g * 8;
    __syncthreads();

    f32x4 acc0 = {0.f, 0.f, 0.f, 0.f};
    f32x4 acc1 = {0.f, 0.f, 0.f, 0.f};
#pragma unroll 8
    for (int s = 0; s < 16; ++s) {
        const int ka = k0 + s * 64;
        const int kb = ka + 32;
        long long a0 = __builtin_bit_cast(long long, *(const uint2*)&Al[fr * 4096 + (ka ^ sfr)]);
        long long a1 = __builtin_bit_cast(long long, *(const uint2*)&Al[fr * 4096 + (kb ^ sfr)]);
        long long b0 = __builtin_bit_cast(long long, *(const uint2*)(Xb + ka));
        long long b1 = __builtin_bit_cast(long long, *(const uint2*)(Xb + kb));
        acc0 = __builtin_amdgcn_mfma_f32_16x16x32_fp8_fp8(a0, b0, acc0, 0, 0, 0);
        acc1 = __builtin_amdgcn_mfma_f32_16x16x32_fp8_fp8(a1, b1, acc1, 0, 0, 0);
    }
    {
        const int r4 = g * 4;
#pragma unroll
        for (int q = 0; q < 4; ++q)
            yred[wave][(r4 + q) * 16 + fr] = acc0[q] + acc1[q];
    }
    __syncthreads();

    // ---- update phase: thread t -> row r=t>>4, class c=t&15
    const int r = t >> 4, c = t & 15;
    const int row = row0 + r;
    const float T = yred[0][t] + yred[1][t] + yred[2][t] + yred[3][t];
    const float y = Scol[it * 80 + p * 16 + c] - T;
    const float x = (c < 10) ? X32i[((size_t)p * 4096 + row) * 10 + c] : 0.f;
    const float m = x * y;
    float s = m;
    s += __shfl_xor(s, 1, 16);
    s += __shfl_xor(s, 2, 16);
    s += __shfl_xor(s, 4, 16);
    s += __shfl_xor(s, 8, 16);
    const float dv = m / (s + 1e-8f);
    const float xn = x + dv;
    if (c < 10) {
        X32o[((size_t)p * 4096 + row) * 10 + c] = xn;
        unsigned pk = __builtin_amdgcn_cvt_pk_fp8_f32(xn, xn, 0, false);
        X8o[(size_t)p * 65536 + c * 4096 + row] = (uchar)(pk & 0xff);
        if (p < 4) Xs[((size_t)p * 4096 + row) * 300 + c * 30 + it] = xn;
    }
    if (p == 4) {
        float e = (c < 10) ? (-dv * logf(dv + 1e-8f)) : 0.f;
        e += __shfl_xor(e, 1, 16);
        e += __shfl_xor(e, 2, 16);
        e += __shfl_xor(e, 4, 16);
        e += __shfl_xor(e, 8, 16);
        if (c == 0) {
            float prev = (it == 0) ? 0.f : ytacc[row];
            ytacc[row] = prev + e;
        }
    }

    // ---- colsum for next iteration
    __syncthreads();
    yred[0][t] = (c < 10) ? xn : 0.f;
    __syncthreads();
    if (t < 10) {
        float sc = 0.f;
#pragma unroll
        for (int rr = 0; rr < 16; ++rr) sc += yred[0][t + rr * 16];
        atomicAdd(&Scol[(it + 1) * 80 + p * 16 + t], sc);
    }
}

// ---------------------------------------------------------------------------
// MLP layers 1+2 for one level
// ---------------------------------------------------------------------------
__global__ __launch_bounds__(256) void mlp12_kernel(const float* __restrict__ Xs,
                                                    const float* __restrict__ w1,
                                                    const float* __restrict__ b1,
                                                    const float* __restrict__ w2,
                                                    const float* __restrict__ b2,
                                                    float* __restrict__ H2, int lvl)
{
    __shared__ float xsh[8][300];
    __shared__ float h1[8][152];
    const int t = threadIdx.x;
    const size_t r0 = (size_t)blockIdx.x * 8;
    for (int i = t; i < 2400; i += 256) xsh[i / 300][i % 300] = Xs[r0 * 300 + i];
    __syncthreads();
    if (t < 150) {
        float acc[8];
#pragma unroll
        for (int r = 0; r < 8; ++r) acc[r] = b1[t];
        for (int k = 0; k < 300; ++k) {
            float wv = w1[(size_t)k * 150 + t];
#pragma unroll
            for (int r = 0; r < 8; ++r) acc[r] = fmaf(xsh[r][k], wv, acc[r]);
        }
#pragma unroll
        for (int r = 0; r < 8; ++r) h1[r][t] = fmaxf(acc[r], 0.f);
    }
    __syncthreads();
    if (t < 75) {
        float acc[8];
#pragma unroll
        for (int r = 0; r < 8; ++r) acc[r] = b2[t];
        for (int k = 0; k < 150; ++k) {
            float wv = w2[(size_t)k * 75 + t];
#pragma unroll
            for (int r = 0; r < 8; ++r) acc[r] = fmaf(h1[r][k], wv, acc[r]);
        }
#pragma unroll
        for (int r = 0; r < 8; ++r) H2[(r0 + r) * 300 + lvl * 75 + t] = fmaxf(acc[r], 0.f);
    }
}

// ---------------------------------------------------------------------------
// Final: y_pred = H2 @ w3 + b3; y_true = ytacc/30; labelled_mask
// ---------------------------------------------------------------------------
__global__ __launch_bounds__(256) void final_kernel(const float* __restrict__ H2,
                                                    const float* __restrict__ w3,
                                                    const float* __restrict__ b3,
                                                    const float* __restrict__ ytacc,
                                                    float* __restrict__ out)
{
    __shared__ float w[300];
    const int t = threadIdx.x;
    const int b = blockIdx.x * 256 + t;
    for (int i = t; i < 300; i += 256) w[i] = w3[i];
    __syncthreads();
    float acc = b3[0];
    const float4* row = (const float4*)(H2 + (size_t)b * 300);
    for (int k4 = 0; k4 < 75; ++k4) {
        float4 v = row[k4];
        acc += v.x * w[k4 * 4] + v.y * w[k4 * 4 + 1] + v.z * w[k4 * 4 + 2] + v.w * w[k4 * 4 + 3];
    }
    out[b] = acc;
    out[4096 + b] = ytacc[b] * (1.0f / 30.0f);
    out[2 * 4096 + b] = (b < 2048) ? 1.0f : 0.0f;
}

// ---------------------------------------------------------------------------
extern "C" void kernel_launch(void* const* d_in, const int* in_sizes, int n_in,
                              void* d_out, int out_size, void* d_ws, size_t ws_size,
                              hipStream_t stream)
{
    (void)in_sizes; (void)n_in; (void)out_size;

    const float* feats[4] = {(const float*)d_in[0], (const float*)d_in[1],
                             (const float*)d_in[2], (const float*)d_in[3]};
    const float* embedds = (const float*)d_in[4];
    const int* labels = (const int*)d_in[6];
    const float* lsw[4] = {(const float*)d_in[7], (const float*)d_in[9],
                           (const float*)d_in[11], (const float*)d_in[13]};
    const float* lsb[4] = {(const float*)d_in[8], (const float*)d_in[10],
                           (const float*)d_in[12], (const float*)d_in[14]};
    const float* w1 = (const float*)d_in[15];
    const float* b1 = (const float*)d_in[16];
    const float* w2 = (const float*)d_in[17];
    const float* b2 = (const float*)d_in[18];
    const float* w3 = (const float*)d_in[19];
    const float* b3 = (const float*)d_in[20];

    // fused path: 5 fp8 A' matrices resident (5*16MB); else 1 reused
    const bool fused = ws_size >= 123375872ULL;
    const size_t A8_BYTES = fused ? 83886080ULL : 16777216ULL;

    char* ws = (char*)d_ws;
    uchar* A8       = (uchar*)(ws);
    char* base      = ws + A8_BYTES;
    float* pooled   = (float*)(base);                 //  8388608
    __half* N16     = (__half*)(base + 8388608);      //  4194304
    uchar* Xt8      = (uchar*)(base + 12582912);      //  2 x 327680
    float* X32      = (float*)(base + 13238272);      //  2 x 819200
    float* Xs       = (float*)(base + 14876672);      //  19660800 (4 problems)
    float* H2       = (float*)(base + 34537472);      //  4915200
    float* ytacc    = (float*)(base + 39452672);      //  16384
    float* partials = (float*)(base + 39469056);      //  4096
    float* scal     = (float*)(base + 39473152);      //  256
    float* Scol     = (float*)(base + 39473408);      //  16384 (31 x 5 x 16 fp32)

    uchar* Xt8b[2] = {Xt8, Xt8 + 327680};
    float* X32b[2] = {X32, X32 + 204800};
    float* out = (float*)d_out;

    const int Cs[4] = {64, 128, 256, 512};
    const int S2s[4] = {64, 64, 16, 16};

    auto run_iters = [&](const uchar* Ab8, int pbase, int nprob) {
        hipMemsetAsync(Scol, 0, 31 * 80 * sizeof(float), stream);
        scol0_kernel<<<1, 256, 0, stream>>>(labels, Scol);
        init_kernel<<<1280, 256, 0, stream>>>(labels, Xt8b[0], Xt8b[1], X32b[0]);
        for (int it = 0; it < 30; ++it) {
            const int i = it & 1, o = i ^ 1;
            gtg8_kernel<<<nprob * 256, 256, 0, stream>>>(
                Ab8, Xt8b[i], Xt8b[o], X32b[i], X32b[o], Xs, ytacc, Scol, it, pbase);
        }
    };

    for (int lvl = 0; lvl < 4; ++lvl) {
        const int c = Cs[lvl];
        const int total = 4096 * c;
        if (S2s[lvl] == 64)
            pool_kernel<64><<<total / 256, 256, 0, stream>>>(feats[lvl], pooled, total);
        else
            pool_kernel<16><<<total / 256, 256, 0, stream>>>(feats[lvl], pooled, total);
        ls_norm_kernel<<<4096, 128, 0, stream>>>(pooled, lsw[lvl], lsb[lvl], N16, c);
        uchar* Ab8 = A8 + (fused ? (size_t)lvl * 16777216 : 0);
        a_gemm_core<128, false><<<1024, 256, 0, stream>>>(N16, Ab8, partials, scal);
        mean_kernel<<<1, 256, 0, stream>>>(partials, scal);
        a_gemm_core<128, true><<<1024, 256, 0, stream>>>(N16, Ab8, partials, scal);
        if (!fused) {
            run_iters(Ab8, lvl, 1);
            mlp12_kernel<<<512, 256, 0, stream>>>(Xs + (size_t)lvl * 1228800,
                                                  w1, b1, w2, b2, H2, lvl);
        }
    }

    // embeddings branch
    norm512_kernel<<<4096, 256, 0, stream>>>(embedds, N16);
    {
        uchar* Ab8 = A8 + (fused ? (size_t)4 * 16777216 : 0);
        a_gemm_core<512, false><<<1024, 256, 0, stream>>>(N16, Ab8, partials, scal);
        mean_kernel<<<1, 256, 0, stream>>>(partials, scal);
        a_gemm_core<512, true><<<1024, 256, 0, stream>>>(N16, Ab8, partials, scal);
        if (!fused) run_iters(Ab8, 4, 1);
    }

    if (fused) {
        run_iters(A8, 0, 5);
        for (int lvl = 0; lvl < 4; ++lvl)
            mlp12_kernel<<<512, 256, 0, stream>>>(Xs + (size_t)lvl * 1228800,
                                                  w1, b1, w2, b2, H2, lvl);
    }

    final_kernel<<<16, 256, 0, stream>>>(H2, w3, b3, ytacc, out);
}

// Round 7
// 1067.736 us; speedup vs baseline: 1.7018x; 1.4532x over previous
//
#include <hip/hip_runtime.h>
#include <hip/hip_fp16.h>

typedef _Float16 f16x8 __attribute__((ext_vector_type(8)));
typedef float f32x4 __attribute__((ext_vector_type(4)));
typedef unsigned char uchar;

static __device__ __forceinline__ long long mk64(unsigned lo, unsigned hi)
{
    return (long long)(((unsigned long long)hi << 32) | (unsigned long long)lo);
}

// fragment-layout offset for X8 (B-operand): class c, row j
static __device__ __forceinline__ int xfrag_off(int c, int j)
{
    return (j >> 6) * 1024 + (((j >> 3) & 3) * 16 + c) * 16 + ((j >> 5) & 1) * 8 + (j & 7);
}

// ---------------------------------------------------------------------------
// Pool: mean over spatial (S2 elements) per (b, ch)
// ---------------------------------------------------------------------------
template <int S2>
__global__ __launch_bounds__(256) void pool_kernel(const float* __restrict__ feat,
                                                   float* __restrict__ pooled, int total)
{
    int idx = blockIdx.x * 256 + threadIdx.x;
    if (idx >= total) return;
    const float4* p4 = (const float4*)(feat + (size_t)idx * S2);
    float s = 0.f;
#pragma unroll
    for (int i = 0; i < S2 / 4; ++i) {
        float4 v = p4[i];
        s += v.x + v.y + v.z + v.w;
    }
    pooled[idx] = s * (1.0f / S2);
}

// ---------------------------------------------------------------------------
// LS: emb = relu(pooled @ w + b), row-normalize -> fp16 N16 [4096,128]
// ---------------------------------------------------------------------------
__global__ __launch_bounds__(128) void ls_norm_kernel(const float* __restrict__ pooled,
                                                      const float* __restrict__ w,
                                                      const float* __restrict__ bias,
                                                      __half* __restrict__ n16, int K)
{
    __shared__ float pl[512];
    __shared__ float red2[2];
    const int b = blockIdx.x, t = threadIdx.x;
    for (int k = t; k < K; k += 128) pl[k] = pooled[(size_t)b * K + k];
    __syncthreads();
    float acc = bias[t];
    for (int k = 0; k < K; ++k) acc = fmaf(pl[k], w[(size_t)k * 128 + t], acc);
    float v = fmaxf(acc, 0.f);
    float ss = v * v;
    for (int off = 32; off > 0; off >>= 1) ss += __shfl_down(ss, off, 64);
    if ((t & 63) == 0) red2[t >> 6] = ss;
    __syncthreads();
    float inv = 1.0f / fmaxf(sqrtf(red2[0] + red2[1]), 1e-12f);
    n16[(size_t)b * 128 + t] = __float2half(v * inv);
}

// ---------------------------------------------------------------------------
// Normalize embedds rows (d=512) -> fp16 N16 [4096,512]
// ---------------------------------------------------------------------------
__global__ __launch_bounds__(256) void norm512_kernel(const float* __restrict__ E,
                                                      __half* __restrict__ n16)
{
    __shared__ float red4[4];
    const int b = blockIdx.x, t = threadIdx.x;
    float2 v = *(const float2*)(E + (size_t)b * 512 + t * 2);
    float ss = v.x * v.x + v.y * v.y;
    for (int off = 32; off > 0; off >>= 1) ss += __shfl_down(ss, off, 64);
    if ((t & 63) == 0) red4[t >> 6] = ss;
    __syncthreads();
    float inv = 1.0f / fmaxf(sqrtf(red4[0] + red4[1] + red4[2] + red4[3]), 1e-12f);
    __half2 o;
    o.x = __float2half(v.x * inv);
    o.y = __float2half(v.y * inv);
    *(__half2*)(n16 + (size_t)b * 512 + t * 2) = o;
}

// ---------------------------------------------------------------------------
// LDS-staged MFMA GEMM core. 128x128 tile, BK=64, 4 waves 2x2.
// WRITE=false: only fp32 partial sums of clamp(nnT,0,1) w/ zero diag.
// WRITE=true : writes fp8 A' = (v<mean ? 0 : v) in MFMA-FRAGMENT ORDER:
//              off = rowblk*65536 + ks2*1024 + lane*16 (+o*8+b), coalesced.
// ---------------------------------------------------------------------------
template <int K, bool WRITE>
__global__ __launch_bounds__(256) void a_gemm_core(const __half* __restrict__ N16,
                                                   uchar* __restrict__ A8,
                                                   float* __restrict__ partials,
                                                   const float* __restrict__ scal)
{
    __shared__ __half As[128 * 64];
    __shared__ __half Bs[128 * 64];
    __shared__ float reds[4];
    const int t = threadIdx.x;
    const int lane = t & 63, wave = t >> 6;
    const int bx = blockIdx.x & 31, by = blockIdx.x >> 5;
    const int wr = wave >> 1, wc = wave & 1;
    const int fr = lane & 15;
    const int g = lane >> 4;
    const int r0 = by * 128, c0 = bx * 128;
    const int sr = t >> 3;   // staging row within 32-row group
    const int sc = t & 7;    // staging 16B-chunk 0..7

    f32x4 acc[4][4];
#pragma unroll
    for (int i = 0; i < 4; ++i)
#pragma unroll
        for (int j = 0; j < 4; ++j) acc[i][j] = (f32x4){0.f, 0.f, 0.f, 0.f};

    for (int kt = 0; kt < K / 64; ++kt) {
        const int kb = kt * 64;
        __syncthreads();
#pragma unroll
        for (int pp = 0; pp < 4; ++pp) {
            const int r = pp * 32 + sr;
            uint4 va = *(const uint4*)(N16 + (size_t)(r0 + r) * K + kb + sc * 8);
            uint4 vb = *(const uint4*)(N16 + (size_t)(c0 + r) * K + kb + sc * 8);
            const int d = r * 64 + ((((sc * 16) ^ ((r & 7) << 4))) >> 1);
            *(uint4*)&As[d] = va;
            *(uint4*)&Bs[d] = vb;
        }
        __syncthreads();
#pragma unroll
        for (int ks = 0; ks < 2; ++ks) {
            const int ko = ((ks * 64 + g * 16) ^ ((fr & 7) << 4)) >> 1;
            f16x8 af[4], bf[4];
#pragma unroll
            for (int i = 0; i < 4; ++i) {
                af[i] = *(const f16x8*)&As[(wr * 64 + i * 16 + fr) * 64 + ko];
                bf[i] = *(const f16x8*)&Bs[(wc * 64 + i * 16 + fr) * 64 + ko];
            }
#pragma unroll
            for (int i = 0; i < 4; ++i)
#pragma unroll
                for (int j = 0; j < 4; ++j)
                    acc[i][j] = __builtin_amdgcn_mfma_f32_16x16x32_f16(af[i], bf[j], acc[i][j], 0, 0, 0);
        }
    }
    __syncthreads();

    const int r4 = g * 4;
    if (!WRITE) {
        float lsum = 0.f;
#pragma unroll
        for (int i = 0; i < 4; ++i)
#pragma unroll
            for (int q = 0; q < 4; ++q) {
                const int row = r0 + i * 16 + r4 + q;
#pragma unroll
                for (int j = 0; j < 4; ++j) {
                    const int col = c0 + j * 16 + fr;
                    float v = fminf(fmaxf(acc[i][j][q], 0.f), 1.f);
                    if (row == col) v = 0.f;
                    lsum += v;
                }
            }
        for (int off = 32; off > 0; off >>= 1) lsum += __shfl_down(lsum, off, 64);
        if (lane == 0) reds[wave] = lsum;
        __syncthreads();
        if (t == 0) partials[blockIdx.x] = reds[0] + reds[1] + reds[2] + reds[3];
    } else {
        const float mean = scal[0];
        uchar* Cs8 = (uchar*)As;  // 128*144 = 18432 <= 32768
#pragma unroll
        for (int i = 0; i < 4; ++i)
#pragma unroll
            for (int q = 0; q < 4; ++q) {
                const int lr = wr * 64 + i * 16 + r4 + q;
                const int row = r0 + lr;
#pragma unroll
                for (int j = 0; j < 4; ++j) {
                    const int lc = wc * 64 + j * 16 + fr;
                    const int col = c0 + lc;
                    float v = fminf(fmaxf(acc[i][j][q], 0.f), 1.f);
                    if (row == col) v = 0.f;
                    if (v < mean) v = 0.f;
                    unsigned pk = __builtin_amdgcn_cvt_pk_fp8_f32(v, v, 0, false);
                    Cs8[lr * 144 + lc] = (uchar)(pk & 0xff);
                }
            }
        __syncthreads();
        // write in MFMA-fragment order, coalesced (1 KB per wave per pass)
#pragma unroll
        for (int pp = 0; pp < 4; ++pp) {
            const int rbl2 = pp * 4 + (t >> 6);
            const int rbl = rbl2 >> 1, ks2l = rbl2 & 1;
            const int l = t & 63;
            const int lr = rbl * 16 + (l & 15);
            const int lc = ks2l * 64 + (l >> 4) * 8;
            uint2 lo = *(const uint2*)&Cs8[lr * 144 + lc];
            uint2 hi = *(const uint2*)&Cs8[lr * 144 + lc + 32];
            uint4 v; v.x = lo.x; v.y = lo.y; v.z = hi.x; v.w = hi.y;
            const size_t rb = (size_t)(by * 8 + rbl);
            const size_t ks2 = (size_t)(bx * 2 + ks2l);
            *(uint4*)(A8 + rb * 65536 + ks2 * 1024 + l * 16) = v;
        }
    }
}

// ---------------------------------------------------------------------------
// mean of A from per-block partials
// ---------------------------------------------------------------------------
__global__ __launch_bounds__(256) void mean_kernel(const float* __restrict__ partials,
                                                   float* __restrict__ scal)
{
    __shared__ float red[4];
    const int t = threadIdx.x;
    float s = 0.f;
    for (int i = t; i < 1024; i += 256) s += partials[i];
    for (int off = 32; off > 0; off >>= 1) s += __shfl_down(s, off, 64);
    if ((t & 63) == 0) red[t >> 6] = s;
    __syncthreads();
    if (t == 0) scal[0] = (red[0] + red[1] + red[2] + red[3]) * (1.0f / 16777216.0f);
}

// ---------------------------------------------------------------------------
// Scol[0][p][c] = #{labels[0..2047]==c} + 204.8 ; rest zeroed by memset
// ---------------------------------------------------------------------------
__global__ __launch_bounds__(256) void scol0_kernel(const int* __restrict__ labels,
                                                    float* __restrict__ Scol)
{
    __shared__ int hist[16];
    const int t = threadIdx.x;
    if (t < 16) hist[t] = 0;
    __syncthreads();
    for (int i = t; i < 2048; i += 256) atomicAdd(&hist[labels[i]], 1);
    __syncthreads();
    if (t < 80) {
        const int p = t >> 4, c = t & 15;
        Scol[p * 16 + c] = (c < 10) ? ((float)hist[c] + 204.8f) : 0.f;
    }
}

// ---------------------------------------------------------------------------
// X0 init (X8 in fragment layout)
// ---------------------------------------------------------------------------
__global__ __launch_bounds__(256) void init_kernel(const int* __restrict__ labels,
                                                   uchar* __restrict__ X8_0,
                                                   uchar* __restrict__ X8_1,
                                                   float* __restrict__ X32)
{
    const int idx = blockIdx.x * 256 + threadIdx.x;   // 5*16*4096 = 327680
    const int p = idx >> 16;
    const int rem = idx & 65535;
    const int c = rem >> 12, j = rem & 4095;
    float v;
    if (c >= 10) v = 0.f;
    else if (j < 2048) v = (labels[j] == c) ? 1.0f : 0.0f;
    else v = 0.1f;
    unsigned pk = __builtin_amdgcn_cvt_pk_fp8_f32(v, v, 0, false);
    const int xo = (int)((size_t)p * 65536) + xfrag_off(c, j);
    X8_0[(size_t)p * 65536 + xfrag_off(c, j)] = (uchar)(pk & 0xff);
    (void)xo;
    if (c >= 10) X8_1[(size_t)p * 65536 + xfrag_off(c, j)] = 0;
    if (c < 10) X32[((size_t)p * 4096 + j) * 10 + c] = v;
}

// ---------------------------------------------------------------------------
// One GTG iteration via fp8 MFMA, fragment-ordered operands, NO LDS staging.
// Block: 256 threads (4 waves), 16 rows of one problem; wave w = k-quarter.
// T = A8'@X8; Y = Scol[it] - T. Then replicator update + next colsum.
// ---------------------------------------------------------------------------
__global__ __launch_bounds__(256, 4) void gtg8_kernel(
    const uchar* __restrict__ A8f,
    const uchar* __restrict__ X8i, uchar* __restrict__ X8o,
    const float* __restrict__ X32i, float* __restrict__ X32o,
    float* __restrict__ Xs, float* __restrict__ ytacc,
    float* __restrict__ Scol, int it, int pbase)
{
    __shared__ float yred[4][256];
    const int t = threadIdx.x;
    const int lane = t & 63, wave = t >> 6;
    const int p = pbase + (blockIdx.x >> 8);
    const int pl = p - pbase;
    const int rb = blockIdx.x & 255;

    const uchar* Ab = A8f + (size_t)pl * 16777216 + (size_t)rb * 65536
                    + wave * 16384 + lane * 16;
    const uchar* Xb = X8i + (size_t)p * 65536 + wave * 16384 + lane * 16;

    f32x4 acc0 = {0.f, 0.f, 0.f, 0.f};
    f32x4 acc1 = {0.f, 0.f, 0.f, 0.f};
#pragma unroll
    for (int u = 0; u < 16; ++u) {
        uint4 av = *(const uint4*)(Ab + u * 1024);
        uint4 bv = *(const uint4*)(Xb + u * 1024);
        long long a0 = mk64(av.x, av.y), a1 = mk64(av.z, av.w);
        long long b0 = mk64(bv.x, bv.y), b1 = mk64(bv.z, bv.w);
        acc0 = __builtin_amdgcn_mfma_f32_16x16x32_fp8_fp8(a0, b0, acc0, 0, 0, 0);
        acc1 = __builtin_amdgcn_mfma_f32_16x16x32_fp8_fp8(a1, b1, acc1, 0, 0, 0);
    }
    {
        const int r4 = (lane >> 4) * 4;
        const int fr = lane & 15;
#pragma unroll
        for (int q = 0; q < 4; ++q)
            yred[wave][(r4 + q) * 16 + fr] = acc0[q] + acc1[q];
    }
    __syncthreads();

    // ---- update phase: thread t -> row r=t>>4, class c=t&15
    const int r = t >> 4, c = t & 15;
    const int row = rb * 16 + r;
    const float T = yred[0][t] + yred[1][t] + yred[2][t] + yred[3][t];
    const float y = Scol[it * 80 + pl * 16 + c] - T;
    const float x = (c < 10) ? X32i[((size_t)p * 4096 + row) * 10 + c] : 0.f;
    const float m = x * y;
    float s = m;
    s += __shfl_xor(s, 1, 16);
    s += __shfl_xor(s, 2, 16);
    s += __shfl_xor(s, 4, 16);
    s += __shfl_xor(s, 8, 16);
    const float dv = m / (s + 1e-8f);
    const float xn = x + dv;
    if (c < 10) {
        X32o[((size_t)p * 4096 + row) * 10 + c] = xn;
        unsigned pk = __builtin_amdgcn_cvt_pk_fp8_f32(xn, xn, 0, false);
        X8o[(size_t)p * 65536 + xfrag_off(c, row)] = (uchar)(pk & 0xff);
        if (p < 4) Xs[((size_t)p * 4096 + row) * 300 + c * 30 + it] = xn;
    }
    if (p == 4) {
        float e = (c < 10) ? (-dv * logf(dv + 1e-8f)) : 0.f;
        e += __shfl_xor(e, 1, 16);
        e += __shfl_xor(e, 2, 16);
        e += __shfl_xor(e, 4, 16);
        e += __shfl_xor(e, 8, 16);
        if (c == 0) {
            float prev = (it == 0) ? 0.f : ytacc[row];
            ytacc[row] = prev + e;
        }
    }

    // ---- colsum for next iteration
    __syncthreads();
    yred[0][t] = (c < 10) ? xn : 0.f;
    __syncthreads();
    if (t < 10) {
        float sc = 0.f;
#pragma unroll
        for (int rr = 0; rr < 16; ++rr) sc += yred[0][t + rr * 16];
        atomicAdd(&Scol[(it + 1) * 80 + pl * 16 + t], sc);
    }
}

// ---------------------------------------------------------------------------
// MLP layers 1+2 for one level
// ---------------------------------------------------------------------------
__global__ __launch_bounds__(256) void mlp12_kernel(const float* __restrict__ Xs,
                                                    const float* __restrict__ w1,
                                                    const float* __restrict__ b1,
                                                    const float* __restrict__ w2,
                                                    const float* __restrict__ b2,
                                                    float* __restrict__ H2, int lvl)
{
    __shared__ float xsh[8][300];
    __shared__ float h1[8][152];
    const int t = threadIdx.x;
    const size_t r0 = (size_t)blockIdx.x * 8;
    for (int i = t; i < 2400; i += 256) xsh[i / 300][i % 300] = Xs[r0 * 300 + i];
    __syncthreads();
    if (t < 150) {
        float acc[8];
#pragma unroll
        for (int r = 0; r < 8; ++r) acc[r] = b1[t];
        for (int k = 0; k < 300; ++k) {
            float wv = w1[(size_t)k * 150 + t];
#pragma unroll
            for (int r = 0; r < 8; ++r) acc[r] = fmaf(xsh[r][k], wv, acc[r]);
        }
#pragma unroll
        for (int r = 0; r < 8; ++r) h1[r][t] = fmaxf(acc[r], 0.f);
    }
    __syncthreads();
    if (t < 75) {
        float acc[8];
#pragma unroll
        for (int r = 0; r < 8; ++r) acc[r] = b2[t];
        for (int k = 0; k < 150; ++k) {
            float wv = w2[(size_t)k * 75 + t];
#pragma unroll
            for (int r = 0; r < 8; ++r) acc[r] = fmaf(h1[r][k], wv, acc[r]);
        }
#pragma unroll
        for (int r = 0; r < 8; ++r) H2[(r0 + r) * 300 + lvl * 75 + t] = fmaxf(acc[r], 0.f);
    }
}

// ---------------------------------------------------------------------------
// Final: y_pred = H2 @ w3 + b3; y_true = ytacc/30; labelled_mask
// ---------------------------------------------------------------------------
__global__ __launch_bounds__(256) void final_kernel(const float* __restrict__ H2,
                                                    const float* __restrict__ w3,
                                                    const float* __restrict__ b3,
                                                    const float* __restrict__ ytacc,
                                                    float* __restrict__ out)
{
    __shared__ float w[300];
    const int t = threadIdx.x;
    const int b = blockIdx.x * 256 + t;
    for (int i = t; i < 300; i += 256) w[i] = w3[i];
    __syncthreads();
    float acc = b3[0];
    const float4* row = (const float4*)(H2 + (size_t)b * 300);
    for (int k4 = 0; k4 < 75; ++k4) {
        float4 v = row[k4];
        acc += v.x * w[k4 * 4] + v.y * w[k4 * 4 + 1] + v.z * w[k4 * 4 + 2] + v.w * w[k4 * 4 + 3];
    }
    out[b] = acc;
    out[4096 + b] = ytacc[b] * (1.0f / 30.0f);
    out[2 * 4096 + b] = (b < 2048) ? 1.0f : 0.0f;
}

// ---------------------------------------------------------------------------
extern "C" void kernel_launch(void* const* d_in, const int* in_sizes, int n_in,
                              void* d_out, int out_size, void* d_ws, size_t ws_size,
                              hipStream_t stream)
{
    (void)in_sizes; (void)n_in; (void)out_size;

    const float* feats[4] = {(const float*)d_in[0], (const float*)d_in[1],
                             (const float*)d_in[2], (const float*)d_in[3]};
    const float* embedds = (const float*)d_in[4];
    const int* labels = (const int*)d_in[6];
    const float* lsw[4] = {(const float*)d_in[7], (const float*)d_in[9],
                           (const float*)d_in[11], (const float*)d_in[13]};
    const float* lsb[4] = {(const float*)d_in[8], (const float*)d_in[10],
                           (const float*)d_in[12], (const float*)d_in[14]};
    const float* w1 = (const float*)d_in[15];
    const float* b1 = (const float*)d_in[16];
    const float* w2 = (const float*)d_in[17];
    const float* b2 = (const float*)d_in[18];
    const float* w3 = (const float*)d_in[19];
    const float* b3 = (const float*)d_in[20];

    // fused path: 5 fp8 A' matrices resident (5*16MB); else 1 reused
    const bool fused = ws_size >= 123375872ULL;
    const size_t A8_BYTES = fused ? 83886080ULL : 16777216ULL;

    char* ws = (char*)d_ws;
    uchar* A8       = (uchar*)(ws);
    char* base      = ws + A8_BYTES;
    float* pooled   = (float*)(base);                 //  8388608
    __half* N16     = (__half*)(base + 8388608);      //  4194304
    uchar* Xt8      = (uchar*)(base + 12582912);      //  2 x 327680
    float* X32      = (float*)(base + 13238272);      //  2 x 819200
    float* Xs       = (float*)(base + 14876672);      //  19660800 (4 problems)
    float* H2       = (float*)(base + 34537472);      //  4915200
    float* ytacc    = (float*)(base + 39452672);      //  16384
    float* partials = (float*)(base + 39469056);      //  4096
    float* scal     = (float*)(base + 39473152);      //  256
    float* Scol     = (float*)(base + 39473408);      //  16384 (31 x 5 x 16 fp32)

    uchar* Xt8b[2] = {Xt8, Xt8 + 327680};
    float* X32b[2] = {X32, X32 + 204800};
    float* out = (float*)d_out;

    const int Cs[4] = {64, 128, 256, 512};
    const int S2s[4] = {64, 64, 16, 16};

    auto run_iters = [&](const uchar* Ab8, int pbase, int nprob) {
        hipMemsetAsync(Scol, 0, 31 * 80 * sizeof(float), stream);
        scol0_kernel<<<1, 256, 0, stream>>>(labels, Scol);
        init_kernel<<<1280, 256, 0, stream>>>(labels, Xt8b[0], Xt8b[1], X32b[0]);
        for (int it = 0; it < 30; ++it) {
            const int i = it & 1, o = i ^ 1;
            gtg8_kernel<<<nprob * 256, 256, 0, stream>>>(
                Ab8, Xt8b[i], Xt8b[o], X32b[i], X32b[o], Xs, ytacc, Scol, it, pbase);
        }
    };

    for (int lvl = 0; lvl < 4; ++lvl) {
        const int c = Cs[lvl];
        const int total = 4096 * c;
        if (S2s[lvl] == 64)
            pool_kernel<64><<<total / 256, 256, 0, stream>>>(feats[lvl], pooled, total);
        else
            pool_kernel<16><<<total / 256, 256, 0, stream>>>(feats[lvl], pooled, total);
        ls_norm_kernel<<<4096, 128, 0, stream>>>(pooled, lsw[lvl], lsb[lvl], N16, c);
        uchar* Ab8 = A8 + (fused ? (size_t)lvl * 16777216 : 0);
        a_gemm_core<128, false><<<1024, 256, 0, stream>>>(N16, Ab8, partials, scal);
        mean_kernel<<<1, 256, 0, stream>>>(partials, scal);
        a_gemm_core<128, true><<<1024, 256, 0, stream>>>(N16, Ab8, partials, scal);
        if (!fused) {
            run_iters(Ab8, lvl, 1);
            mlp12_kernel<<<512, 256, 0, stream>>>(Xs + (size_t)lvl * 1228800,
                                                  w1, b1, w2, b2, H2, lvl);
        }
    }

    // embeddings branch
    norm512_kernel<<<4096, 256, 0, stream>>>(embedds, N16);
    {
        uchar* Ab8 = A8 + (fused ? (size_t)4 * 16777216 : 0);
        a_gemm_core<512, false><<<1024, 256, 0, stream>>>(N16, Ab8, partials, scal);
        mean_kernel<<<1, 256, 0, stream>>>(partials, scal);
        a_gemm_core<512, true><<<1024, 256, 0, stream>>>(N16, Ab8, partials, scal);
        if (!fused) run_iters(Ab8, 4, 1);
    }

    if (fused) {
        run_iters(A8, 0, 5);
        for (int lvl = 0; lvl < 4; ++lvl)
            mlp12_kernel<<<512, 256, 0, stream>>>(Xs + (size_t)lvl * 1228800,
                                                  w1, b1, w2, b2, H2, lvl);
    }

    final_kernel<<<16, 256, 0, stream>>>(H2, w3, b3, ytacc, out);
}

// Round 8
// 1035.735 us; speedup vs baseline: 1.7544x; 1.0309x over previous
//
#include <hip/hip_runtime.h>
#include <hip/hip_fp16.h>

typedef _Float16 f16x8 __attribute__((ext_vector_type(8)));
typedef float f32x4 __attribute__((ext_vector_type(4)));
typedef unsigned char uchar;

static __device__ __forceinline__ long long mk64(unsigned lo, unsigned hi)
{
    return (long long)(((unsigned long long)hi << 32) | (unsigned long long)lo);
}

// fragment-layout offset for X8 (B-operand): class c, row j
static __device__ __forceinline__ int xfrag_off(int c, int j)
{
    return (j >> 6) * 1024 + (((j >> 3) & 3) * 16 + c) * 16 + ((j >> 5) & 1) * 8 + (j & 7);
}

// ---------------------------------------------------------------------------
// Pool: mean over spatial (S2 elements) per (b, ch)
// ---------------------------------------------------------------------------
template <int S2>
__global__ __launch_bounds__(256) void pool_kernel(const float* __restrict__ feat,
                                                   float* __restrict__ pooled, int total)
{
    int idx = blockIdx.x * 256 + threadIdx.x;
    if (idx >= total) return;
    const float4* p4 = (const float4*)(feat + (size_t)idx * S2);
    float s = 0.f;
#pragma unroll
    for (int i = 0; i < S2 / 4; ++i) {
        float4 v = p4[i];
        s += v.x + v.y + v.z + v.w;
    }
    pooled[idx] = s * (1.0f / S2);
}

// ---------------------------------------------------------------------------
// LS: emb = relu(pooled @ w + b), row-normalize -> fp16 N16 [4096,128]
// ---------------------------------------------------------------------------
__global__ __launch_bounds__(128) void ls_norm_kernel(const float* __restrict__ pooled,
                                                      const float* __restrict__ w,
                                                      const float* __restrict__ bias,
                                                      __half* __restrict__ n16, int K)
{
    __shared__ float pl[512];
    __shared__ float red2[2];
    const int b = blockIdx.x, t = threadIdx.x;
    for (int k = t; k < K; k += 128) pl[k] = pooled[(size_t)b * K + k];
    __syncthreads();
    float acc = bias[t];
    for (int k = 0; k < K; ++k) acc = fmaf(pl[k], w[(size_t)k * 128 + t], acc);
    float v = fmaxf(acc, 0.f);
    float ss = v * v;
    for (int off = 32; off > 0; off >>= 1) ss += __shfl_down(ss, off, 64);
    if ((t & 63) == 0) red2[t >> 6] = ss;
    __syncthreads();
    float inv = 1.0f / fmaxf(sqrtf(red2[0] + red2[1]), 1e-12f);
    n16[(size_t)b * 128 + t] = __float2half(v * inv);
}

// ---------------------------------------------------------------------------
// Normalize embedds rows (d=512) -> fp16 N16 [4096,512]
// ---------------------------------------------------------------------------
__global__ __launch_bounds__(256) void norm512_kernel(const float* __restrict__ E,
                                                      __half* __restrict__ n16)
{
    __shared__ float red4[4];
    const int b = blockIdx.x, t = threadIdx.x;
    float2 v = *(const float2*)(E + (size_t)b * 512 + t * 2);
    float ss = v.x * v.x + v.y * v.y;
    for (int off = 32; off > 0; off >>= 1) ss += __shfl_down(ss, off, 64);
    if ((t & 63) == 0) red4[t >> 6] = ss;
    __syncthreads();
    float inv = 1.0f / fmaxf(sqrtf(red4[0] + red4[1] + red4[2] + red4[3]), 1e-12f);
    __half2 o;
    o.x = __float2half(v.x * inv);
    o.y = __float2half(v.y * inv);
    *(__half2*)(n16 + (size_t)b * 512 + t * 2) = o;
}

// ---------------------------------------------------------------------------
// Single-pass MFMA GEMM. 128x128 tile, BK=64, 4 waves 2x2.
// Writes fp16 C = clamp(nnT,0,1) w/ diag=0 in FRAGMENT-MAJOR order (32 MB,
// coalesced via 32KB LDS transpose) + fp32 per-block partial sums for mean.
// A16f byte layout: rb*131072 + ks2*2048 + lane*32, each 32B = fp16 of the
// 16 elements the fp8 fragment at rb*65536+ks2*1024+lane*16 will hold.
// ---------------------------------------------------------------------------
template <int K>
__global__ __launch_bounds__(256) void a_gemm_core(const __half* __restrict__ N16,
                                                   __half* __restrict__ A16f,
                                                   float* __restrict__ partials)
{
    __shared__ __half smem[16384];   // As(8192) | Bs(8192); reused as Cst(16384)
    __shared__ float reds[4];
    __half* As = smem;
    __half* Bs = smem + 8192;
    char* Cb = (char*)smem;          // Cst: 128 rows x 256 bytes, XOR-swizzled
    const int t = threadIdx.x;
    const int lane = t & 63, wave = t >> 6;
    const int bx = blockIdx.x & 31, by = blockIdx.x >> 5;
    const int wr = wave >> 1, wc = wave & 1;
    const int fr = lane & 15;
    const int g = lane >> 4;
    const int r0 = by * 128, c0 = bx * 128;
    const int sr = t >> 3;   // staging row within 32-row group
    const int sc = t & 7;    // staging 16B-chunk 0..7

    f32x4 acc[4][4];
#pragma unroll
    for (int i = 0; i < 4; ++i)
#pragma unroll
        for (int j = 0; j < 4; ++j) acc[i][j] = (f32x4){0.f, 0.f, 0.f, 0.f};

    for (int kt = 0; kt < K / 64; ++kt) {
        const int kb = kt * 64;
        __syncthreads();
#pragma unroll
        for (int pp = 0; pp < 4; ++pp) {
            const int r = pp * 32 + sr;
            uint4 va = *(const uint4*)(N16 + (size_t)(r0 + r) * K + kb + sc * 8);
            uint4 vb = *(const uint4*)(N16 + (size_t)(c0 + r) * K + kb + sc * 8);
            const int d = r * 64 + ((((sc * 16) ^ ((r & 7) << 4))) >> 1);
            *(uint4*)&As[d] = va;
            *(uint4*)&Bs[d] = vb;
        }
        __syncthreads();
#pragma unroll
        for (int ks = 0; ks < 2; ++ks) {
            const int ko = ((ks * 64 + g * 16) ^ ((fr & 7) << 4)) >> 1;
            f16x8 af[4], bf[4];
#pragma unroll
            for (int i = 0; i < 4; ++i) {
                af[i] = *(const f16x8*)&As[(wr * 64 + i * 16 + fr) * 64 + ko];
                bf[i] = *(const f16x8*)&Bs[(wc * 64 + i * 16 + fr) * 64 + ko];
            }
#pragma unroll
            for (int i = 0; i < 4; ++i)
#pragma unroll
                for (int j = 0; j < 4; ++j)
                    acc[i][j] = __builtin_amdgcn_mfma_f32_16x16x32_f16(af[i], bf[j], acc[i][j], 0, 0, 0);
        }
    }
    __syncthreads();

    // epilogue: clamp, zero diag, sum, stage fp16 into swizzled Cst
    float lsum = 0.f;
    const int r4 = g * 4;
#pragma unroll
    for (int i = 0; i < 4; ++i) {
#pragma unroll
        for (int q = 0; q < 4; ++q) {
            const int lr = wr * 64 + i * 16 + r4 + q;
            const int row = r0 + lr;
#pragma unroll
            for (int j = 0; j < 4; ++j) {
                const int lc = wc * 64 + j * 16 + fr;
                const int col = c0 + lc;
                float v = fminf(fmaxf(acc[i][j][q], 0.f), 1.f);
                if (row == col) v = 0.f;
                lsum += v;
                *(__half*)(Cb + lr * 256 + ((lc * 2) ^ ((lr & 7) << 4))) = __float2half(v);
            }
        }
    }
    __syncthreads();

    // fragment-major coalesced store: 4 passes x 256 threads x 32B = 32 KB
#pragma unroll
    for (int pp = 0; pp < 4; ++pp) {
        const int rbl2 = pp * 4 + (t >> 6);
        const int rbl = rbl2 >> 1, ks2l = rbl2 & 1;
        const int l = t & 63;
        const int lr = rbl * 16 + (l & 15);
        const int e0 = ks2l * 64 + (l >> 4) * 8;
        uint4 v0 = *(const uint4*)(Cb + lr * 256 + ((e0 * 2) ^ ((lr & 7) << 4)));
        uint4 v1 = *(const uint4*)(Cb + lr * 256 + (((e0 + 32) * 2) ^ ((lr & 7) << 4)));
        const size_t rb = (size_t)(by * 8 + rbl);
        const size_t ks2 = (size_t)(bx * 2 + ks2l);
        char* dst = (char*)A16f + rb * 131072 + ks2 * 2048 + l * 32;
        *(uint4*)dst = v0;
        *(uint4*)(dst + 16) = v1;
    }

    for (int off = 32; off > 0; off >>= 1) lsum += __shfl_down(lsum, off, 64);
    if (lane == 0) reds[wave] = lsum;
    __syncthreads();
    if (t == 0) partials[blockIdx.x] = reds[0] + reds[1] + reds[2] + reds[3];
}

// ---------------------------------------------------------------------------
// mean of A from per-block partials
// ---------------------------------------------------------------------------
__global__ __launch_bounds__(256) void mean_kernel(const float* __restrict__ partials,
                                                   float* __restrict__ scal)
{
    __shared__ float red[4];
    const int t = threadIdx.x;
    float s = 0.f;
    for (int i = t; i < 1024; i += 256) s += partials[i];
    for (int off = 32; off > 0; off >>= 1) s += __shfl_down(s, off, 64);
    if ((t & 63) == 0) red[t >> 6] = s;
    __syncthreads();
    if (t == 0) scal[0] = (red[0] + red[1] + red[2] + red[3]) * (1.0f / 16777216.0f);
}

// ---------------------------------------------------------------------------
// Elementwise: A8[i] = fp8( a16[i] < mean ? 0 : a16[i] ) on linear frag order.
// 16B fp8 out per thread <- 32B fp16 in.
// ---------------------------------------------------------------------------
__global__ __launch_bounds__(256) void abar8_frag_kernel(const __half* __restrict__ A16f,
                                                         uchar* __restrict__ A8,
                                                         const float* __restrict__ scal)
{
    const float mean = scal[0];
    const size_t i = ((size_t)blockIdx.x * 256 + threadIdx.x) * 16;
    uint4 u0 = *(const uint4*)(A16f + i);
    uint4 u1 = *(const uint4*)(A16f + i + 8);
    __half h[16];
    *(uint4*)h = u0;
    *(uint4*)(h + 8) = u1;
    float v[16];
#pragma unroll
    for (int k = 0; k < 16; ++k) {
        float a = __half2float(h[k]);
        v[k] = (a < mean) ? 0.f : a;
    }
    unsigned w0 = __builtin_amdgcn_cvt_pk_fp8_f32(v[0], v[1], 0, false);
    w0 = __builtin_amdgcn_cvt_pk_fp8_f32(v[2], v[3], (int)w0, true);
    unsigned w1 = __builtin_amdgcn_cvt_pk_fp8_f32(v[4], v[5], 0, false);
    w1 = __builtin_amdgcn_cvt_pk_fp8_f32(v[6], v[7], (int)w1, true);
    unsigned w2 = __builtin_amdgcn_cvt_pk_fp8_f32(v[8], v[9], 0, false);
    w2 = __builtin_amdgcn_cvt_pk_fp8_f32(v[10], v[11], (int)w2, true);
    unsigned w3 = __builtin_amdgcn_cvt_pk_fp8_f32(v[12], v[13], 0, false);
    w3 = __builtin_amdgcn_cvt_pk_fp8_f32(v[14], v[15], (int)w3, true);
    uint4 o; o.x = w0; o.y = w1; o.z = w2; o.w = w3;
    *(uint4*)(A8 + i) = o;
}

// ---------------------------------------------------------------------------
// Scol[0][p][c] = #{labels[0..2047]==c} + 204.8 ; rest zeroed by memset
// ---------------------------------------------------------------------------
__global__ __launch_bounds__(256) void scol0_kernel(const int* __restrict__ labels,
                                                    float* __restrict__ Scol)
{
    __shared__ int hist[16];
    const int t = threadIdx.x;
    if (t < 16) hist[t] = 0;
    __syncthreads();
    for (int i = t; i < 2048; i += 256) atomicAdd(&hist[labels[i]], 1);
    __syncthreads();
    if (t < 80) {
        const int p = t >> 4, c = t & 15;
        Scol[p * 16 + c] = (c < 10) ? ((float)hist[c] + 204.8f) : 0.f;
    }
}

// ---------------------------------------------------------------------------
// X0 init (X8 in fragment layout)
// ---------------------------------------------------------------------------
__global__ __launch_bounds__(256) void init_kernel(const int* __restrict__ labels,
                                                   uchar* __restrict__ X8_0,
                                                   uchar* __restrict__ X8_1,
                                                   float* __restrict__ X32)
{
    const int idx = blockIdx.x * 256 + threadIdx.x;   // 5*16*4096 = 327680
    const int p = idx >> 16;
    const int rem = idx & 65535;
    const int c = rem >> 12, j = rem & 4095;
    float v;
    if (c >= 10) v = 0.f;
    else if (j < 2048) v = (labels[j] == c) ? 1.0f : 0.0f;
    else v = 0.1f;
    unsigned pk = __builtin_amdgcn_cvt_pk_fp8_f32(v, v, 0, false);
    X8_0[(size_t)p * 65536 + xfrag_off(c, j)] = (uchar)(pk & 0xff);
    if (c >= 10) X8_1[(size_t)p * 65536 + xfrag_off(c, j)] = 0;
    if (c < 10) X32[((size_t)p * 4096 + j) * 10 + c] = v;
}

// ---------------------------------------------------------------------------
// One GTG iteration via fp8 MFMA, fragment-ordered operands, NO LDS staging.
// ---------------------------------------------------------------------------
__global__ __launch_bounds__(256, 4) void gtg8_kernel(
    const uchar* __restrict__ A8f,
    const uchar* __restrict__ X8i, uchar* __restrict__ X8o,
    const float* __restrict__ X32i, float* __restrict__ X32o,
    float* __restrict__ Xs, float* __restrict__ ytacc,
    float* __restrict__ Scol, int it, int pbase)
{
    __shared__ float yred[4][256];
    const int t = threadIdx.x;
    const int lane = t & 63, wave = t >> 6;
    const int p = pbase + (blockIdx.x >> 8);
    const int pl = p - pbase;
    const int rb = blockIdx.x & 255;

    const uchar* Ab = A8f + (size_t)pl * 16777216 + (size_t)rb * 65536
                    + wave * 16384 + lane * 16;
    const uchar* Xb = X8i + (size_t)p * 65536 + wave * 16384 + lane * 16;

    f32x4 acc0 = {0.f, 0.f, 0.f, 0.f};
    f32x4 acc1 = {0.f, 0.f, 0.f, 0.f};
#pragma unroll
    for (int u = 0; u < 16; ++u) {
        uint4 av = *(const uint4*)(Ab + u * 1024);
        uint4 bv = *(const uint4*)(Xb + u * 1024);
        long long a0 = mk64(av.x, av.y), a1 = mk64(av.z, av.w);
        long long b0 = mk64(bv.x, bv.y), b1 = mk64(bv.z, bv.w);
        acc0 = __builtin_amdgcn_mfma_f32_16x16x32_fp8_fp8(a0, b0, acc0, 0, 0, 0);
        acc1 = __builtin_amdgcn_mfma_f32_16x16x32_fp8_fp8(a1, b1, acc1, 0, 0, 0);
    }
    {
        const int r4 = (lane >> 4) * 4;
        const int fr = lane & 15;
#pragma unroll
        for (int q = 0; q < 4; ++q)
            yred[wave][(r4 + q) * 16 + fr] = acc0[q] + acc1[q];
    }
    __syncthreads();

    // ---- update phase: thread t -> row r=t>>4, class c=t&15
    const int r = t >> 4, c = t & 15;
    const int row = rb * 16 + r;
    const float T = yred[0][t] + yred[1][t] + yred[2][t] + yred[3][t];
    const float y = Scol[it * 80 + pl * 16 + c] - T;
    const float x = (c < 10) ? X32i[((size_t)p * 4096 + row) * 10 + c] : 0.f;
    const float m = x * y;
    float s = m;
    s += __shfl_xor(s, 1, 16);
    s += __shfl_xor(s, 2, 16);
    s += __shfl_xor(s, 4, 16);
    s += __shfl_xor(s, 8, 16);
    const float dv = m / (s + 1e-8f);
    const float xn = x + dv;
    if (c < 10) {
        X32o[((size_t)p * 4096 + row) * 10 + c] = xn;
        unsigned pk = __builtin_amdgcn_cvt_pk_fp8_f32(xn, xn, 0, false);
        X8o[(size_t)p * 65536 + xfrag_off(c, row)] = (uchar)(pk & 0xff);
        if (p < 4) Xs[((size_t)p * 4096 + row) * 300 + c * 30 + it] = xn;
    }
    if (p == 4) {
        float e = (c < 10) ? (-dv * logf(dv + 1e-8f)) : 0.f;
        e += __shfl_xor(e, 1, 16);
        e += __shfl_xor(e, 2, 16);
        e += __shfl_xor(e, 4, 16);
        e += __shfl_xor(e, 8, 16);
        if (c == 0) {
            float prev = (it == 0) ? 0.f : ytacc[row];
            ytacc[row] = prev + e;
        }
    }

    // ---- colsum for next iteration
    __syncthreads();
    yred[0][t] = (c < 10) ? xn : 0.f;
    __syncthreads();
    if (t < 10) {
        float sc = 0.f;
#pragma unroll
        for (int rr = 0; rr < 16; ++rr) sc += yred[0][t + rr * 16];
        atomicAdd(&Scol[(it + 1) * 80 + pl * 16 + t], sc);
    }
}

// ---------------------------------------------------------------------------
// MLP layers 1+2, all 4 levels in one dispatch (lvl = blockIdx >> 9)
// ---------------------------------------------------------------------------
__global__ __launch_bounds__(256) void mlp12_all_kernel(const float* __restrict__ XsBase,
                                                        const float* __restrict__ w1,
                                                        const float* __restrict__ b1,
                                                        const float* __restrict__ w2,
                                                        const float* __restrict__ b2,
                                                        float* __restrict__ H2)
{
    __shared__ float xsh[8][300];
    __shared__ float h1[8][152];
    const int t = threadIdx.x;
    const int lvl = blockIdx.x >> 9;
    const float* Xs = XsBase + (size_t)lvl * 1228800;
    const size_t r0 = (size_t)(blockIdx.x & 511) * 8;
    for (int i = t; i < 2400; i += 256) xsh[i / 300][i % 300] = Xs[r0 * 300 + i];
    __syncthreads();
    if (t < 150) {
        float acc[8];
#pragma unroll
        for (int r = 0; r < 8; ++r) acc[r] = b1[t];
        for (int k = 0; k < 300; ++k) {
            float wv = w1[(size_t)k * 150 + t];
#pragma unroll
            for (int r = 0; r < 8; ++r) acc[r] = fmaf(xsh[r][k], wv, acc[r]);
        }
#pragma unroll
        for (int r = 0; r < 8; ++r) h1[r][t] = fmaxf(acc[r], 0.f);
    }
    __syncthreads();
    if (t < 75) {
        float acc[8];
#pragma unroll
        for (int r = 0; r < 8; ++r) acc[r] = b2[t];
        for (int k = 0; k < 150; ++k) {
            float wv = w2[(size_t)k * 75 + t];
#pragma unroll
            for (int r = 0; r < 8; ++r) acc[r] = fmaf(h1[r][k], wv, acc[r]);
        }
#pragma unroll
        for (int r = 0; r < 8; ++r) H2[(r0 + r) * 300 + lvl * 75 + t] = fmaxf(acc[r], 0.f);
    }
}

// ---------------------------------------------------------------------------
// Final: y_pred = H2 @ w3 + b3; y_true = ytacc/30; labelled_mask
// ---------------------------------------------------------------------------
__global__ __launch_bounds__(256) void final_kernel(const float* __restrict__ H2,
                                                    const float* __restrict__ w3,
                                                    const float* __restrict__ b3,
                                                    const float* __restrict__ ytacc,
                                                    float* __restrict__ out)
{
    __shared__ float w[300];
    const int t = threadIdx.x;
    const int b = blockIdx.x * 256 + t;
    for (int i = t; i < 300; i += 256) w[i] = w3[i];
    __syncthreads();
    float acc = b3[0];
    const float4* row = (const float4*)(H2 + (size_t)b * 300);
    for (int k4 = 0; k4 < 75; ++k4) {
        float4 v = row[k4];
        acc += v.x * w[k4 * 4] + v.y * w[k4 * 4 + 1] + v.z * w[k4 * 4 + 2] + v.w * w[k4 * 4 + 3];
    }
    out[b] = acc;
    out[4096 + b] = ytacc[b] * (1.0f / 30.0f);
    out[2 * 4096 + b] = (b < 2048) ? 1.0f : 0.0f;
}

// ---------------------------------------------------------------------------
extern "C" void kernel_launch(void* const* d_in, const int* in_sizes, int n_in,
                              void* d_out, int out_size, void* d_ws, size_t ws_size,
                              hipStream_t stream)
{
    (void)in_sizes; (void)n_in; (void)out_size;

    const float* feats[4] = {(const float*)d_in[0], (const float*)d_in[1],
                             (const float*)d_in[2], (const float*)d_in[3]};
    const float* embedds = (const float*)d_in[4];
    const int* labels = (const int*)d_in[6];
    const float* lsw[4] = {(const float*)d_in[7], (const float*)d_in[9],
                           (const float*)d_in[11], (const float*)d_in[13]};
    const float* lsb[4] = {(const float*)d_in[8], (const float*)d_in[10],
                           (const float*)d_in[12], (const float*)d_in[14]};
    const float* w1 = (const float*)d_in[15];
    const float* b1 = (const float*)d_in[16];
    const float* w2 = (const float*)d_in[17];
    const float* b2 = (const float*)d_in[18];
    const float* w3 = (const float*)d_in[19];
    const float* b3 = (const float*)d_in[20];

    // fused path: 5 fp8 A' matrices resident (5*16MB) + 32MB A16f; else 1 A8
    const bool fused = ws_size >= 156930304ULL;
    const size_t A8_BYTES = fused ? 83886080ULL : 16777216ULL;

    char* ws = (char*)d_ws;
    uchar* A8       = (uchar*)(ws);
    __half* A16f    = (__half*)(ws + A8_BYTES);       // 33554432 (scratch)
    char* base      = ws + A8_BYTES + 33554432;
    float* pooled   = (float*)(base);                 //  8388608
    __half* N16     = (__half*)(base + 8388608);      //  4194304
    uchar* Xt8      = (uchar*)(base + 12582912);      //  2 x 327680
    float* X32      = (float*)(base + 13238272);      //  2 x 819200
    float* Xs       = (float*)(base + 14876672);      //  19660800 (4 problems)
    float* H2       = (float*)(base + 34537472);      //  4915200
    float* ytacc    = (float*)(base + 39452672);      //  16384
    float* partials = (float*)(base + 39469056);      //  4096
    float* scal     = (float*)(base + 39473152);      //  256
    float* Scol     = (float*)(base + 39473408);      //  16384 (31 x 5 x 16 fp32)

    uchar* Xt8b[2] = {Xt8, Xt8 + 327680};
    float* X32b[2] = {X32, X32 + 204800};
    float* out = (float*)d_out;

    const int Cs[4] = {64, 128, 256, 512};
    const int S2s[4] = {64, 64, 16, 16};

    auto run_iters = [&](const uchar* Ab8, int pbase, int nprob) {
        hipMemsetAsync(Scol, 0, 31 * 80 * sizeof(float), stream);
        scol0_kernel<<<1, 256, 0, stream>>>(labels, Scol);
        init_kernel<<<1280, 256, 0, stream>>>(labels, Xt8b[0], Xt8b[1], X32b[0]);
        for (int it = 0; it < 30; ++it) {
            const int i = it & 1, o = i ^ 1;
            gtg8_kernel<<<nprob * 256, 256, 0, stream>>>(
                Ab8, Xt8b[i], Xt8b[o], X32b[i], X32b[o], Xs, ytacc, Scol, it, pbase);
        }
    };

    auto do_mlp = [&]() {
        mlp12_all_kernel<<<2048, 256, 0, stream>>>(Xs, w1, b1, w2, b2, H2);
    };

    for (int lvl = 0; lvl < 4; ++lvl) {
        const int c = Cs[lvl];
        const int total = 4096 * c;
        if (S2s[lvl] == 64)
            pool_kernel<64><<<total / 256, 256, 0, stream>>>(feats[lvl], pooled, total);
        else
            pool_kernel<16><<<total / 256, 256, 0, stream>>>(feats[lvl], pooled, total);
        ls_norm_kernel<<<4096, 128, 0, stream>>>(pooled, lsw[lvl], lsb[lvl], N16, c);
        uchar* Ab8 = A8 + (fused ? (size_t)lvl * 16777216 : 0);
        a_gemm_core<128><<<1024, 256, 0, stream>>>(N16, A16f, partials);
        mean_kernel<<<1, 256, 0, stream>>>(partials, scal);
        abar8_frag_kernel<<<4096, 256, 0, stream>>>(A16f, Ab8, scal);
        if (!fused) {
            run_iters(Ab8, lvl, 1);
        }
    }

    // embeddings branch
    norm512_kernel<<<4096, 256, 0, stream>>>(embedds, N16);
    {
        uchar* Ab8 = A8 + (fused ? (size_t)4 * 16777216 : 0);
        a_gemm_core<512><<<1024, 256, 0, stream>>>(N16, A16f, partials);
        mean_kernel<<<1, 256, 0, stream>>>(partials, scal);
        abar8_frag_kernel<<<4096, 256, 0, stream>>>(A16f, Ab8, scal);
        if (!fused) run_iters(Ab8, 4, 1);
    }

    if (fused) run_iters(A8, 0, 5);
    do_mlp();

    final_kernel<<<16, 256, 0, stream>>>(H2, w3, b3, ytacc, out);
}

// Round 9
// 940.368 us; speedup vs baseline: 1.9323x; 1.1014x over previous
//
#include <hip/hip_runtime.h>
#include <hip/hip_fp16.h>

typedef _Float16 f16x8 __attribute__((ext_vector_type(8)));
typedef float f32x4 __attribute__((ext_vector_type(4)));
typedef unsigned char uchar;

static __device__ __forceinline__ long long mk64(unsigned lo, unsigned hi)
{
    return (long long)(((unsigned long long)hi << 32) | (unsigned long long)lo);
}

// fragment-layout offset for X8 (B-operand): class c, row j
static __device__ __forceinline__ int xfrag_off(int c, int j)
{
    return (j >> 6) * 1024 + (((j >> 3) & 3) * 16 + c) * 16 + ((j >> 5) & 1) * 8 + (j & 7);
}

// fragment-layout offset (halves) for Xs16f (A-operand): row (0..4095), k (0..319)
static __device__ __forceinline__ int xsfrag_off(int row, int k)
{
    return (row >> 4) * 5120 + (k >> 5) * 512 + (((k >> 3) & 3) * 16 + (row & 15)) * 8 + (k & 7);
}

// ---------------------------------------------------------------------------
// Pool: mean over spatial (S2 elements) per (b, ch)
// ---------------------------------------------------------------------------
template <int S2>
__global__ __launch_bounds__(256) void pool_kernel(const float* __restrict__ feat,
                                                   float* __restrict__ pooled, int total)
{
    int idx = blockIdx.x * 256 + threadIdx.x;
    if (idx >= total) return;
    const float4* p4 = (const float4*)(feat + (size_t)idx * S2);
    float s = 0.f;
#pragma unroll
    for (int i = 0; i < S2 / 4; ++i) {
        float4 v = p4[i];
        s += v.x + v.y + v.z + v.w;
    }
    pooled[idx] = s * (1.0f / S2);
}

// ---------------------------------------------------------------------------
// LS: emb = relu(pooled @ w + b), row-normalize -> fp16 N16 [4096,128]
// ---------------------------------------------------------------------------
__global__ __launch_bounds__(128) void ls_norm_kernel(const float* __restrict__ pooled,
                                                      const float* __restrict__ w,
                                                      const float* __restrict__ bias,
                                                      __half* __restrict__ n16, int K)
{
    __shared__ float pl[512];
    __shared__ float red2[2];
    const int b = blockIdx.x, t = threadIdx.x;
    for (int k = t; k < K; k += 128) pl[k] = pooled[(size_t)b * K + k];
    __syncthreads();
    float acc = bias[t];
    for (int k = 0; k < K; ++k) acc = fmaf(pl[k], w[(size_t)k * 128 + t], acc);
    float v = fmaxf(acc, 0.f);
    float ss = v * v;
    for (int off = 32; off > 0; off >>= 1) ss += __shfl_down(ss, off, 64);
    if ((t & 63) == 0) red2[t >> 6] = ss;
    __syncthreads();
    float inv = 1.0f / fmaxf(sqrtf(red2[0] + red2[1]), 1e-12f);
    n16[(size_t)b * 128 + t] = __float2half(v * inv);
}

// ---------------------------------------------------------------------------
// Normalize embedds rows (d=512) -> fp16 N16 [4096,512]
// ---------------------------------------------------------------------------
__global__ __launch_bounds__(256) void norm512_kernel(const float* __restrict__ E,
                                                      __half* __restrict__ n16)
{
    __shared__ float red4[4];
    const int b = blockIdx.x, t = threadIdx.x;
    float2 v = *(const float2*)(E + (size_t)b * 512 + t * 2);
    float ss = v.x * v.x + v.y * v.y;
    for (int off = 32; off > 0; off >>= 1) ss += __shfl_down(ss, off, 64);
    if ((t & 63) == 0) red4[t >> 6] = ss;
    __syncthreads();
    float inv = 1.0f / fmaxf(sqrtf(red4[0] + red4[1] + red4[2] + red4[3]), 1e-12f);
    __half2 o;
    o.x = __float2half(v.x * inv);
    o.y = __float2half(v.y * inv);
    *(__half2*)(n16 + (size_t)b * 512 + t * 2) = o;
}

// ---------------------------------------------------------------------------
// Single-pass MFMA GEMM. 128x128 tile, BK=64, 4 waves 2x2.
// Writes fp16 C = clamp(nnT,0,1) w/ diag=0 in FRAGMENT-MAJOR order (32 MB,
// coalesced via LDS transpose) + fp32 per-block partial sums for mean.
// ---------------------------------------------------------------------------
template <int K>
__global__ __launch_bounds__(256) void a_gemm_core(const __half* __restrict__ N16,
                                                   __half* __restrict__ A16f,
                                                   float* __restrict__ partials)
{
    __shared__ __half smem[16384];   // As(8192) | Bs(8192); reused as Cst(16384)
    __shared__ float reds[4];
    __half* As = smem;
    __half* Bs = smem + 8192;
    char* Cb = (char*)smem;          // Cst: 128 rows x 256 bytes, XOR-swizzled
    const int t = threadIdx.x;
    const int lane = t & 63, wave = t >> 6;
    const int bx = blockIdx.x & 31, by = blockIdx.x >> 5;
    const int wr = wave >> 1, wc = wave & 1;
    const int fr = lane & 15;
    const int g = lane >> 4;
    const int r0 = by * 128, c0 = bx * 128;
    const int sr = t >> 3;   // staging row within 32-row group
    const int sc = t & 7;    // staging 16B-chunk 0..7

    f32x4 acc[4][4];
#pragma unroll
    for (int i = 0; i < 4; ++i)
#pragma unroll
        for (int j = 0; j < 4; ++j) acc[i][j] = (f32x4){0.f, 0.f, 0.f, 0.f};

    for (int kt = 0; kt < K / 64; ++kt) {
        const int kb = kt * 64;
        __syncthreads();
#pragma unroll
        for (int pp = 0; pp < 4; ++pp) {
            const int r = pp * 32 + sr;
            uint4 va = *(const uint4*)(N16 + (size_t)(r0 + r) * K + kb + sc * 8);
            uint4 vb = *(const uint4*)(N16 + (size_t)(c0 + r) * K + kb + sc * 8);
            const int d = r * 64 + ((((sc * 16) ^ ((r & 7) << 4))) >> 1);
            *(uint4*)&As[d] = va;
            *(uint4*)&Bs[d] = vb;
        }
        __syncthreads();
#pragma unroll
        for (int ks = 0; ks < 2; ++ks) {
            const int ko = ((ks * 64 + g * 16) ^ ((fr & 7) << 4)) >> 1;
            f16x8 af[4], bf[4];
#pragma unroll
            for (int i = 0; i < 4; ++i) {
                af[i] = *(const f16x8*)&As[(wr * 64 + i * 16 + fr) * 64 + ko];
                bf[i] = *(const f16x8*)&Bs[(wc * 64 + i * 16 + fr) * 64 + ko];
            }
#pragma unroll
            for (int i = 0; i < 4; ++i)
#pragma unroll
                for (int j = 0; j < 4; ++j)
                    acc[i][j] = __builtin_amdgcn_mfma_f32_16x16x32_f16(af[i], bf[j], acc[i][j], 0, 0, 0);
        }
    }
    __syncthreads();

    // epilogue: clamp, zero diag, sum, stage fp16 into swizzled Cst
    float lsum = 0.f;
    const int r4 = g * 4;
#pragma unroll
    for (int i = 0; i < 4; ++i) {
#pragma unroll
        for (int q = 0; q < 4; ++q) {
            const int lr = wr * 64 + i * 16 + r4 + q;
            const int row = r0 + lr;
#pragma unroll
            for (int j = 0; j < 4; ++j) {
                const int lc = wc * 64 + j * 16 + fr;
                const int col = c0 + lc;
                float v = fminf(fmaxf(acc[i][j][q], 0.f), 1.f);
                if (row == col) v = 0.f;
                lsum += v;
                *(__half*)(Cb + lr * 256 + ((lc * 2) ^ ((lr & 7) << 4))) = __float2half(v);
            }
        }
    }
    __syncthreads();

    // fragment-major coalesced store: 4 passes x 256 threads x 32B = 32 KB
#pragma unroll
    for (int pp = 0; pp < 4; ++pp) {
        const int rbl2 = pp * 4 + (t >> 6);
        const int rbl = rbl2 >> 1, ks2l = rbl2 & 1;
        const int l = t & 63;
        const int lr = rbl * 16 + (l & 15);
        const int e0 = ks2l * 64 + (l >> 4) * 8;
        uint4 v0 = *(const uint4*)(Cb + lr * 256 + ((e0 * 2) ^ ((lr & 7) << 4)));
        uint4 v1 = *(const uint4*)(Cb + lr * 256 + (((e0 + 32) * 2) ^ ((lr & 7) << 4)));
        const size_t rb = (size_t)(by * 8 + rbl);
        const size_t ks2 = (size_t)(bx * 2 + ks2l);
        char* dst = (char*)A16f + rb * 131072 + ks2 * 2048 + l * 32;
        *(uint4*)dst = v0;
        *(uint4*)(dst + 16) = v1;
    }

    for (int off = 32; off > 0; off >>= 1) lsum += __shfl_down(lsum, off, 64);
    if (lane == 0) reds[wave] = lsum;
    __syncthreads();
    if (t == 0) partials[blockIdx.x] = reds[0] + reds[1] + reds[2] + reds[3];
}

// ---------------------------------------------------------------------------
// mean of A from per-block partials
// ---------------------------------------------------------------------------
__global__ __launch_bounds__(256) void mean_kernel(const float* __restrict__ partials,
                                                   float* __restrict__ scal)
{
    __shared__ float red[4];
    const int t = threadIdx.x;
    float s = 0.f;
    for (int i = t; i < 1024; i += 256) s += partials[i];
    for (int off = 32; off > 0; off >>= 1) s += __shfl_down(s, off, 64);
    if ((t & 63) == 0) red[t >> 6] = s;
    __syncthreads();
    if (t == 0) scal[0] = (red[0] + red[1] + red[2] + red[3]) * (1.0f / 16777216.0f);
}

// ---------------------------------------------------------------------------
// Elementwise: A8[i] = fp8( a16[i] < mean ? 0 : a16[i] ) on linear frag order.
// ---------------------------------------------------------------------------
__global__ __launch_bounds__(256) void abar8_frag_kernel(const __half* __restrict__ A16f,
                                                         uchar* __restrict__ A8,
                                                         const float* __restrict__ scal)
{
    const float mean = scal[0];
    const size_t i = ((size_t)blockIdx.x * 256 + threadIdx.x) * 16;
    uint4 u0 = *(const uint4*)(A16f + i);
    uint4 u1 = *(const uint4*)(A16f + i + 8);
    __half h[16];
    *(uint4*)h = u0;
    *(uint4*)(h + 8) = u1;
    float v[16];
#pragma unroll
    for (int k = 0; k < 16; ++k) {
        float a = __half2float(h[k]);
        v[k] = (a < mean) ? 0.f : a;
    }
    unsigned w0 = __builtin_amdgcn_cvt_pk_fp8_f32(v[0], v[1], 0, false);
    w0 = __builtin_amdgcn_cvt_pk_fp8_f32(v[2], v[3], (int)w0, true);
    unsigned w1 = __builtin_amdgcn_cvt_pk_fp8_f32(v[4], v[5], 0, false);
    w1 = __builtin_amdgcn_cvt_pk_fp8_f32(v[6], v[7], (int)w1, true);
    unsigned w2 = __builtin_amdgcn_cvt_pk_fp8_f32(v[8], v[9], 0, false);
    w2 = __builtin_amdgcn_cvt_pk_fp8_f32(v[10], v[11], (int)w2, true);
    unsigned w3 = __builtin_amdgcn_cvt_pk_fp8_f32(v[12], v[13], 0, false);
    w3 = __builtin_amdgcn_cvt_pk_fp8_f32(v[14], v[15], (int)w3, true);
    uint4 o; o.x = w0; o.y = w1; o.z = w2; o.w = w3;
    *(uint4*)(A8 + i) = o;
}

// ---------------------------------------------------------------------------
// Scol[0][p][c] = #{labels[0..2047]==c} + 204.8 ; rest zeroed by memset
// ---------------------------------------------------------------------------
__global__ __launch_bounds__(256) void scol0_kernel(const int* __restrict__ labels,
                                                    float* __restrict__ Scol)
{
    __shared__ int hist[16];
    const int t = threadIdx.x;
    if (t < 16) hist[t] = 0;
    __syncthreads();
    for (int i = t; i < 2048; i += 256) atomicAdd(&hist[labels[i]], 1);
    __syncthreads();
    if (t < 80) {
        const int p = t >> 4, c = t & 15;
        Scol[p * 16 + c] = (c < 10) ? ((float)hist[c] + 204.8f) : 0.f;
    }
}

// ---------------------------------------------------------------------------
// X0 init (X8 in fragment layout)
// ---------------------------------------------------------------------------
__global__ __launch_bounds__(256) void init_kernel(const int* __restrict__ labels,
                                                   uchar* __restrict__ X8_0,
                                                   uchar* __restrict__ X8_1,
                                                   float* __restrict__ X32)
{
    const int idx = blockIdx.x * 256 + threadIdx.x;   // 5*16*4096 = 327680
    const int p = idx >> 16;
    const int rem = idx & 65535;
    const int c = rem >> 12, j = rem & 4095;
    float v;
    if (c >= 10) v = 0.f;
    else if (j < 2048) v = (labels[j] == c) ? 1.0f : 0.0f;
    else v = 0.1f;
    unsigned pk = __builtin_amdgcn_cvt_pk_fp8_f32(v, v, 0, false);
    X8_0[(size_t)p * 65536 + xfrag_off(c, j)] = (uchar)(pk & 0xff);
    if (c >= 10) X8_1[(size_t)p * 65536 + xfrag_off(c, j)] = 0;
    if (c < 10) X32[((size_t)p * 4096 + j) * 10 + c] = v;
}

// ---------------------------------------------------------------------------
// Pack w1 (300x150) and w2 (150x75) into fragment-major fp16 B-operand form.
// W1f: [10 ks][10 nf][512], K pad 320, N pad 160.
// W2f: [5 ks][5 nf][512],  K pad 160, N pad 80.
// ---------------------------------------------------------------------------
__global__ __launch_bounds__(256) void wfrag_kernel(const float* __restrict__ w1,
                                                    const float* __restrict__ w2,
                                                    __half* __restrict__ W1f,
                                                    __half* __restrict__ W2f)
{
    int idx = blockIdx.x * 256 + threadIdx.x;   // 51200 + 12800 = 64000
    if (idx < 51200) {
        const int frag = idx >> 9, e9 = idx & 511;
        const int s = frag / 10, j = frag % 10;
        const int g = e9 >> 7, fr = (e9 >> 3) & 15, e = e9 & 7;
        const int k = s * 32 + g * 8 + e, n = j * 16 + fr;
        const float v = (k < 300 && n < 150) ? w1[(size_t)k * 150 + n] : 0.f;
        W1f[idx] = __float2half(v);
    } else if (idx < 64000) {
        const int i2 = idx - 51200;
        const int frag = i2 >> 9, e9 = i2 & 511;
        const int s = frag / 5, j = frag % 5;
        const int g = e9 >> 7, fr = (e9 >> 3) & 15, e = e9 & 7;
        const int k = s * 32 + g * 8 + e, n = j * 16 + fr;
        const float v = (k < 150 && n < 75) ? w2[(size_t)k * 75 + n] : 0.f;
        W2f[i2] = __float2half(v);
    }
}

// ---------------------------------------------------------------------------
// One GTG iteration via fp8 MFMA, fragment-ordered operands, NO LDS staging.
// Xs trajectory written as fp16 fragments (Xs16f) for the MFMA MLP.
// ---------------------------------------------------------------------------
__global__ __launch_bounds__(256, 4) void gtg8_kernel(
    const uchar* __restrict__ A8f,
    const uchar* __restrict__ X8i, uchar* __restrict__ X8o,
    const float* __restrict__ X32i, float* __restrict__ X32o,
    __half* __restrict__ Xs16f, float* __restrict__ ytacc,
    float* __restrict__ Scol, int it, int pbase)
{
    __shared__ float yred[4][256];
    const int t = threadIdx.x;
    const int lane = t & 63, wave = t >> 6;
    const int p = pbase + (blockIdx.x >> 8);
    const int pl = p - pbase;
    const int rb = blockIdx.x & 255;

    const uchar* Ab = A8f + (size_t)pl * 16777216 + (size_t)rb * 65536
                    + wave * 16384 + lane * 16;
    const uchar* Xb = X8i + (size_t)p * 65536 + wave * 16384 + lane * 16;

    f32x4 acc0 = {0.f, 0.f, 0.f, 0.f};
    f32x4 acc1 = {0.f, 0.f, 0.f, 0.f};
#pragma unroll
    for (int u = 0; u < 16; ++u) {
        uint4 av = *(const uint4*)(Ab + u * 1024);
        uint4 bv = *(const uint4*)(Xb + u * 1024);
        long long a0 = mk64(av.x, av.y), a1 = mk64(av.z, av.w);
        long long b0 = mk64(bv.x, bv.y), b1 = mk64(bv.z, bv.w);
        acc0 = __builtin_amdgcn_mfma_f32_16x16x32_fp8_fp8(a0, b0, acc0, 0, 0, 0);
        acc1 = __builtin_amdgcn_mfma_f32_16x16x32_fp8_fp8(a1, b1, acc1, 0, 0, 0);
    }
    {
        const int r4 = (lane >> 4) * 4;
        const int fr = lane & 15;
#pragma unroll
        for (int q = 0; q < 4; ++q)
            yred[wave][(r4 + q) * 16 + fr] = acc0[q] + acc1[q];
    }
    __syncthreads();

    // ---- update phase: thread t -> row r=t>>4, class c=t&15
    const int r = t >> 4, c = t & 15;
    const int row = rb * 16 + r;
    const float T = yred[0][t] + yred[1][t] + yred[2][t] + yred[3][t];
    const float y = Scol[it * 80 + pl * 16 + c] - T;
    const float x = (c < 10) ? X32i[((size_t)p * 4096 + row) * 10 + c] : 0.f;
    const float m = x * y;
    float s = m;
    s += __shfl_xor(s, 1, 16);
    s += __shfl_xor(s, 2, 16);
    s += __shfl_xor(s, 4, 16);
    s += __shfl_xor(s, 8, 16);
    const float dv = m / (s + 1e-8f);
    const float xn = x + dv;
    if (c < 10) {
        X32o[((size_t)p * 4096 + row) * 10 + c] = xn;
        unsigned pk = __builtin_amdgcn_cvt_pk_fp8_f32(xn, xn, 0, false);
        X8o[(size_t)p * 65536 + xfrag_off(c, row)] = (uchar)(pk & 0xff);
        if (p < 4) {
            const int k = c * 30 + it;
            Xs16f[(size_t)p * 1310720 + xsfrag_off(row, k)] = __float2half(xn);
        }
    }
    if (p == 4) {
        float e = (c < 10) ? (-dv * logf(dv + 1e-8f)) : 0.f;
        e += __shfl_xor(e, 1, 16);
        e += __shfl_xor(e, 2, 16);
        e += __shfl_xor(e, 4, 16);
        e += __shfl_xor(e, 8, 16);
        if (c == 0) {
            float prev = (it == 0) ? 0.f : ytacc[row];
            ytacc[row] = prev + e;
        }
    }

    // ---- colsum for next iteration
    __syncthreads();
    yred[0][t] = (c < 10) ? xn : 0.f;
    __syncthreads();
    if (t < 10) {
        float sc = 0.f;
#pragma unroll
        for (int rr = 0; rr < 16; ++rr) sc += yred[0][t + rr * 16];
        atomicAdd(&Scol[(it + 1) * 80 + pl * 16 + t], sc);
    }
}

// ---------------------------------------------------------------------------
// MFMA MLP (layers 1+2, all levels). 256 blocks x 4 waves; wave owns one
// 16-row block. L1: 10k x 10n MFMAs; h1 via per-wave swizzled LDS; L2: 5x5.
// ---------------------------------------------------------------------------
__global__ __launch_bounds__(256) void mlp_mfma_kernel(const __half* __restrict__ Xs16f,
                                                       const __half* __restrict__ W1f,
                                                       const __half* __restrict__ W2f,
                                                       const float* __restrict__ b1,
                                                       const float* __restrict__ b2,
                                                       float* __restrict__ H2)
{
    __shared__ char h1s[4][16 * 384];   // per-wave h1 [16 rows][192 halves], swizzled
    __shared__ float b1s[160];
    __shared__ float b2s[80];
    const int t = threadIdx.x;
    const int lane = t & 63, wave = t >> 6;
    const int fr = lane & 15, g = lane >> 4;
    const int lvl = blockIdx.x >> 6;
    const int rb = (blockIdx.x & 63) * 4 + wave;

    if (t < 160) b1s[t] = (t < 150) ? b1[t] : 0.f;
    else if (t < 240) b2s[t - 160] = (t < 235) ? b2[t - 160] : 0.f;
    __syncthreads();

    // ---- layer 1: [16 x 320] @ [320 x 160]
    const __half* Abase = Xs16f + (size_t)lvl * 1310720 + (size_t)rb * 5120;
    f32x4 acc1[10];
#pragma unroll
    for (int j = 0; j < 10; ++j) acc1[j] = (f32x4){0.f, 0.f, 0.f, 0.f};
#pragma unroll
    for (int s = 0; s < 10; ++s) {
        f16x8 a = *(const f16x8*)(Abase + s * 512 + lane * 8);
#pragma unroll
        for (int j = 0; j < 10; ++j) {
            f16x8 b = *(const f16x8*)(W1f + (s * 10 + j) * 512 + lane * 8);
            acc1[j] = __builtin_amdgcn_mfma_f32_16x16x32_f16(a, b, acc1[j], 0, 0, 0);
        }
    }
    // bias + relu -> h1s (swizzled 2B writes)
    char* hw = h1s[wave];
#pragma unroll
    for (int j = 0; j < 10; ++j) {
#pragma unroll
        for (int q = 0; q < 4; ++q) {
            const int row = g * 4 + q;
            const int col = j * 16 + fr;
            float v = fmaxf(acc1[j][q] + b1s[col], 0.f);
            *(__half*)(hw + row * 384 + ((col * 2) ^ ((row & 7) << 4))) = __float2half(v);
        }
    }
    __syncthreads();

    // ---- layer 2: [16 x 160] @ [160 x 80]
    f32x4 acc2[5];
#pragma unroll
    for (int j = 0; j < 5; ++j) acc2[j] = (f32x4){0.f, 0.f, 0.f, 0.f};
#pragma unroll
    for (int s = 0; s < 5; ++s) {
        f16x8 a = *(const f16x8*)(hw + fr * 384 + ((s * 64 + g * 16) ^ ((fr & 7) << 4)));
#pragma unroll
        for (int j = 0; j < 5; ++j) {
            f16x8 b = *(const f16x8*)(W2f + (s * 5 + j) * 512 + lane * 8);
            acc2[j] = __builtin_amdgcn_mfma_f32_16x16x32_f16(a, b, acc2[j], 0, 0, 0);
        }
    }
    // bias + relu -> H2 (cols < 75)
#pragma unroll
    for (int j = 0; j < 5; ++j) {
        const int col = j * 16 + fr;
        if (col < 75) {
#pragma unroll
            for (int q = 0; q < 4; ++q) {
                const int row = rb * 16 + g * 4 + q;
                float v = fmaxf(acc2[j][q] + b2s[col], 0.f);
                H2[(size_t)row * 300 + lvl * 75 + col] = v;
            }
        }
    }
}

// ---------------------------------------------------------------------------
// Final: y_pred = H2 @ w3 + b3; y_true = ytacc/30; labelled_mask
// ---------------------------------------------------------------------------
__global__ __launch_bounds__(256) void final_kernel(const float* __restrict__ H2,
                                                    const float* __restrict__ w3,
                                                    const float* __restrict__ b3,
                                                    const float* __restrict__ ytacc,
                                                    float* __restrict__ out)
{
    __shared__ float w[300];
    const int t = threadIdx.x;
    const int b = blockIdx.x * 256 + t;
    for (int i = t; i < 300; i += 256) w[i] = w3[i];
    __syncthreads();
    float acc = b3[0];
    const float4* row = (const float4*)(H2 + (size_t)b * 300);
    for (int k4 = 0; k4 < 75; ++k4) {
        float4 v = row[k4];
        acc += v.x * w[k4 * 4] + v.y * w[k4 * 4 + 1] + v.z * w[k4 * 4 + 2] + v.w * w[k4 * 4 + 3];
    }
    out[b] = acc;
    out[4096 + b] = ytacc[b] * (1.0f / 30.0f);
    out[2 * 4096 + b] = (b < 2048) ? 1.0f : 0.0f;
}

// ---------------------------------------------------------------------------
extern "C" void kernel_launch(void* const* d_in, const int* in_sizes, int n_in,
                              void* d_out, int out_size, void* d_ws, size_t ws_size,
                              hipStream_t stream)
{
    (void)in_sizes; (void)n_in; (void)out_size;

    const float* feats[4] = {(const float*)d_in[0], (const float*)d_in[1],
                             (const float*)d_in[2], (const float*)d_in[3]};
    const float* embedds = (const float*)d_in[4];
    const int* labels = (const int*)d_in[6];
    const float* lsw[4] = {(const float*)d_in[7], (const float*)d_in[9],
                           (const float*)d_in[11], (const float*)d_in[13]};
    const float* lsb[4] = {(const float*)d_in[8], (const float*)d_in[10],
                           (const float*)d_in[12], (const float*)d_in[14]};
    const float* w1 = (const float*)d_in[15];
    const float* b1 = (const float*)d_in[16];
    const float* w2 = (const float*)d_in[17];
    const float* b2 = (const float*)d_in[18];
    const float* w3 = (const float*)d_in[19];
    const float* b3 = (const float*)d_in[20];

    // fused path: 5 fp8 A' matrices resident (5*16MB) + 32MB A16f; else 1 A8
    const bool fused = ws_size >= 156930304ULL;
    const size_t A8_BYTES = fused ? 83886080ULL : 16777216ULL;

    char* ws = (char*)d_ws;
    uchar* A8       = (uchar*)(ws);
    __half* A16f    = (__half*)(ws + A8_BYTES);       // 33554432 (scratch)
    char* base      = ws + A8_BYTES + 33554432;
    float* pooled   = (float*)(base);                 //  8388608
    __half* N16     = (__half*)(base + 8388608);      //  4194304
    uchar* Xt8      = (uchar*)(base + 12582912);      //  2 x 327680
    float* X32      = (float*)(base + 13238272);      //  2 x 819200
    __half* Xs16f   = (__half*)(base + 14876672);     //  10485760 (4 levels frag)
    float* H2       = (float*)(base + 25362432);      //  4915200
    float* ytacc    = (float*)(base + 30277632);      //  16384
    float* partials = (float*)(base + 30294016);      //  4096
    float* scal     = (float*)(base + 30298112);      //  256
    float* Scol     = (float*)(base + 30298368);      //  16384 (31 x 5 x 16 fp32)
    __half* W1f     = (__half*)(base + 30314752);     //  102400
    __half* W2f     = (__half*)(base + 30417152);     //  25600

    uchar* Xt8b[2] = {Xt8, Xt8 + 327680};
    float* X32b[2] = {X32, X32 + 204800};
    float* out = (float*)d_out;

    const int Cs[4] = {64, 128, 256, 512};
    const int S2s[4] = {64, 64, 16, 16};

    auto run_iters = [&](const uchar* Ab8, int pbase, int nprob) {
        hipMemsetAsync(Scol, 0, 31 * 80 * sizeof(float), stream);
        if (pbase == 0) hipMemsetAsync(Xs16f, 0, 10485760, stream);
        scol0_kernel<<<1, 256, 0, stream>>>(labels, Scol);
        init_kernel<<<1280, 256, 0, stream>>>(labels, Xt8b[0], Xt8b[1], X32b[0]);
        for (int it = 0; it < 30; ++it) {
            const int i = it & 1, o = i ^ 1;
            gtg8_kernel<<<nprob * 256, 256, 0, stream>>>(
                Ab8, Xt8b[i], Xt8b[o], X32b[i], X32b[o], Xs16f, ytacc, Scol, it, pbase);
        }
    };

    wfrag_kernel<<<250, 256, 0, stream>>>(w1, w2, W1f, W2f);

    for (int lvl = 0; lvl < 4; ++lvl) {
        const int c = Cs[lvl];
        const int total = 4096 * c;
        if (S2s[lvl] == 64)
            pool_kernel<64><<<total / 256, 256, 0, stream>>>(feats[lvl], pooled, total);
        else
            pool_kernel<16><<<total / 256, 256, 0, stream>>>(feats[lvl], pooled, total);
        ls_norm_kernel<<<4096, 128, 0, stream>>>(pooled, lsw[lvl], lsb[lvl], N16, c);
        uchar* Ab8 = A8 + (fused ? (size_t)lvl * 16777216 : 0);
        a_gemm_core<128><<<1024, 256, 0, stream>>>(N16, A16f, partials);
        mean_kernel<<<1, 256, 0, stream>>>(partials, scal);
        abar8_frag_kernel<<<4096, 256, 0, stream>>>(A16f, Ab8, scal);
        if (!fused) {
            run_iters(Ab8, lvl, 1);
        }
    }

    // embeddings branch
    norm512_kernel<<<4096, 256, 0, stream>>>(embedds, N16);
    {
        uchar* Ab8 = A8 + (fused ? (size_t)4 * 16777216 : 0);
        a_gemm_core<512><<<1024, 256, 0, stream>>>(N16, A16f, partials);
        mean_kernel<<<1, 256, 0, stream>>>(partials, scal);
        abar8_frag_kernel<<<4096, 256, 0, stream>>>(A16f, Ab8, scal);
        if (!fused) run_iters(Ab8, 4, 1);
    }

    if (fused) run_iters(A8, 0, 5);
    mlp_mfma_kernel<<<256, 256, 0, stream>>>(Xs16f, W1f, W2f, b1, b2, H2);

    final_kernel<<<16, 256, 0, stream>>>(H2, w3, b3, ytacc, out);
}

// Round 10
// 824.738 us; speedup vs baseline: 2.2032x; 1.1402x over previous
//
#include <hip/hip_runtime.h>
#include <hip/hip_fp16.h>

typedef _Float16 f16x8 __attribute__((ext_vector_type(8)));
typedef float f32x4 __attribute__((ext_vector_type(4)));
typedef unsigned char uchar;

static __device__ __forceinline__ long long mk64(unsigned lo, unsigned hi)
{
    return (long long)(((unsigned long long)hi << 32) | (unsigned long long)lo);
}

// fragment-layout offset for X8 (B-operand): class c, row j
static __device__ __forceinline__ int xfrag_off(int c, int j)
{
    return (j >> 6) * 1024 + (((j >> 3) & 3) * 16 + c) * 16 + ((j >> 5) & 1) * 8 + (j & 7);
}

// fragment-layout offset (halves) for Xs16f (A-operand): row (0..4095), k (0..319)
static __device__ __forceinline__ int xsfrag_off(int row, int k)
{
    return (row >> 4) * 5120 + (k >> 5) * 512 + (((k >> 3) & 3) * 16 + (row & 15)) * 8 + (k & 7);
}

// nibble codes -> fp8 e4m3 bytes of k/16 (exact): LUT via v_perm
// T[0..15] = 0x00,0x18,0x20,0x24,0x28,0x2A,0x2C,0x2E,0x30,0x31,...,0x37
#define T03 0x24201800u
#define T47 0x2E2C2A28u
#define T8B 0x33323130u
#define TCF 0x37363534u

// expand 8 nibbles (one dword) -> 8 fp8 bytes (two dwords)
static __device__ __forceinline__ void expand4(unsigned w, unsigned& o0, unsigned& o1)
{
    unsigned even = w & 0x0F0F0F0Fu;           // c0,c2,c4,c6
    unsigned odd  = (w >> 4) & 0x0F0F0F0Fu;    // c1,c3,c5,c7
    unsigned i_lo = __builtin_amdgcn_perm(odd, even, 0x05010400u);  // c0,c1,c2,c3
    unsigned i_hi = __builtin_amdgcn_perm(odd, even, 0x07030602u);  // c4,c5,c6,c7
    {
        unsigned i3 = i_lo & 0x07070707u;
        unsigned ta = __builtin_amdgcn_perm(T47, T03, i3);
        unsigned tb = __builtin_amdgcn_perm(TCF, T8B, i3);
        unsigned m  = ((i_lo >> 3) & 0x01010101u) * 0xFFu;
        o0 = ta ^ ((ta ^ tb) & m);
    }
    {
        unsigned i3 = i_hi & 0x07070707u;
        unsigned ta = __builtin_amdgcn_perm(T47, T03, i3);
        unsigned tb = __builtin_amdgcn_perm(TCF, T8B, i3);
        unsigned m  = ((i_hi >> 3) & 0x01010101u) * 0xFFu;
        o1 = ta ^ ((ta ^ tb) & m);
    }
}

// ---------------------------------------------------------------------------
// Pool: mean over spatial (S2 elements) per (b, ch)
// ---------------------------------------------------------------------------
template <int S2>
__global__ __launch_bounds__(256) void pool_kernel(const float* __restrict__ feat,
                                                   float* __restrict__ pooled, int total)
{
    int idx = blockIdx.x * 256 + threadIdx.x;
    if (idx >= total) return;
    const float4* p4 = (const float4*)(feat + (size_t)idx * S2);
    float s = 0.f;
#pragma unroll
    for (int i = 0; i < S2 / 4; ++i) {
        float4 v = p4[i];
        s += v.x + v.y + v.z + v.w;
    }
    pooled[idx] = s * (1.0f / S2);
}

// ---------------------------------------------------------------------------
// LS: emb = relu(pooled @ w + b), row-normalize -> fp16 N16 [4096,128]
// ---------------------------------------------------------------------------
__global__ __launch_bounds__(128) void ls_norm_kernel(const float* __restrict__ pooled,
                                                      const float* __restrict__ w,
                                                      const float* __restrict__ bias,
                                                      __half* __restrict__ n16, int K)
{
    __shared__ float pl[512];
    __shared__ float red2[2];
    const int b = blockIdx.x, t = threadIdx.x;
    for (int k = t; k < K; k += 128) pl[k] = pooled[(size_t)b * K + k];
    __syncthreads();
    float acc = bias[t];
    for (int k = 0; k < K; ++k) acc = fmaf(pl[k], w[(size_t)k * 128 + t], acc);
    float v = fmaxf(acc, 0.f);
    float ss = v * v;
    for (int off = 32; off > 0; off >>= 1) ss += __shfl_down(ss, off, 64);
    if ((t & 63) == 0) red2[t >> 6] = ss;
    __syncthreads();
    float inv = 1.0f / fmaxf(sqrtf(red2[0] + red2[1]), 1e-12f);
    n16[(size_t)b * 128 + t] = __float2half(v * inv);
}

// ---------------------------------------------------------------------------
// Normalize embedds rows (d=512) -> fp16 N16 [4096,512]
// ---------------------------------------------------------------------------
__global__ __launch_bounds__(256) void norm512_kernel(const float* __restrict__ E,
                                                      __half* __restrict__ n16)
{
    __shared__ float red4[4];
    const int b = blockIdx.x, t = threadIdx.x;
    float2 v = *(const float2*)(E + (size_t)b * 512 + t * 2);
    float ss = v.x * v.x + v.y * v.y;
    for (int off = 32; off > 0; off >>= 1) ss += __shfl_down(ss, off, 64);
    if ((t & 63) == 0) red4[t >> 6] = ss;
    __syncthreads();
    float inv = 1.0f / fmaxf(sqrtf(red4[0] + red4[1] + red4[2] + red4[3]), 1e-12f);
    __half2 o;
    o.x = __float2half(v.x * inv);
    o.y = __float2half(v.y * inv);
    *(__half2*)(n16 + (size_t)b * 512 + t * 2) = o;
}

// ---------------------------------------------------------------------------
// Single-pass MFMA GEMM. 128x128 tile, BK=64, 4 waves 2x2.
// Writes fp16 C = clamp(nnT,0,1) w/ diag=0 in FRAGMENT-MAJOR order (32 MB,
// coalesced via LDS transpose) + fp32 per-block partial sums for mean.
// ---------------------------------------------------------------------------
template <int K>
__global__ __launch_bounds__(256) void a_gemm_core(const __half* __restrict__ N16,
                                                   __half* __restrict__ A16f,
                                                   float* __restrict__ partials)
{
    __shared__ __half smem[16384];   // As(8192) | Bs(8192); reused as Cst(16384)
    __shared__ float reds[4];
    __half* As = smem;
    __half* Bs = smem + 8192;
    char* Cb = (char*)smem;          // Cst: 128 rows x 256 bytes, XOR-swizzled
    const int t = threadIdx.x;
    const int lane = t & 63, wave = t >> 6;
    const int bx = blockIdx.x & 31, by = blockIdx.x >> 5;
    const int wr = wave >> 1, wc = wave & 1;
    const int fr = lane & 15;
    const int g = lane >> 4;
    const int r0 = by * 128, c0 = bx * 128;
    const int sr = t >> 3;   // staging row within 32-row group
    const int sc = t & 7;    // staging 16B-chunk 0..7

    f32x4 acc[4][4];
#pragma unroll
    for (int i = 0; i < 4; ++i)
#pragma unroll
        for (int j = 0; j < 4; ++j) acc[i][j] = (f32x4){0.f, 0.f, 0.f, 0.f};

    for (int kt = 0; kt < K / 64; ++kt) {
        const int kb = kt * 64;
        __syncthreads();
#pragma unroll
        for (int pp = 0; pp < 4; ++pp) {
            const int r = pp * 32 + sr;
            uint4 va = *(const uint4*)(N16 + (size_t)(r0 + r) * K + kb + sc * 8);
            uint4 vb = *(const uint4*)(N16 + (size_t)(c0 + r) * K + kb + sc * 8);
            const int d = r * 64 + ((((sc * 16) ^ ((r & 7) << 4))) >> 1);
            *(uint4*)&As[d] = va;
            *(uint4*)&Bs[d] = vb;
        }
        __syncthreads();
#pragma unroll
        for (int ks = 0; ks < 2; ++ks) {
            const int ko = ((ks * 64 + g * 16) ^ ((fr & 7) << 4)) >> 1;
            f16x8 af[4], bf[4];
#pragma unroll
            for (int i = 0; i < 4; ++i) {
                af[i] = *(const f16x8*)&As[(wr * 64 + i * 16 + fr) * 64 + ko];
                bf[i] = *(const f16x8*)&Bs[(wc * 64 + i * 16 + fr) * 64 + ko];
            }
#pragma unroll
            for (int i = 0; i < 4; ++i)
#pragma unroll
                for (int j = 0; j < 4; ++j)
                    acc[i][j] = __builtin_amdgcn_mfma_f32_16x16x32_f16(af[i], bf[j], acc[i][j], 0, 0, 0);
        }
    }
    __syncthreads();

    // epilogue: clamp, zero diag, sum, stage fp16 into swizzled Cst
    float lsum = 0.f;
    const int r4 = g * 4;
#pragma unroll
    for (int i = 0; i < 4; ++i) {
#pragma unroll
        for (int q = 0; q < 4; ++q) {
            const int lr = wr * 64 + i * 16 + r4 + q;
            const int row = r0 + lr;
#pragma unroll
            for (int j = 0; j < 4; ++j) {
                const int lc = wc * 64 + j * 16 + fr;
                const int col = c0 + lc;
                float v = fminf(fmaxf(acc[i][j][q], 0.f), 1.f);
                if (row == col) v = 0.f;
                lsum += v;
                *(__half*)(Cb + lr * 256 + ((lc * 2) ^ ((lr & 7) << 4))) = __float2half(v);
            }
        }
    }
    __syncthreads();

    // fragment-major coalesced store: 4 passes x 256 threads x 32B = 32 KB
#pragma unroll
    for (int pp = 0; pp < 4; ++pp) {
        const int rbl2 = pp * 4 + (t >> 6);
        const int rbl = rbl2 >> 1, ks2l = rbl2 & 1;
        const int l = t & 63;
        const int lr = rbl * 16 + (l & 15);
        const int e0 = ks2l * 64 + (l >> 4) * 8;
        uint4 v0 = *(const uint4*)(Cb + lr * 256 + ((e0 * 2) ^ ((lr & 7) << 4)));
        uint4 v1 = *(const uint4*)(Cb + lr * 256 + (((e0 + 32) * 2) ^ ((lr & 7) << 4)));
        const size_t rb = (size_t)(by * 8 + rbl);
        const size_t ks2 = (size_t)(bx * 2 + ks2l);
        char* dst = (char*)A16f + rb * 131072 + ks2 * 2048 + l * 32;
        *(uint4*)dst = v0;
        *(uint4*)(dst + 16) = v1;
    }

    for (int off = 32; off > 0; off >>= 1) lsum += __shfl_down(lsum, off, 64);
    if (lane == 0) reds[wave] = lsum;
    __syncthreads();
    if (t == 0) partials[blockIdx.x] = reds[0] + reds[1] + reds[2] + reds[3];
}

// ---------------------------------------------------------------------------
// mean of A from per-block partials
// ---------------------------------------------------------------------------
__global__ __launch_bounds__(256) void mean_kernel(const float* __restrict__ partials,
                                                   float* __restrict__ scal)
{
    __shared__ float red[4];
    const int t = threadIdx.x;
    float s = 0.f;
    for (int i = t; i < 1024; i += 256) s += partials[i];
    for (int off = 32; off > 0; off >>= 1) s += __shfl_down(s, off, 64);
    if ((t & 63) == 0) red[t >> 6] = s;
    __syncthreads();
    if (t == 0) scal[0] = (red[0] + red[1] + red[2] + red[3]) * (1.0f / 16777216.0f);
}

// ---------------------------------------------------------------------------
// Quantize to 4-bit: code = round(16 * (a<mean?0:a)) clamped to 15, on
// linear frag order. 32B fp16 in -> 8B (16 nibbles) out per thread.
// ---------------------------------------------------------------------------
__global__ __launch_bounds__(256) void abar4_frag_kernel(const __half* __restrict__ A16f,
                                                         uchar* __restrict__ A4,
                                                         const float* __restrict__ scal)
{
    const float mean = scal[0];
    const size_t i = ((size_t)blockIdx.x * 256 + threadIdx.x);
    uint4 u0 = *(const uint4*)(A16f + i * 16);
    uint4 u1 = *(const uint4*)(A16f + i * 16 + 8);
    __half h[16];
    *(uint4*)h = u0;
    *(uint4*)(h + 8) = u1;
    unsigned d0 = 0, d1 = 0;
#pragma unroll
    for (int k = 0; k < 8; ++k) {
        float a = __half2float(h[k]);
        float v = (a < mean) ? 0.f : a;
        unsigned n = (unsigned)fminf(v * 16.f + 0.5f, 15.f);
        d0 |= n << (4 * k);
    }
#pragma unroll
    for (int k = 0; k < 8; ++k) {
        float a = __half2float(h[8 + k]);
        float v = (a < mean) ? 0.f : a;
        unsigned n = (unsigned)fminf(v * 16.f + 0.5f, 15.f);
        d1 |= n << (4 * k);
    }
    uint2 o; o.x = d0; o.y = d1;
    *(uint2*)(A4 + i * 8) = o;
}

// ---------------------------------------------------------------------------
// Scol[0][p][c] = #{labels[0..2047]==c} + 204.8 ; rest zeroed by memset
// ---------------------------------------------------------------------------
__global__ __launch_bounds__(256) void scol0_kernel(const int* __restrict__ labels,
                                                    float* __restrict__ Scol)
{
    __shared__ int hist[16];
    const int t = threadIdx.x;
    if (t < 16) hist[t] = 0;
    __syncthreads();
    for (int i = t; i < 2048; i += 256) atomicAdd(&hist[labels[i]], 1);
    __syncthreads();
    if (t < 80) {
        const int p = t >> 4, c = t & 15;
        Scol[p * 16 + c] = (c < 10) ? ((float)hist[c] + 204.8f) : 0.f;
    }
}

// ---------------------------------------------------------------------------
// X0 init (X8 in fragment layout)
// ---------------------------------------------------------------------------
__global__ __launch_bounds__(256) void init_kernel(const int* __restrict__ labels,
                                                   uchar* __restrict__ X8_0,
                                                   uchar* __restrict__ X8_1,
                                                   float* __restrict__ X32)
{
    const int idx = blockIdx.x * 256 + threadIdx.x;   // 5*16*4096 = 327680
    const int p = idx >> 16;
    const int rem = idx & 65535;
    const int c = rem >> 12, j = rem & 4095;
    float v;
    if (c >= 10) v = 0.f;
    else if (j < 2048) v = (labels[j] == c) ? 1.0f : 0.0f;
    else v = 0.1f;
    unsigned pk = __builtin_amdgcn_cvt_pk_fp8_f32(v, v, 0, false);
    X8_0[(size_t)p * 65536 + xfrag_off(c, j)] = (uchar)(pk & 0xff);
    if (c >= 10) X8_1[(size_t)p * 65536 + xfrag_off(c, j)] = 0;
    if (c < 10) X32[((size_t)p * 4096 + j) * 10 + c] = v;
}

// ---------------------------------------------------------------------------
// Pack w1 (300x150) and w2 (150x75) into fragment-major fp16 B-operand form.
// ---------------------------------------------------------------------------
__global__ __launch_bounds__(256) void wfrag_kernel(const float* __restrict__ w1,
                                                    const float* __restrict__ w2,
                                                    __half* __restrict__ W1f,
                                                    __half* __restrict__ W2f)
{
    int idx = blockIdx.x * 256 + threadIdx.x;   // 51200 + 12800 = 64000
    if (idx < 51200) {
        const int frag = idx >> 9, e9 = idx & 511;
        const int s = frag / 10, j = frag % 10;
        const int g = e9 >> 7, fr = (e9 >> 3) & 15, e = e9 & 7;
        const int k = s * 32 + g * 8 + e, n = j * 16 + fr;
        const float v = (k < 300 && n < 150) ? w1[(size_t)k * 150 + n] : 0.f;
        W1f[idx] = __float2half(v);
    } else if (idx < 64000) {
        const int i2 = idx - 51200;
        const int frag = i2 >> 9, e9 = i2 & 511;
        const int s = frag / 5, j = frag % 5;
        const int g = e9 >> 7, fr = (e9 >> 3) & 15, e = e9 & 7;
        const int k = s * 32 + g * 8 + e, n = j * 16 + fr;
        const float v = (k < 150 && n < 75) ? w2[(size_t)k * 75 + n] : 0.f;
        W2f[i2] = __float2half(v);
    }
}

// ---------------------------------------------------------------------------
// One GTG iteration: 4-bit A expanded in-register to fp8 (LUT), fp8 MFMA.
// ---------------------------------------------------------------------------
__global__ __launch_bounds__(256, 4) void gtg8_kernel(
    const uchar* __restrict__ A4f,
    const uchar* __restrict__ X8i, uchar* __restrict__ X8o,
    const float* __restrict__ X32i, float* __restrict__ X32o,
    __half* __restrict__ Xs16f, float* __restrict__ ytacc,
    float* __restrict__ Scol, int it, int pbase)
{
    __shared__ float yred[4][256];
    const int t = threadIdx.x;
    const int lane = t & 63, wave = t >> 6;
    const int p = pbase + (blockIdx.x >> 8);
    const int pl = p - pbase;
    const int rb = blockIdx.x & 255;

    const uchar* Ab = A4f + (size_t)pl * 8388608 + (size_t)rb * 32768
                    + wave * 8192 + lane * 8;
    const uchar* Xb = X8i + (size_t)p * 65536 + wave * 16384 + lane * 16;

    f32x4 acc0 = {0.f, 0.f, 0.f, 0.f};
    f32x4 acc1 = {0.f, 0.f, 0.f, 0.f};
#pragma unroll
    for (int u = 0; u < 16; ++u) {
        uint2 a4 = *(const uint2*)(Ab + u * 512);
        uint4 bv = *(const uint4*)(Xb + u * 1024);
        unsigned e00, e01, e10, e11;
        expand4(a4.x, e00, e01);
        expand4(a4.y, e10, e11);
        acc0 = __builtin_amdgcn_mfma_f32_16x16x32_fp8_fp8(
            mk64(e00, e01), mk64(bv.x, bv.y), acc0, 0, 0, 0);
        acc1 = __builtin_amdgcn_mfma_f32_16x16x32_fp8_fp8(
            mk64(e10, e11), mk64(bv.z, bv.w), acc1, 0, 0, 0);
    }
    {
        const int r4 = (lane >> 4) * 4;
        const int fr = lane & 15;
#pragma unroll
        for (int q = 0; q < 4; ++q)
            yred[wave][(r4 + q) * 16 + fr] = acc0[q] + acc1[q];
    }
    __syncthreads();

    // ---- update phase: thread t -> row r=t>>4, class c=t&15
    const int r = t >> 4, c = t & 15;
    const int row = rb * 16 + r;
    const float T = yred[0][t] + yred[1][t] + yred[2][t] + yred[3][t];
    const float y = Scol[it * 80 + pl * 16 + c] - T;
    const float x = (c < 10) ? X32i[((size_t)p * 4096 + row) * 10 + c] : 0.f;
    const float m = x * y;
    float s = m;
    s += __shfl_xor(s, 1, 16);
    s += __shfl_xor(s, 2, 16);
    s += __shfl_xor(s, 4, 16);
    s += __shfl_xor(s, 8, 16);
    const float dv = m / (s + 1e-8f);
    const float xn = x + dv;
    if (c < 10) {
        X32o[((size_t)p * 4096 + row) * 10 + c] = xn;
        unsigned pk = __builtin_amdgcn_cvt_pk_fp8_f32(xn, xn, 0, false);
        X8o[(size_t)p * 65536 + xfrag_off(c, row)] = (uchar)(pk & 0xff);
        if (p < 4) {
            const int k = c * 30 + it;
            Xs16f[(size_t)p * 1310720 + xsfrag_off(row, k)] = __float2half(xn);
        }
    }
    if (p == 4) {
        float e = (c < 10) ? (-dv * logf(dv + 1e-8f)) : 0.f;
        e += __shfl_xor(e, 1, 16);
        e += __shfl_xor(e, 2, 16);
        e += __shfl_xor(e, 4, 16);
        e += __shfl_xor(e, 8, 16);
        if (c == 0) {
            float prev = (it == 0) ? 0.f : ytacc[row];
            ytacc[row] = prev + e;
        }
    }

    // ---- colsum for next iteration
    __syncthreads();
    yred[0][t] = (c < 10) ? xn : 0.f;
    __syncthreads();
    if (t < 10) {
        float sc = 0.f;
#pragma unroll
        for (int rr = 0; rr < 16; ++rr) sc += yred[0][t + rr * 16];
        atomicAdd(&Scol[(it + 1) * 80 + pl * 16 + t], sc);
    }
}

// ---------------------------------------------------------------------------
// MFMA MLP (layers 1+2, all levels). 256 blocks x 4 waves.
// ---------------------------------------------------------------------------
__global__ __launch_bounds__(256) void mlp_mfma_kernel(const __half* __restrict__ Xs16f,
                                                       const __half* __restrict__ W1f,
                                                       const __half* __restrict__ W2f,
                                                       const float* __restrict__ b1,
                                                       const float* __restrict__ b2,
                                                       float* __restrict__ H2)
{
    __shared__ char h1s[4][16 * 384];   // per-wave h1 [16 rows][192 halves], swizzled
    __shared__ float b1s[160];
    __shared__ float b2s[80];
    const int t = threadIdx.x;
    const int lane = t & 63, wave = t >> 6;
    const int fr = lane & 15, g = lane >> 4;
    const int lvl = blockIdx.x >> 6;
    const int rb = (blockIdx.x & 63) * 4 + wave;

    if (t < 160) b1s[t] = (t < 150) ? b1[t] : 0.f;
    else if (t < 240) b2s[t - 160] = (t < 235) ? b2[t - 160] : 0.f;
    __syncthreads();

    // ---- layer 1: [16 x 320] @ [320 x 160]
    const __half* Abase = Xs16f + (size_t)lvl * 1310720 + (size_t)rb * 5120;
    f32x4 acc1[10];
#pragma unroll
    for (int j = 0; j < 10; ++j) acc1[j] = (f32x4){0.f, 0.f, 0.f, 0.f};
#pragma unroll
    for (int s = 0; s < 10; ++s) {
        f16x8 a = *(const f16x8*)(Abase + s * 512 + lane * 8);
#pragma unroll
        for (int j = 0; j < 10; ++j) {
            f16x8 b = *(const f16x8*)(W1f + (s * 10 + j) * 512 + lane * 8);
            acc1[j] = __builtin_amdgcn_mfma_f32_16x16x32_f16(a, b, acc1[j], 0, 0, 0);
        }
    }
    // bias + relu -> h1s (swizzled 2B writes)
    char* hw = h1s[wave];
#pragma unroll
    for (int j = 0; j < 10; ++j) {
#pragma unroll
        for (int q = 0; q < 4; ++q) {
            const int row = g * 4 + q;
            const int col = j * 16 + fr;
            float v = fmaxf(acc1[j][q] + b1s[col], 0.f);
            *(__half*)(hw + row * 384 + ((col * 2) ^ ((row & 7) << 4))) = __float2half(v);
        }
    }
    __syncthreads();

    // ---- layer 2: [16 x 160] @ [160 x 80]
    f32x4 acc2[5];
#pragma unroll
    for (int j = 0; j < 5; ++j) acc2[j] = (f32x4){0.f, 0.f, 0.f, 0.f};
#pragma unroll
    for (int s = 0; s < 5; ++s) {
        f16x8 a = *(const f16x8*)(hw + fr * 384 + ((s * 64 + g * 16) ^ ((fr & 7) << 4)));
#pragma unroll
        for (int j = 0; j < 5; ++j) {
            f16x8 b = *(const f16x8*)(W2f + (s * 5 + j) * 512 + lane * 8);
            acc2[j] = __builtin_amdgcn_mfma_f32_16x16x32_f16(a, b, acc2[j], 0, 0, 0);
        }
    }
    // bias + relu -> H2 (cols < 75)
#pragma unroll
    for (int j = 0; j < 5; ++j) {
        const int col = j * 16 + fr;
        if (col < 75) {
#pragma unroll
            for (int q = 0; q < 4; ++q) {
                const int row = rb * 16 + g * 4 + q;
                float v = fmaxf(acc2[j][q] + b2s[col], 0.f);
                H2[(size_t)row * 300 + lvl * 75 + col] = v;
            }
        }
    }
}

// ---------------------------------------------------------------------------
// Final: y_pred = H2 @ w3 + b3; y_true = ytacc/30; labelled_mask
// ---------------------------------------------------------------------------
__global__ __launch_bounds__(256) void final_kernel(const float* __restrict__ H2,
                                                    const float* __restrict__ w3,
                                                    const float* __restrict__ b3,
                                                    const float* __restrict__ ytacc,
                                                    float* __restrict__ out)
{
    __shared__ float w[300];
    const int t = threadIdx.x;
    const int b = blockIdx.x * 256 + t;
    for (int i = t; i < 300; i += 256) w[i] = w3[i];
    __syncthreads();
    float acc = b3[0];
    const float4* row = (const float4*)(H2 + (size_t)b * 300);
    for (int k4 = 0; k4 < 75; ++k4) {
        float4 v = row[k4];
        acc += v.x * w[k4 * 4] + v.y * w[k4 * 4 + 1] + v.z * w[k4 * 4 + 2] + v.w * w[k4 * 4 + 3];
    }
    out[b] = acc;
    out[4096 + b] = ytacc[b] * (1.0f / 30.0f);
    out[2 * 4096 + b] = (b < 2048) ? 1.0f : 0.0f;
}

// ---------------------------------------------------------------------------
extern "C" void kernel_launch(void* const* d_in, const int* in_sizes, int n_in,
                              void* d_out, int out_size, void* d_ws, size_t ws_size,
                              hipStream_t stream)
{
    (void)in_sizes; (void)n_in; (void)out_size;

    const float* feats[4] = {(const float*)d_in[0], (const float*)d_in[1],
                             (const float*)d_in[2], (const float*)d_in[3]};
    const float* embedds = (const float*)d_in[4];
    const int* labels = (const int*)d_in[6];
    const float* lsw[4] = {(const float*)d_in[7], (const float*)d_in[9],
                           (const float*)d_in[11], (const float*)d_in[13]};
    const float* lsb[4] = {(const float*)d_in[8], (const float*)d_in[10],
                           (const float*)d_in[12], (const float*)d_in[14]};
    const float* w1 = (const float*)d_in[15];
    const float* b1 = (const float*)d_in[16];
    const float* w2 = (const float*)d_in[17];
    const float* b2 = (const float*)d_in[18];
    const float* w3 = (const float*)d_in[19];
    const float* b3 = (const float*)d_in[20];

    // fused path: 5 fp4 A' matrices resident (5*8MB) + 32MB A16f; else 1 A4
    const bool fused = ws_size >= 156930304ULL;
    const size_t A4_BYTES = fused ? 41943040ULL : 8388608ULL;

    char* ws = (char*)d_ws;
    uchar* A4       = (uchar*)(ws);
    __half* A16f    = (__half*)(ws + A4_BYTES);       // 33554432 (scratch)
    char* base      = ws + A4_BYTES + 33554432;
    float* pooled   = (float*)(base);                 //  8388608
    __half* N16     = (__half*)(base + 8388608);      //  4194304
    uchar* Xt8      = (uchar*)(base + 12582912);      //  2 x 327680
    float* X32      = (float*)(base + 13238272);      //  2 x 819200
    __half* Xs16f   = (__half*)(base + 14876672);     //  10485760 (4 levels frag)
    float* H2       = (float*)(base + 25362432);      //  4915200
    float* ytacc    = (float*)(base + 30277632);      //  16384
    float* partials = (float*)(base + 30294016);      //  4096
    float* scal     = (float*)(base + 30298112);      //  256
    float* Scol     = (float*)(base + 30298368);      //  16384 (31 x 5 x 16 fp32)
    __half* W1f     = (__half*)(base + 30314752);     //  102400
    __half* W2f     = (__half*)(base + 30417152);     //  25600

    uchar* Xt8b[2] = {Xt8, Xt8 + 327680};
    float* X32b[2] = {X32, X32 + 204800};
    float* out = (float*)d_out;

    const int Cs[4] = {64, 128, 256, 512};
    const int S2s[4] = {64, 64, 16, 16};

    auto run_iters = [&](const uchar* Ab4, int pbase, int nprob) {
        hipMemsetAsync(Scol, 0, 31 * 80 * sizeof(float), stream);
        if (pbase == 0) hipMemsetAsync(Xs16f, 0, 10485760, stream);
        scol0_kernel<<<1, 256, 0, stream>>>(labels, Scol);
        init_kernel<<<1280, 256, 0, stream>>>(labels, Xt8b[0], Xt8b[1], X32b[0]);
        for (int it = 0; it < 30; ++it) {
            const int i = it & 1, o = i ^ 1;
            gtg8_kernel<<<nprob * 256, 256, 0, stream>>>(
                Ab4, Xt8b[i], Xt8b[o], X32b[i], X32b[o], Xs16f, ytacc, Scol, it, pbase);
        }
    };

    wfrag_kernel<<<250, 256, 0, stream>>>(w1, w2, W1f, W2f);

    for (int lvl = 0; lvl < 4; ++lvl) {
        const int c = Cs[lvl];
        const int total = 4096 * c;
        if (S2s[lvl] == 64)
            pool_kernel<64><<<total / 256, 256, 0, stream>>>(feats[lvl], pooled, total);
        else
            pool_kernel<16><<<total / 256, 256, 0, stream>>>(feats[lvl], pooled, total);
        ls_norm_kernel<<<4096, 128, 0, stream>>>(pooled, lsw[lvl], lsb[lvl], N16, c);
        uchar* Ab4 = A4 + (fused ? (size_t)lvl * 8388608 : 0);
        a_gemm_core<128><<<1024, 256, 0, stream>>>(N16, A16f, partials);
        mean_kernel<<<1, 256, 0, stream>>>(partials, scal);
        abar4_frag_kernel<<<4096, 256, 0, stream>>>(A16f, Ab4, scal);
        if (!fused) {
            run_iters(Ab4, lvl, 1);
        }
    }

    // embeddings branch
    norm512_kernel<<<4096, 256, 0, stream>>>(embedds, N16);
    {
        uchar* Ab4 = A4 + (fused ? (size_t)4 * 8388608 : 0);
        a_gemm_core<512><<<1024, 256, 0, stream>>>(N16, A16f, partials);
        mean_kernel<<<1, 256, 0, stream>>>(partials, scal);
        abar4_frag_kernel<<<4096, 256, 0, stream>>>(A16f, Ab4, scal);
        if (!fused) run_iters(Ab4, 4, 1);
    }

    if (fused) run_iters(A4, 0, 5);
    mlp_mfma_kernel<<<256, 256, 0, stream>>>(Xs16f, W1f, W2f, b1, b2, H2);

    final_kernel<<<16, 256, 0, stream>>>(H2, w3, b3, ytacc, out);
}

// Round 11
// 770.489 us; speedup vs baseline: 2.3584x; 1.0704x over previous
//
#include <hip/hip_runtime.h>
#include <hip/hip_fp16.h>

typedef _Float16 f16x8 __attribute__((ext_vector_type(8)));
typedef float f32x4 __attribute__((ext_vector_type(4)));
typedef unsigned char uchar;

static __device__ __forceinline__ long long mk64(unsigned lo, unsigned hi)
{
    return (long long)(((unsigned long long)hi << 32) | (unsigned long long)lo);
}

// fragment-layout offset for X8 (B-operand): class c, row j
static __device__ __forceinline__ int xfrag_off(int c, int j)
{
    return (j >> 6) * 1024 + (((j >> 3) & 3) * 16 + c) * 16 + ((j >> 5) & 1) * 8 + (j & 7);
}

// fragment-layout offset (halves) for Xs16f (A-operand): row (0..4095), k (0..319)
static __device__ __forceinline__ int xsfrag_off(int row, int k)
{
    return (row >> 4) * 5120 + (k >> 5) * 512 + (((k >> 3) & 3) * 16 + (row & 15)) * 8 + (k & 7);
}

// nibble codes -> fp8 e4m3 bytes of k/16 (exact): LUT via v_perm
#define T03 0x24201800u
#define T47 0x2E2C2A28u
#define T8B 0x33323130u
#define TCF 0x37363534u

static __device__ __forceinline__ void expand4(unsigned w, unsigned& o0, unsigned& o1)
{
    unsigned even = w & 0x0F0F0F0Fu;
    unsigned odd  = (w >> 4) & 0x0F0F0F0Fu;
    unsigned i_lo = __builtin_amdgcn_perm(odd, even, 0x05010400u);
    unsigned i_hi = __builtin_amdgcn_perm(odd, even, 0x07030602u);
    {
        unsigned i3 = i_lo & 0x07070707u;
        unsigned ta = __builtin_amdgcn_perm(T47, T03, i3);
        unsigned tb = __builtin_amdgcn_perm(TCF, T8B, i3);
        unsigned m  = ((i_lo >> 3) & 0x01010101u) * 0xFFu;
        o0 = ta ^ ((ta ^ tb) & m);
    }
    {
        unsigned i3 = i_hi & 0x07070707u;
        unsigned ta = __builtin_amdgcn_perm(T47, T03, i3);
        unsigned tb = __builtin_amdgcn_perm(TCF, T8B, i3);
        unsigned m  = ((i_hi >> 3) & 0x01010101u) * 0xFFu;
        o1 = ta ^ ((ta ^ tb) & m);
    }
}

// ---------------------------------------------------------------------------
// Fused pool + linear + relu + row-normalize for 4 levels, plus embedds
// normalize. Grid: pcount*4096 blocks, 256 threads. p = pbase + blk>>12.
// Writes N16all: level p at halves-offset p*524288; embedds at 2097152.
// ---------------------------------------------------------------------------
__global__ __launch_bounds__(256) void fused_ls_kernel(
    const float* __restrict__ f0, const float* __restrict__ f1,
    const float* __restrict__ f2, const float* __restrict__ f3,
    const float* __restrict__ embedds,
    const float* __restrict__ lw0, const float* __restrict__ lb0,
    const float* __restrict__ lw1, const float* __restrict__ lb1,
    const float* __restrict__ lw2, const float* __restrict__ lb2,
    const float* __restrict__ lw3, const float* __restrict__ lb3,
    __half* __restrict__ N16all, int pbase)
{
    __shared__ float pl[512];
    __shared__ float red[4];
    const int t = threadIdx.x;
    const int p = pbase + (blockIdx.x >> 12);
    const int row = blockIdx.x & 4095;

    if (p == 4) {
        float2 v = *(const float2*)(embedds + (size_t)row * 512 + t * 2);
        float ss = v.x * v.x + v.y * v.y;
        for (int off = 32; off > 0; off >>= 1) ss += __shfl_down(ss, off, 64);
        if ((t & 63) == 0) red[t >> 6] = ss;
        __syncthreads();
        float inv = 1.0f / fmaxf(sqrtf(red[0] + red[1] + red[2] + red[3]), 1e-12f);
        __half2 o;
        o.x = __float2half(v.x * inv);
        o.y = __float2half(v.y * inv);
        *(__half2*)(N16all + 2097152 + (size_t)row * 512 + t * 2) = o;
        return;
    }

    const float* feat; const float* w; const float* b; int C;
    switch (p) {
        case 0:  feat = f0; w = lw0; b = lb0; C = 64;  break;
        case 1:  feat = f1; w = lw1; b = lb1; C = 128; break;
        case 2:  feat = f2; w = lw2; b = lb2; C = 256; break;
        default: feat = f3; w = lw3; b = lb3; C = 512; break;
    }
    const float* fr = feat + (size_t)row * C * ((p < 2) ? 64 : 16);

    if (p == 0) {            // 64 ch x 64 sp: 4 threads/ch
        const int c = t >> 2, q = t & 3;
        const float4* src = (const float4*)(fr + c * 64 + q * 16);
        float s = 0.f;
#pragma unroll
        for (int i = 0; i < 4; ++i) { float4 v = src[i]; s += v.x + v.y + v.z + v.w; }
        s += __shfl_xor(s, 1, 64);
        s += __shfl_xor(s, 2, 64);
        if (q == 0) pl[c] = s * (1.0f / 64.f);
    } else if (p == 1) {     // 128 ch x 64 sp: 2 threads/ch
        const int c = t >> 1, h = t & 1;
        const float4* src = (const float4*)(fr + c * 64 + h * 32);
        float s = 0.f;
#pragma unroll
        for (int i = 0; i < 8; ++i) { float4 v = src[i]; s += v.x + v.y + v.z + v.w; }
        s += __shfl_xor(s, 1, 64);
        if (h == 0) pl[c] = s * (1.0f / 64.f);
    } else if (p == 2) {     // 256 ch x 16 sp
        const float4* src = (const float4*)(fr + t * 16);
        float s = 0.f;
#pragma unroll
        for (int i = 0; i < 4; ++i) { float4 v = src[i]; s += v.x + v.y + v.z + v.w; }
        pl[t] = s * (1.0f / 16.f);
    } else {                 // 512 ch x 16 sp: 2 ch/thread
#pragma unroll
        for (int cc = 0; cc < 2; ++cc) {
            const int c = t + cc * 256;
            const float4* src = (const float4*)(fr + c * 16);
            float s = 0.f;
#pragma unroll
            for (int i = 0; i < 4; ++i) { float4 v = src[i]; s += v.x + v.y + v.z + v.w; }
            pl[c] = s * (1.0f / 16.f);
        }
    }
    __syncthreads();

    float v = 0.f, ss = 0.f;
    if (t < 128) {
        float acc = b[t];
        for (int k = 0; k < C; ++k) acc = fmaf(pl[k], w[(size_t)k * 128 + t], acc);
        v = fmaxf(acc, 0.f);
        ss = v * v;
        for (int off = 32; off > 0; off >>= 1) ss += __shfl_down(ss, off, 64);
        if ((t & 63) == 0) red[t >> 6] = ss;
    }
    __syncthreads();
    if (t < 128) {
        float inv = 1.0f / fmaxf(sqrtf(red[0] + red[1]), 1e-12f);
        N16all[(size_t)p * 524288 + (size_t)row * 128 + t] = __float2half(v * inv);
    }
}

// ---------------------------------------------------------------------------
// All-problem MFMA GEMM. Grid pcount*1024; p = pbase + blk>>10, runtime K.
// Writes fp16 C = clamp(nnT,0,1), diag=0, FRAGMENT-MAJOR, per-problem slice
// of A16f (32 MB each) + fp32 partial sums -> partials[lp*1024+blk].
// ---------------------------------------------------------------------------
__global__ __launch_bounds__(256) void a_gemm_all(const __half* __restrict__ N16all,
                                                  __half* __restrict__ A16f,
                                                  float* __restrict__ partials,
                                                  int pbase)
{
    __shared__ __half smem[16384];   // As(8192) | Bs(8192); reused as Cst
    __shared__ float reds[4];
    __half* As = smem;
    __half* Bs = smem + 8192;
    char* Cb = (char*)smem;
    const int t = threadIdx.x;
    const int lane = t & 63, wave = t >> 6;
    const int lp = blockIdx.x >> 10;
    const int p = pbase + lp;
    const int blk = blockIdx.x & 1023;
    const int K = (p == 4) ? 512 : 128;
    const __half* N16 = N16all + ((p == 4) ? 2097152u : (unsigned)p * 524288u);
    const int bx = blk & 31, by = blk >> 5;
    const int wr = wave >> 1, wc = wave & 1;
    const int fr = lane & 15;
    const int g = lane >> 4;
    const int r0 = by * 128, c0 = bx * 128;
    const int sr = t >> 3;
    const int sc = t & 7;

    f32x4 acc[4][4];
#pragma unroll
    for (int i = 0; i < 4; ++i)
#pragma unroll
        for (int j = 0; j < 4; ++j) acc[i][j] = (f32x4){0.f, 0.f, 0.f, 0.f};

    for (int kt = 0; kt < (K >> 6); ++kt) {
        const int kb = kt * 64;
        __syncthreads();
#pragma unroll
        for (int pp = 0; pp < 4; ++pp) {
            const int r = pp * 32 + sr;
            uint4 va = *(const uint4*)(N16 + (size_t)(r0 + r) * K + kb + sc * 8);
            uint4 vb = *(const uint4*)(N16 + (size_t)(c0 + r) * K + kb + sc * 8);
            const int d = r * 64 + ((((sc * 16) ^ ((r & 7) << 4))) >> 1);
            *(uint4*)&As[d] = va;
            *(uint4*)&Bs[d] = vb;
        }
        __syncthreads();
#pragma unroll
        for (int ks = 0; ks < 2; ++ks) {
            const int ko = ((ks * 64 + g * 16) ^ ((fr & 7) << 4)) >> 1;
            f16x8 af[4], bf[4];
#pragma unroll
            for (int i = 0; i < 4; ++i) {
                af[i] = *(const f16x8*)&As[(wr * 64 + i * 16 + fr) * 64 + ko];
                bf[i] = *(const f16x8*)&Bs[(wc * 64 + i * 16 + fr) * 64 + ko];
            }
#pragma unroll
            for (int i = 0; i < 4; ++i)
#pragma unroll
                for (int j = 0; j < 4; ++j)
                    acc[i][j] = __builtin_amdgcn_mfma_f32_16x16x32_f16(af[i], bf[j], acc[i][j], 0, 0, 0);
        }
    }
    __syncthreads();

    float lsum = 0.f;
    const int r4 = g * 4;
#pragma unroll
    for (int i = 0; i < 4; ++i) {
#pragma unroll
        for (int q = 0; q < 4; ++q) {
            const int lr = wr * 64 + i * 16 + r4 + q;
            const int row = r0 + lr;
#pragma unroll
            for (int j = 0; j < 4; ++j) {
                const int lc = wc * 64 + j * 16 + fr;
                const int col = c0 + lc;
                float v = fminf(fmaxf(acc[i][j][q], 0.f), 1.f);
                if (row == col) v = 0.f;
                lsum += v;
                *(__half*)(Cb + lr * 256 + ((lc * 2) ^ ((lr & 7) << 4))) = __float2half(v);
            }
        }
    }
    __syncthreads();

#pragma unroll
    for (int pp = 0; pp < 4; ++pp) {
        const int rbl2 = pp * 4 + (t >> 6);
        const int rbl = rbl2 >> 1, ks2l = rbl2 & 1;
        const int l = t & 63;
        const int lr = rbl * 16 + (l & 15);
        const int e0 = ks2l * 64 + (l >> 4) * 8;
        uint4 v0 = *(const uint4*)(Cb + lr * 256 + ((e0 * 2) ^ ((lr & 7) << 4)));
        uint4 v1 = *(const uint4*)(Cb + lr * 256 + (((e0 + 32) * 2) ^ ((lr & 7) << 4)));
        const size_t rb = (size_t)(by * 8 + rbl);
        const size_t ks2 = (size_t)(bx * 2 + ks2l);
        char* dst = (char*)A16f + (size_t)lp * 33554432 + rb * 131072 + ks2 * 2048 + l * 32;
        *(uint4*)dst = v0;
        *(uint4*)(dst + 16) = v1;
    }

    for (int off = 32; off > 0; off >>= 1) lsum += __shfl_down(lsum, off, 64);
    if (lane == 0) reds[wave] = lsum;
    __syncthreads();
    if (t == 0) partials[lp * 1024 + blk] = reds[0] + reds[1] + reds[2] + reds[3];
}

// ---------------------------------------------------------------------------
// mean per problem: block lp reduces partials[lp][0..1023] -> scal[lp]
// ---------------------------------------------------------------------------
__global__ __launch_bounds__(256) void mean_all_kernel(const float* __restrict__ partials,
                                                       float* __restrict__ scal)
{
    __shared__ float red[4];
    const int t = threadIdx.x, lp = blockIdx.x;
    float s = 0.f;
    for (int i = t; i < 1024; i += 256) s += partials[lp * 1024 + i];
    for (int off = 32; off > 0; off >>= 1) s += __shfl_down(s, off, 64);
    if ((t & 63) == 0) red[t >> 6] = s;
    __syncthreads();
    if (t == 0) scal[lp] = (red[0] + red[1] + red[2] + red[3]) * (1.0f / 16777216.0f);
}

// ---------------------------------------------------------------------------
// Quantize to 4-bit codes round(16*(a<mean?0:a)), linear frag order.
// Grid pcount*4096; lp = blk>>12.
// ---------------------------------------------------------------------------
__global__ __launch_bounds__(256) void abar4_all_kernel(const __half* __restrict__ A16f,
                                                        uchar* __restrict__ A4,
                                                        const float* __restrict__ scal)
{
    const int lp = blockIdx.x >> 12;
    const float mean = scal[lp];
    const size_t i = (size_t)(blockIdx.x & 4095) * 256 + threadIdx.x;
    const __half* src = A16f + (size_t)lp * 16777216 + i * 16;
    uint4 u0 = *(const uint4*)(src);
    uint4 u1 = *(const uint4*)(src + 8);
    __half h[16];
    *(uint4*)h = u0;
    *(uint4*)(h + 8) = u1;
    unsigned d0 = 0, d1 = 0;
#pragma unroll
    for (int k = 0; k < 8; ++k) {
        float a = __half2float(h[k]);
        float v = (a < mean) ? 0.f : a;
        unsigned n = (unsigned)fminf(v * 16.f + 0.5f, 15.f);
        d0 |= n << (4 * k);
    }
#pragma unroll
    for (int k = 0; k < 8; ++k) {
        float a = __half2float(h[8 + k]);
        float v = (a < mean) ? 0.f : a;
        unsigned n = (unsigned)fminf(v * 16.f + 0.5f, 15.f);
        d1 |= n << (4 * k);
    }
    uint2 o; o.x = d0; o.y = d1;
    *(uint2*)(A4 + (size_t)lp * 8388608 + i * 8) = o;
}

// ---------------------------------------------------------------------------
// X0 init + Scol init (blocks 0..30) + label histogram (block 0)
// ---------------------------------------------------------------------------
__global__ __launch_bounds__(256) void init_kernel(const int* __restrict__ labels,
                                                   uchar* __restrict__ X8_0,
                                                   uchar* __restrict__ X8_1,
                                                   float* __restrict__ X32,
                                                   float* __restrict__ Scol)
{
    __shared__ int hist[16];
    const int blk = blockIdx.x;
    const int t = threadIdx.x;
    const int idx = blk * 256 + t;   // 5*16*4096 = 327680
    const int p = idx >> 16;
    const int rem = idx & 65535;
    const int c = rem >> 12, j = rem & 4095;
    float v;
    if (c >= 10) v = 0.f;
    else if (j < 2048) v = (labels[j] == c) ? 1.0f : 0.0f;
    else v = 0.1f;
    unsigned pk = __builtin_amdgcn_cvt_pk_fp8_f32(v, v, 0, false);
    X8_0[(size_t)p * 65536 + xfrag_off(c, j)] = (uchar)(pk & 0xff);
    if (c >= 10) X8_1[(size_t)p * 65536 + xfrag_off(c, j)] = 0;
    if (c < 10) X32[((size_t)p * 4096 + j) * 10 + c] = v;

    if (blk == 0) {
        if (t < 16) hist[t] = 0;
        __syncthreads();
        for (int i = t; i < 2048; i += 256) atomicAdd(&hist[labels[i]], 1);
        __syncthreads();
        if (t < 80) {
            const int pp = t >> 4, cc = t & 15;
            Scol[pp * 16 + cc] = (cc < 10) ? ((float)hist[cc] + 204.8f) : 0.f;
        }
    } else if (blk <= 30) {
        if (t < 80) Scol[blk * 80 + t] = 0.f;
    }
}

// ---------------------------------------------------------------------------
// Pack w1 (300x150) and w2 (150x75) into fragment-major fp16 B-operand form.
// ---------------------------------------------------------------------------
__global__ __launch_bounds__(256) void wfrag_kernel(const float* __restrict__ w1,
                                                    const float* __restrict__ w2,
                                                    __half* __restrict__ W1f,
                                                    __half* __restrict__ W2f)
{
    int idx = blockIdx.x * 256 + threadIdx.x;   // 51200 + 12800 = 64000
    if (idx < 51200) {
        const int frag = idx >> 9, e9 = idx & 511;
        const int s = frag / 10, j = frag % 10;
        const int g = e9 >> 7, fr = (e9 >> 3) & 15, e = e9 & 7;
        const int k = s * 32 + g * 8 + e, n = j * 16 + fr;
        const float v = (k < 300 && n < 150) ? w1[(size_t)k * 150 + n] : 0.f;
        W1f[idx] = __float2half(v);
    } else if (idx < 64000) {
        const int i2 = idx - 51200;
        const int frag = i2 >> 9, e9 = i2 & 511;
        const int s = frag / 5, j = frag % 5;
        const int g = e9 >> 7, fr = (e9 >> 3) & 15, e = e9 & 7;
        const int k = s * 32 + g * 8 + e, n = j * 16 + fr;
        const float v = (k < 150 && n < 75) ? w2[(size_t)k * 75 + n] : 0.f;
        W2f[i2] = __float2half(v);
    }
}

// ---------------------------------------------------------------------------
// One GTG iteration: 4-bit A expanded in-register to fp8 (LUT), fp8 MFMA.
// 5 blocks/CU residency (min 5 waves/EU).
// ---------------------------------------------------------------------------
__global__ __launch_bounds__(256, 5) void gtg8_kernel(
    const uchar* __restrict__ A4f,
    const uchar* __restrict__ X8i, uchar* __restrict__ X8o,
    const float* __restrict__ X32i, float* __restrict__ X32o,
    __half* __restrict__ Xs16f, float* __restrict__ ytacc,
    float* __restrict__ Scol, int it, int pbase)
{
    __shared__ float yred[4][256];
    const int t = threadIdx.x;
    const int lane = t & 63, wave = t >> 6;
    const int p = pbase + (blockIdx.x >> 8);
    const int pl = p - pbase;
    const int rb = blockIdx.x & 255;

    const uchar* Ab = A4f + (size_t)pl * 8388608 + (size_t)rb * 32768
                    + wave * 8192 + lane * 8;
    const uchar* Xb = X8i + (size_t)p * 65536 + wave * 16384 + lane * 16;

    f32x4 acc0 = {0.f, 0.f, 0.f, 0.f};
    f32x4 acc1 = {0.f, 0.f, 0.f, 0.f};
#pragma unroll
    for (int u = 0; u < 16; ++u) {
        uint2 a4 = *(const uint2*)(Ab + u * 512);
        uint4 bv = *(const uint4*)(Xb + u * 1024);
        unsigned e00, e01, e10, e11;
        expand4(a4.x, e00, e01);
        expand4(a4.y, e10, e11);
        acc0 = __builtin_amdgcn_mfma_f32_16x16x32_fp8_fp8(
            mk64(e00, e01), mk64(bv.x, bv.y), acc0, 0, 0, 0);
        acc1 = __builtin_amdgcn_mfma_f32_16x16x32_fp8_fp8(
            mk64(e10, e11), mk64(bv.z, bv.w), acc1, 0, 0, 0);
    }
    {
        const int r4 = (lane >> 4) * 4;
        const int fr = lane & 15;
#pragma unroll
        for (int q = 0; q < 4; ++q)
            yred[wave][(r4 + q) * 16 + fr] = acc0[q] + acc1[q];
    }
    __syncthreads();

    // ---- update phase: thread t -> row r=t>>4, class c=t&15
    const int r = t >> 4, c = t & 15;
    const int row = rb * 16 + r;
    const float T = yred[0][t] + yred[1][t] + yred[2][t] + yred[3][t];
    const float y = Scol[it * 80 + pl * 16 + c] - T;
    const float x = (c < 10) ? X32i[((size_t)p * 4096 + row) * 10 + c] : 0.f;
    const float m = x * y;
    float s = m;
    s += __shfl_xor(s, 1, 16);
    s += __shfl_xor(s, 2, 16);
    s += __shfl_xor(s, 4, 16);
    s += __shfl_xor(s, 8, 16);
    const float dv = m / (s + 1e-8f);
    const float xn = x + dv;
    if (c < 10) {
        X32o[((size_t)p * 4096 + row) * 10 + c] = xn;
        unsigned pk = __builtin_amdgcn_cvt_pk_fp8_f32(xn, xn, 0, false);
        X8o[(size_t)p * 65536 + xfrag_off(c, row)] = (uchar)(pk & 0xff);
        if (p < 4) {
            const int k = c * 30 + it;
            Xs16f[(size_t)p * 1310720 + xsfrag_off(row, k)] = __float2half(xn);
        }
    }
    if (p == 4) {
        float e = (c < 10) ? (-dv * logf(dv + 1e-8f)) : 0.f;
        e += __shfl_xor(e, 1, 16);
        e += __shfl_xor(e, 2, 16);
        e += __shfl_xor(e, 4, 16);
        e += __shfl_xor(e, 8, 16);
        if (c == 0) {
            float prev = (it == 0) ? 0.f : ytacc[row];
            ytacc[row] = prev + e;
        }
    }

    // ---- colsum for next iteration
    __syncthreads();
    yred[0][t] = (c < 10) ? xn : 0.f;
    __syncthreads();
    if (t < 10) {
        float sc = 0.f;
#pragma unroll
        for (int rr = 0; rr < 16; ++rr) sc += yred[0][t + rr * 16];
        atomicAdd(&Scol[(it + 1) * 80 + pl * 16 + t], sc);
    }
}

// ---------------------------------------------------------------------------
// MFMA MLP (layers 1+2, all levels). 256 blocks x 4 waves.
// ---------------------------------------------------------------------------
__global__ __launch_bounds__(256) void mlp_mfma_kernel(const __half* __restrict__ Xs16f,
                                                       const __half* __restrict__ W1f,
                                                       const __half* __restrict__ W2f,
                                                       const float* __restrict__ b1,
                                                       const float* __restrict__ b2,
                                                       float* __restrict__ H2)
{
    __shared__ char h1s[4][16 * 384];
    __shared__ float b1s[160];
    __shared__ float b2s[80];
    const int t = threadIdx.x;
    const int lane = t & 63, wave = t >> 6;
    const int fr = lane & 15, g = lane >> 4;
    const int lvl = blockIdx.x >> 6;
    const int rb = (blockIdx.x & 63) * 4 + wave;

    if (t < 160) b1s[t] = (t < 150) ? b1[t] : 0.f;
    else if (t < 240) b2s[t - 160] = (t < 235) ? b2[t - 160] : 0.f;
    __syncthreads();

    const __half* Abase = Xs16f + (size_t)lvl * 1310720 + (size_t)rb * 5120;
    f32x4 acc1[10];
#pragma unroll
    for (int j = 0; j < 10; ++j) acc1[j] = (f32x4){0.f, 0.f, 0.f, 0.f};
#pragma unroll
    for (int s = 0; s < 10; ++s) {
        f16x8 a = *(const f16x8*)(Abase + s * 512 + lane * 8);
#pragma unroll
        for (int j = 0; j < 10; ++j) {
            f16x8 b = *(const f16x8*)(W1f + (s * 10 + j) * 512 + lane * 8);
            acc1[j] = __builtin_amdgcn_mfma_f32_16x16x32_f16(a, b, acc1[j], 0, 0, 0);
        }
    }
    char* hw = h1s[wave];
#pragma unroll
    for (int j = 0; j < 10; ++j) {
#pragma unroll
        for (int q = 0; q < 4; ++q) {
            const int row = g * 4 + q;
            const int col = j * 16 + fr;
            float v = fmaxf(acc1[j][q] + b1s[col], 0.f);
            *(__half*)(hw + row * 384 + ((col * 2) ^ ((row & 7) << 4))) = __float2half(v);
        }
    }
    __syncthreads();

    f32x4 acc2[5];
#pragma unroll
    for (int j = 0; j < 5; ++j) acc2[j] = (f32x4){0.f, 0.f, 0.f, 0.f};
#pragma unroll
    for (int s = 0; s < 5; ++s) {
        f16x8 a = *(const f16x8*)(hw + fr * 384 + ((s * 64 + g * 16) ^ ((fr & 7) << 4)));
#pragma unroll
        for (int j = 0; j < 5; ++j) {
            f16x8 b = *(const f16x8*)(W2f + (s * 5 + j) * 512 + lane * 8);
            acc2[j] = __builtin_amdgcn_mfma_f32_16x16x32_f16(a, b, acc2[j], 0, 0, 0);
        }
    }
#pragma unroll
    for (int j = 0; j < 5; ++j) {
        const int col = j * 16 + fr;
        if (col < 75) {
#pragma unroll
            for (int q = 0; q < 4; ++q) {
                const int row = rb * 16 + g * 4 + q;
                float v = fmaxf(acc2[j][q] + b2s[col], 0.f);
                H2[(size_t)row * 300 + lvl * 75 + col] = v;
            }
        }
    }
}

// ---------------------------------------------------------------------------
// Final: y_pred = H2 @ w3 + b3; y_true = ytacc/30; labelled_mask
// ---------------------------------------------------------------------------
__global__ __launch_bounds__(256) void final_kernel(const float* __restrict__ H2,
                                                    const float* __restrict__ w3,
                                                    const float* __restrict__ b3,
                                                    const float* __restrict__ ytacc,
                                                    float* __restrict__ out)
{
    __shared__ float w[300];
    const int t = threadIdx.x;
    const int b = blockIdx.x * 256 + t;
    for (int i = t; i < 300; i += 256) w[i] = w3[i];
    __syncthreads();
    float acc = b3[0];
    const float4* row = (const float4*)(H2 + (size_t)b * 300);
    for (int k4 = 0; k4 < 75; ++k4) {
        float4 v = row[k4];
        acc += v.x * w[k4 * 4] + v.y * w[k4 * 4 + 1] + v.z * w[k4 * 4 + 2] + v.w * w[k4 * 4 + 3];
    }
    out[b] = acc;
    out[4096 + b] = ytacc[b] * (1.0f / 30.0f);
    out[2 * 4096 + b] = (b < 2048) ? 1.0f : 0.0f;
}

// ---------------------------------------------------------------------------
extern "C" void kernel_launch(void* const* d_in, const int* in_sizes, int n_in,
                              void* d_out, int out_size, void* d_ws, size_t ws_size,
                              hipStream_t stream)
{
    (void)in_sizes; (void)n_in; (void)out_size;

    const float* feats[4] = {(const float*)d_in[0], (const float*)d_in[1],
                             (const float*)d_in[2], (const float*)d_in[3]};
    const float* embedds = (const float*)d_in[4];
    const int* labels = (const int*)d_in[6];
    const float* lsw[4] = {(const float*)d_in[7], (const float*)d_in[9],
                           (const float*)d_in[11], (const float*)d_in[13]};
    const float* lsb[4] = {(const float*)d_in[8], (const float*)d_in[10],
                           (const float*)d_in[12], (const float*)d_in[14]};
    const float* w1 = (const float*)d_in[15];
    const float* b1 = (const float*)d_in[16];
    const float* w2 = (const float*)d_in[17];
    const float* b2 = (const float*)d_in[18];
    const float* w3 = (const float*)d_in[19];
    const float* b3 = (const float*)d_in[20];

    // fused: 5 A4 slices (40MB) + 5 A16f slices (160MB); else 1+1
    const bool fused = ws_size >= 236000000ULL;
    const size_t A4_BYTES  = fused ? 41943040ULL : 8388608ULL;
    const size_t A16_BYTES = fused ? 167772160ULL : 33554432ULL;

    char* ws = (char*)d_ws;
    uchar* A4       = (uchar*)(ws);
    __half* A16f    = (__half*)(ws + A4_BYTES);
    char* base      = ws + A4_BYTES + A16_BYTES;
    __half* N16all  = (__half*)(base);                //  8388608
    uchar* Xt8      = (uchar*)(base + 8388608);       //  2 x 327680
    float* X32      = (float*)(base + 9043968);       //  2 x 819200
    __half* Xs16f   = (__half*)(base + 10682368);     //  10485760
    float* H2       = (float*)(base + 21168128);      //  4915200
    float* ytacc    = (float*)(base + 26083328);      //  16384
    float* partials = (float*)(base + 26099712);      //  20480
    float* scal     = (float*)(base + 26120192);      //  256
    float* Scol     = (float*)(base + 26120448);      //  16384
    __half* W1f     = (__half*)(base + 26136832);     //  102400
    __half* W2f     = (__half*)(base + 26239232);     //  25600

    uchar* Xt8b[2] = {Xt8, Xt8 + 327680};
    float* X32b[2] = {X32, X32 + 204800};
    float* out = (float*)d_out;

    auto run_iters = [&](const uchar* Ab4, int pbase, int nprob) {
        init_kernel<<<1280, 256, 0, stream>>>(labels, Xt8b[0], Xt8b[1], X32b[0], Scol);
        for (int it = 0; it < 30; ++it) {
            const int i = it & 1, o = i ^ 1;
            gtg8_kernel<<<nprob * 256, 256, 0, stream>>>(
                Ab4, Xt8b[i], Xt8b[o], X32b[i], X32b[o], Xs16f, ytacc, Scol, it, pbase);
        }
    };

    wfrag_kernel<<<250, 256, 0, stream>>>(w1, w2, W1f, W2f);
    hipMemsetAsync(Xs16f, 0, 10485760, stream);

    if (fused) {
        fused_ls_kernel<<<5 * 4096, 256, 0, stream>>>(
            feats[0], feats[1], feats[2], feats[3], embedds,
            lsw[0], lsb[0], lsw[1], lsb[1], lsw[2], lsb[2], lsw[3], lsb[3],
            N16all, 0);
        a_gemm_all<<<5 * 1024, 256, 0, stream>>>(N16all, A16f, partials, 0);
        mean_all_kernel<<<5, 256, 0, stream>>>(partials, scal);
        abar4_all_kernel<<<5 * 4096, 256, 0, stream>>>(A16f, A4, scal);
        run_iters(A4, 0, 5);
    } else {
        for (int p = 0; p < 5; ++p) {
            fused_ls_kernel<<<4096, 256, 0, stream>>>(
                feats[0], feats[1], feats[2], feats[3], embedds,
                lsw[0], lsb[0], lsw[1], lsb[1], lsw[2], lsb[2], lsw[3], lsb[3],
                N16all, p);
            a_gemm_all<<<1024, 256, 0, stream>>>(N16all, A16f, partials, p);
            mean_all_kernel<<<1, 256, 0, stream>>>(partials, scal);
            abar4_all_kernel<<<4096, 256, 0, stream>>>(A16f, A4, scal);
            run_iters(A4, p, 1);
        }
    }

    mlp_mfma_kernel<<<256, 256, 0, stream>>>(Xs16f, W1f, W2f, b1, b2, H2);
    final_kernel<<<16, 256, 0, stream>>>(H2, w3, b3, ytacc, out);
}

// Round 12
// 769.913 us; speedup vs baseline: 2.3601x; 1.0007x over previous
//
#include <hip/hip_runtime.h>
#include <hip/hip_fp16.h>

typedef _Float16 f16x8 __attribute__((ext_vector_type(8)));
typedef float f32x4 __attribute__((ext_vector_type(4)));
typedef unsigned char uchar;

static __device__ __forceinline__ long long mk64(unsigned lo, unsigned hi)
{
    return (long long)(((unsigned long long)hi << 32) | (unsigned long long)lo);
}

// fragment-layout offset for X8 (B-operand): class c, row j
static __device__ __forceinline__ int xfrag_off(int c, int j)
{
    return (j >> 6) * 1024 + (((j >> 3) & 3) * 16 + c) * 16 + ((j >> 5) & 1) * 8 + (j & 7);
}

// fragment-layout offset (halves) for Xs16f (A-operand): row (0..4095), k (0..319)
static __device__ __forceinline__ int xsfrag_off(int row, int k)
{
    return (row >> 4) * 5120 + (k >> 5) * 512 + (((k >> 3) & 3) * 16 + (row & 15)) * 8 + (k & 7);
}

// nibble codes -> fp8 e4m3 bytes of k/16 (exact): LUT via v_perm
#define T03 0x24201800u
#define T47 0x2E2C2A28u
#define T8B 0x33323130u
#define TCF 0x37363534u

static __device__ __forceinline__ void expand4(unsigned w, unsigned& o0, unsigned& o1)
{
    unsigned even = w & 0x0F0F0F0Fu;
    unsigned odd  = (w >> 4) & 0x0F0F0F0Fu;
    unsigned i_lo = __builtin_amdgcn_perm(odd, even, 0x05010400u);
    unsigned i_hi = __builtin_amdgcn_perm(odd, even, 0x07030602u);
    {
        unsigned i3 = i_lo & 0x07070707u;
        unsigned ta = __builtin_amdgcn_perm(T47, T03, i3);
        unsigned tb = __builtin_amdgcn_perm(TCF, T8B, i3);
        unsigned m  = ((i_lo >> 3) & 0x01010101u) * 0xFFu;
        o0 = ta ^ ((ta ^ tb) & m);
    }
    {
        unsigned i3 = i_hi & 0x07070707u;
        unsigned ta = __builtin_amdgcn_perm(T47, T03, i3);
        unsigned tb = __builtin_amdgcn_perm(TCF, T8B, i3);
        unsigned m  = ((i_hi >> 3) & 0x01010101u) * 0xFFu;
        o1 = ta ^ ((ta ^ tb) & m);
    }
}

// ---------------------------------------------------------------------------
// Fused pool + linear + relu + row-normalize, 16 ROWS PER BLOCK so the
// weight column is loaded once and reused across 8 rows per thread.
// Grid: pcount*256 blocks; p = pbase + blk>>8; rows (blk&255)*16..+16.
// p<4: level path; p==4: embedds normalize.
// ---------------------------------------------------------------------------
__global__ __launch_bounds__(256) void fused_ls_kernel(
    const float* __restrict__ f0, const float* __restrict__ f1,
    const float* __restrict__ f2, const float* __restrict__ f3,
    const float* __restrict__ embedds,
    const float* __restrict__ lw0, const float* __restrict__ lb0,
    const float* __restrict__ lw1, const float* __restrict__ lb1,
    const float* __restrict__ lw2, const float* __restrict__ lb2,
    const float* __restrict__ lw3, const float* __restrict__ lb3,
    __half* __restrict__ N16all, int pbase)
{
    __shared__ float pl[16][512];
    __shared__ float red[16][2];
    const int t = threadIdx.x;
    const int p = pbase + (blockIdx.x >> 8);
    const int row0 = (blockIdx.x & 255) * 16;

    if (p == 4) {
        // 16 threads per row, 32 floats each
        const int r = t >> 4, q = t & 15;
        const int row = row0 + r;
        const float4* src = (const float4*)(embedds + (size_t)row * 512 + q * 32);
        float4 v[8];
        float ss = 0.f;
#pragma unroll
        for (int i = 0; i < 8; ++i) {
            v[i] = src[i];
            ss += v[i].x * v[i].x + v[i].y * v[i].y + v[i].z * v[i].z + v[i].w * v[i].w;
        }
        ss += __shfl_xor(ss, 1, 16);
        ss += __shfl_xor(ss, 2, 16);
        ss += __shfl_xor(ss, 4, 16);
        ss += __shfl_xor(ss, 8, 16);
        const float inv = 1.0f / fmaxf(sqrtf(ss), 1e-12f);
        __half out[32];
#pragma unroll
        for (int i = 0; i < 8; ++i) {
            out[i * 4 + 0] = __float2half(v[i].x * inv);
            out[i * 4 + 1] = __float2half(v[i].y * inv);
            out[i * 4 + 2] = __float2half(v[i].z * inv);
            out[i * 4 + 3] = __float2half(v[i].w * inv);
        }
        __half* dst = N16all + 2097152 + (size_t)row * 512 + q * 32;
#pragma unroll
        for (int i = 0; i < 4; ++i)
            *(uint4*)(dst + i * 8) = *(uint4*)(out + i * 8);
        return;
    }

    const float* feat; const float* w; const float* b; int C, lc, S2;
    switch (p) {
        case 0:  feat = f0; w = lw0; b = lb0; C = 64;  lc = 6; S2 = 64; break;
        case 1:  feat = f1; w = lw1; b = lb1; C = 128; lc = 7; S2 = 64; break;
        case 2:  feat = f2; w = lw2; b = lb2; C = 256; lc = 8; S2 = 16; break;
        default: feat = f3; w = lw3; b = lb3; C = 512; lc = 9; S2 = 16; break;
    }

    // ---- pool: one channel-instance per thread iteration (contiguous S2 run)
    const float inv_s2 = 1.0f / (float)S2;
    for (int ci = t; ci < (C << 4); ci += 256) {
        const int r = ci >> lc, ch = ci & (C - 1);
        const float4* src = (const float4*)(feat + ((size_t)(row0 + r) * C + ch) * S2);
        float s = 0.f;
        if (S2 == 64) {
#pragma unroll
            for (int i = 0; i < 16; ++i) { float4 v = src[i]; s += v.x + v.y + v.z + v.w; }
        } else {
#pragma unroll
            for (int i = 0; i < 4; ++i) { float4 v = src[i]; s += v.x + v.y + v.z + v.w; }
        }
        pl[r][ch] = s * inv_s2;
    }
    __syncthreads();

    // ---- linear: col = t&127, rows half*8..+8; w loaded once per (k,col)
    const int col = t & 127, half = t >> 7;
    const int wavepart = (t >> 6) & 1;
    float acc[8];
#pragma unroll
    for (int r = 0; r < 8; ++r) acc[r] = b[col];
#pragma unroll 4
    for (int k = 0; k < C; ++k) {
        const float wv = w[(size_t)k * 128 + col];
#pragma unroll
        for (int r = 0; r < 8; ++r) acc[r] = fmaf(pl[half * 8 + r][k], wv, acc[r]);
    }
    float ssq[8];
#pragma unroll
    for (int r = 0; r < 8; ++r) {
        acc[r] = fmaxf(acc[r], 0.f);
        float q = acc[r] * acc[r];
        q += __shfl_xor(q, 1, 64);
        q += __shfl_xor(q, 2, 64);
        q += __shfl_xor(q, 4, 64);
        q += __shfl_xor(q, 8, 64);
        q += __shfl_xor(q, 16, 64);
        q += __shfl_xor(q, 32, 64);
        ssq[r] = q;
    }
    if ((t & 63) == 0) {
#pragma unroll
        for (int r = 0; r < 8; ++r) red[half * 8 + r][wavepart] = ssq[r];
    }
    __syncthreads();
#pragma unroll
    for (int r = 0; r < 8; ++r) {
        const int row = half * 8 + r;
        const float inv = 1.0f / fmaxf(sqrtf(red[row][0] + red[row][1]), 1e-12f);
        N16all[(size_t)p * 524288 + (size_t)(row0 + row) * 128 + col] =
            __float2half(acc[r] * inv);
    }
}

// ---------------------------------------------------------------------------
// All-problem MFMA GEMM. Grid pcount*1024; p = pbase + blk>>10, runtime K.
// Writes fp16 C = clamp(nnT,0,1), diag=0, FRAGMENT-MAJOR, per-problem slice
// of A16f (32 MB each) + fp32 partial sums -> partials[lp*1024+blk].
// ---------------------------------------------------------------------------
__global__ __launch_bounds__(256) void a_gemm_all(const __half* __restrict__ N16all,
                                                  __half* __restrict__ A16f,
                                                  float* __restrict__ partials,
                                                  int pbase)
{
    __shared__ __half smem[16384];   // As(8192) | Bs(8192); reused as Cst
    __shared__ float reds[4];
    __half* As = smem;
    __half* Bs = smem + 8192;
    char* Cb = (char*)smem;
    const int t = threadIdx.x;
    const int lane = t & 63, wave = t >> 6;
    const int lp = blockIdx.x >> 10;
    const int p = pbase + lp;
    const int blk = blockIdx.x & 1023;
    const int K = (p == 4) ? 512 : 128;
    const __half* N16 = N16all + ((p == 4) ? 2097152u : (unsigned)p * 524288u);
    const int bx = blk & 31, by = blk >> 5;
    const int wr = wave >> 1, wc = wave & 1;
    const int fr = lane & 15;
    const int g = lane >> 4;
    const int r0 = by * 128, c0 = bx * 128;
    const int sr = t >> 3;
    const int sc = t & 7;

    f32x4 acc[4][4];
#pragma unroll
    for (int i = 0; i < 4; ++i)
#pragma unroll
        for (int j = 0; j < 4; ++j) acc[i][j] = (f32x4){0.f, 0.f, 0.f, 0.f};

    for (int kt = 0; kt < (K >> 6); ++kt) {
        const int kb = kt * 64;
        __syncthreads();
#pragma unroll
        for (int pp = 0; pp < 4; ++pp) {
            const int r = pp * 32 + sr;
            uint4 va = *(const uint4*)(N16 + (size_t)(r0 + r) * K + kb + sc * 8);
            uint4 vb = *(const uint4*)(N16 + (size_t)(c0 + r) * K + kb + sc * 8);
            const int d = r * 64 + ((((sc * 16) ^ ((r & 7) << 4))) >> 1);
            *(uint4*)&As[d] = va;
            *(uint4*)&Bs[d] = vb;
        }
        __syncthreads();
#pragma unroll
        for (int ks = 0; ks < 2; ++ks) {
            const int ko = ((ks * 64 + g * 16) ^ ((fr & 7) << 4)) >> 1;
            f16x8 af[4], bf[4];
#pragma unroll
            for (int i = 0; i < 4; ++i) {
                af[i] = *(const f16x8*)&As[(wr * 64 + i * 16 + fr) * 64 + ko];
                bf[i] = *(const f16x8*)&Bs[(wc * 64 + i * 16 + fr) * 64 + ko];
            }
#pragma unroll
            for (int i = 0; i < 4; ++i)
#pragma unroll
                for (int j = 0; j < 4; ++j)
                    acc[i][j] = __builtin_amdgcn_mfma_f32_16x16x32_f16(af[i], bf[j], acc[i][j], 0, 0, 0);
        }
    }
    __syncthreads();

    float lsum = 0.f;
    const int r4 = g * 4;
#pragma unroll
    for (int i = 0; i < 4; ++i) {
#pragma unroll
        for (int q = 0; q < 4; ++q) {
            const int lr = wr * 64 + i * 16 + r4 + q;
            const int row = r0 + lr;
#pragma unroll
            for (int j = 0; j < 4; ++j) {
                const int lc2 = wc * 64 + j * 16 + fr;
                const int col = c0 + lc2;
                float v = fminf(fmaxf(acc[i][j][q], 0.f), 1.f);
                if (row == col) v = 0.f;
                lsum += v;
                *(__half*)(Cb + lr * 256 + ((lc2 * 2) ^ ((lr & 7) << 4))) = __float2half(v);
            }
        }
    }
    __syncthreads();

#pragma unroll
    for (int pp = 0; pp < 4; ++pp) {
        const int rbl2 = pp * 4 + (t >> 6);
        const int rbl = rbl2 >> 1, ks2l = rbl2 & 1;
        const int l = t & 63;
        const int lr = rbl * 16 + (l & 15);
        const int e0 = ks2l * 64 + (l >> 4) * 8;
        uint4 v0 = *(const uint4*)(Cb + lr * 256 + ((e0 * 2) ^ ((lr & 7) << 4)));
        uint4 v1 = *(const uint4*)(Cb + lr * 256 + (((e0 + 32) * 2) ^ ((lr & 7) << 4)));
        const size_t rb = (size_t)(by * 8 + rbl);
        const size_t ks2 = (size_t)(bx * 2 + ks2l);
        char* dst = (char*)A16f + (size_t)lp * 33554432 + rb * 131072 + ks2 * 2048 + l * 32;
        *(uint4*)dst = v0;
        *(uint4*)(dst + 16) = v1;
    }

    for (int off = 32; off > 0; off >>= 1) lsum += __shfl_down(lsum, off, 64);
    if (lane == 0) reds[wave] = lsum;
    __syncthreads();
    if (t == 0) partials[lp * 1024 + blk] = reds[0] + reds[1] + reds[2] + reds[3];
}

// ---------------------------------------------------------------------------
// mean per problem: block lp reduces partials[lp][0..1023] -> scal[lp]
// ---------------------------------------------------------------------------
__global__ __launch_bounds__(256) void mean_all_kernel(const float* __restrict__ partials,
                                                       float* __restrict__ scal)
{
    __shared__ float red[4];
    const int t = threadIdx.x, lp = blockIdx.x;
    float s = 0.f;
    for (int i = t; i < 1024; i += 256) s += partials[lp * 1024 + i];
    for (int off = 32; off > 0; off >>= 1) s += __shfl_down(s, off, 64);
    if ((t & 63) == 0) red[t >> 6] = s;
    __syncthreads();
    if (t == 0) scal[lp] = (red[0] + red[1] + red[2] + red[3]) * (1.0f / 16777216.0f);
}

// ---------------------------------------------------------------------------
// Quantize to 4-bit codes round(16*(a<mean?0:a)), linear frag order.
// Grid pcount*4096; lp = blk>>12.
// ---------------------------------------------------------------------------
__global__ __launch_bounds__(256) void abar4_all_kernel(const __half* __restrict__ A16f,
                                                        uchar* __restrict__ A4,
                                                        const float* __restrict__ scal)
{
    const int lp = blockIdx.x >> 12;
    const float mean = scal[lp];
    const size_t i = (size_t)(blockIdx.x & 4095) * 256 + threadIdx.x;
    const __half* src = A16f + (size_t)lp * 16777216 + i * 16;
    uint4 u0 = *(const uint4*)(src);
    uint4 u1 = *(const uint4*)(src + 8);
    __half h[16];
    *(uint4*)h = u0;
    *(uint4*)(h + 8) = u1;
    unsigned d0 = 0, d1 = 0;
#pragma unroll
    for (int k = 0; k < 8; ++k) {
        float a = __half2float(h[k]);
        float v = (a < mean) ? 0.f : a;
        unsigned n = (unsigned)fminf(v * 16.f + 0.5f, 15.f);
        d0 |= n << (4 * k);
    }
#pragma unroll
    for (int k = 0; k < 8; ++k) {
        float a = __half2float(h[8 + k]);
        float v = (a < mean) ? 0.f : a;
        unsigned n = (unsigned)fminf(v * 16.f + 0.5f, 15.f);
        d1 |= n << (4 * k);
    }
    uint2 o; o.x = d0; o.y = d1;
    *(uint2*)(A4 + (size_t)lp * 8388608 + i * 8) = o;
}

// ---------------------------------------------------------------------------
// X0 init + Scol init (blocks 0..30) + label histogram (block 0)
// ---------------------------------------------------------------------------
__global__ __launch_bounds__(256) void init_kernel(const int* __restrict__ labels,
                                                   uchar* __restrict__ X8_0,
                                                   uchar* __restrict__ X8_1,
                                                   float* __restrict__ X32,
                                                   float* __restrict__ Scol)
{
    __shared__ int hist[16];
    const int blk = blockIdx.x;
    const int t = threadIdx.x;
    const int idx = blk * 256 + t;   // 5*16*4096 = 327680
    const int p = idx >> 16;
    const int rem = idx & 65535;
    const int c = rem >> 12, j = rem & 4095;
    float v;
    if (c >= 10) v = 0.f;
    else if (j < 2048) v = (labels[j] == c) ? 1.0f : 0.0f;
    else v = 0.1f;
    unsigned pk = __builtin_amdgcn_cvt_pk_fp8_f32(v, v, 0, false);
    X8_0[(size_t)p * 65536 + xfrag_off(c, j)] = (uchar)(pk & 0xff);
    if (c >= 10) X8_1[(size_t)p * 65536 + xfrag_off(c, j)] = 0;
    if (c < 10) X32[((size_t)p * 4096 + j) * 10 + c] = v;

    if (blk == 0) {
        if (t < 16) hist[t] = 0;
        __syncthreads();
        for (int i = t; i < 2048; i += 256) atomicAdd(&hist[labels[i]], 1);
        __syncthreads();
        if (t < 80) {
            const int pp = t >> 4, cc = t & 15;
            Scol[pp * 16 + cc] = (cc < 10) ? ((float)hist[cc] + 204.8f) : 0.f;
        }
    } else if (blk <= 30) {
        if (t < 80) Scol[blk * 80 + t] = 0.f;
    }
}

// ---------------------------------------------------------------------------
// Pack w1 (300x150) and w2 (150x75) into fragment-major fp16 B-operand form.
// ---------------------------------------------------------------------------
__global__ __launch_bounds__(256) void wfrag_kernel(const float* __restrict__ w1,
                                                    const float* __restrict__ w2,
                                                    __half* __restrict__ W1f,
                                                    __half* __restrict__ W2f)
{
    int idx = blockIdx.x * 256 + threadIdx.x;   // 51200 + 12800 = 64000
    if (idx < 51200) {
        const int frag = idx >> 9, e9 = idx & 511;
        const int s = frag / 10, j = frag % 10;
        const int g = e9 >> 7, fr = (e9 >> 3) & 15, e = e9 & 7;
        const int k = s * 32 + g * 8 + e, n = j * 16 + fr;
        const float v = (k < 300 && n < 150) ? w1[(size_t)k * 150 + n] : 0.f;
        W1f[idx] = __float2half(v);
    } else if (idx < 64000) {
        const int i2 = idx - 51200;
        const int frag = i2 >> 9, e9 = i2 & 511;
        const int s = frag / 5, j = frag % 5;
        const int g = e9 >> 7, fr = (e9 >> 3) & 15, e = e9 & 7;
        const int k = s * 32 + g * 8 + e, n = j * 16 + fr;
        const float v = (k < 150 && n < 75) ? w2[(size_t)k * 75 + n] : 0.f;
        W2f[i2] = __float2half(v);
    }
}

// ---------------------------------------------------------------------------
// One GTG iteration: 4-bit A expanded in-register to fp8 (LUT), fp8 MFMA.
// 5 blocks/CU residency (min 5 waves/EU).
// ---------------------------------------------------------------------------
__global__ __launch_bounds__(256, 5) void gtg8_kernel(
    const uchar* __restrict__ A4f,
    const uchar* __restrict__ X8i, uchar* __restrict__ X8o,
    const float* __restrict__ X32i, float* __restrict__ X32o,
    __half* __restrict__ Xs16f, float* __restrict__ ytacc,
    float* __restrict__ Scol, int it, int pbase)
{
    __shared__ float yred[4][256];
    const int t = threadIdx.x;
    const int lane = t & 63, wave = t >> 6;
    const int p = pbase + (blockIdx.x >> 8);
    const int pl = p - pbase;
    const int rb = blockIdx.x & 255;

    const uchar* Ab = A4f + (size_t)pl * 8388608 + (size_t)rb * 32768
                    + wave * 8192 + lane * 8;
    const uchar* Xb = X8i + (size_t)p * 65536 + wave * 16384 + lane * 16;

    f32x4 acc0 = {0.f, 0.f, 0.f, 0.f};
    f32x4 acc1 = {0.f, 0.f, 0.f, 0.f};
#pragma unroll
    for (int u = 0; u < 16; ++u) {
        uint2 a4 = *(const uint2*)(Ab + u * 512);
        uint4 bv = *(const uint4*)(Xb + u * 1024);
        unsigned e00, e01, e10, e11;
        expand4(a4.x, e00, e01);
        expand4(a4.y, e10, e11);
        acc0 = __builtin_amdgcn_mfma_f32_16x16x32_fp8_fp8(
            mk64(e00, e01), mk64(bv.x, bv.y), acc0, 0, 0, 0);
        acc1 = __builtin_amdgcn_mfma_f32_16x16x32_fp8_fp8(
            mk64(e10, e11), mk64(bv.z, bv.w), acc1, 0, 0, 0);
    }
    {
        const int r4 = (lane >> 4) * 4;
        const int fr = lane & 15;
#pragma unroll
        for (int q = 0; q < 4; ++q)
            yred[wave][(r4 + q) * 16 + fr] = acc0[q] + acc1[q];
    }
    __syncthreads();

    // ---- update phase: thread t -> row r=t>>4, class c=t&15
    const int r = t >> 4, c = t & 15;
    const int row = rb * 16 + r;
    const float T = yred[0][t] + yred[1][t] + yred[2][t] + yred[3][t];
    const float y = Scol[it * 80 + pl * 16 + c] - T;
    const float x = (c < 10) ? X32i[((size_t)p * 4096 + row) * 10 + c] : 0.f;
    const float m = x * y;
    float s = m;
    s += __shfl_xor(s, 1, 16);
    s += __shfl_xor(s, 2, 16);
    s += __shfl_xor(s, 4, 16);
    s += __shfl_xor(s, 8, 16);
    const float dv = m / (s + 1e-8f);
    const float xn = x + dv;
    if (c < 10) {
        X32o[((size_t)p * 4096 + row) * 10 + c] = xn;
        unsigned pk = __builtin_amdgcn_cvt_pk_fp8_f32(xn, xn, 0, false);
        X8o[(size_t)p * 65536 + xfrag_off(c, row)] = (uchar)(pk & 0xff);
        if (p < 4) {
            const int k = c * 30 + it;
            Xs16f[(size_t)p * 1310720 + xsfrag_off(row, k)] = __float2half(xn);
        }
    }
    if (p == 4) {
        float e = (c < 10) ? (-dv * logf(dv + 1e-8f)) : 0.f;
        e += __shfl_xor(e, 1, 16);
        e += __shfl_xor(e, 2, 16);
        e += __shfl_xor(e, 4, 16);
        e += __shfl_xor(e, 8, 16);
        if (c == 0) {
            float prev = (it == 0) ? 0.f : ytacc[row];
            ytacc[row] = prev + e;
        }
    }

    // ---- colsum for next iteration
    __syncthreads();
    yred[0][t] = (c < 10) ? xn : 0.f;
    __syncthreads();
    if (t < 10) {
        float sc = 0.f;
#pragma unroll
        for (int rr = 0; rr < 16; ++rr) sc += yred[0][t + rr * 16];
        atomicAdd(&Scol[(it + 1) * 80 + pl * 16 + t], sc);
    }
}

// ---------------------------------------------------------------------------
// MFMA MLP (layers 1+2, all levels). 256 blocks x 4 waves.
// ---------------------------------------------------------------------------
__global__ __launch_bounds__(256) void mlp_mfma_kernel(const __half* __restrict__ Xs16f,
                                                       const __half* __restrict__ W1f,
                                                       const __half* __restrict__ W2f,
                                                       const float* __restrict__ b1,
                                                       const float* __restrict__ b2,
                                                       float* __restrict__ H2)
{
    __shared__ char h1s[4][16 * 384];
    __shared__ float b1s[160];
    __shared__ float b2s[80];
    const int t = threadIdx.x;
    const int lane = t & 63, wave = t >> 6;
    const int fr = lane & 15, g = lane >> 4;
    const int lvl = blockIdx.x >> 6;
    const int rb = (blockIdx.x & 63) * 4 + wave;

    if (t < 160) b1s[t] = (t < 150) ? b1[t] : 0.f;
    else if (t < 240) b2s[t - 160] = (t < 235) ? b2[t - 160] : 0.f;
    __syncthreads();

    const __half* Abase = Xs16f + (size_t)lvl * 1310720 + (size_t)rb * 5120;
    f32x4 acc1[10];
#pragma unroll
    for (int j = 0; j < 10; ++j) acc1[j] = (f32x4){0.f, 0.f, 0.f, 0.f};
#pragma unroll
    for (int s = 0; s < 10; ++s) {
        f16x8 a = *(const f16x8*)(Abase + s * 512 + lane * 8);
#pragma unroll
        for (int j = 0; j < 10; ++j) {
            f16x8 b = *(const f16x8*)(W1f + (s * 10 + j) * 512 + lane * 8);
            acc1[j] = __builtin_amdgcn_mfma_f32_16x16x32_f16(a, b, acc1[j], 0, 0, 0);
        }
    }
    char* hw = h1s[wave];
#pragma unroll
    for (int j = 0; j < 10; ++j) {
#pragma unroll
        for (int q = 0; q < 4; ++q) {
            const int row = g * 4 + q;
            const int col = j * 16 + fr;
            float v = fmaxf(acc1[j][q] + b1s[col], 0.f);
            *(__half*)(hw + row * 384 + ((col * 2) ^ ((row & 7) << 4))) = __float2half(v);
        }
    }
    __syncthreads();

    f32x4 acc2[5];
#pragma unroll
    for (int j = 0; j < 5; ++j) acc2[j] = (f32x4){0.f, 0.f, 0.f, 0.f};
#pragma unroll
    for (int s = 0; s < 5; ++s) {
        f16x8 a = *(const f16x8*)(hw + fr * 384 + ((s * 64 + g * 16) ^ ((fr & 7) << 4)));
#pragma unroll
        for (int j = 0; j < 5; ++j) {
            f16x8 b = *(const f16x8*)(W2f + (s * 5 + j) * 512 + lane * 8);
            acc2[j] = __builtin_amdgcn_mfma_f32_16x16x32_f16(a, b, acc2[j], 0, 0, 0);
        }
    }
#pragma unroll
    for (int j = 0; j < 5; ++j) {
        const int col = j * 16 + fr;
        if (col < 75) {
#pragma unroll
            for (int q = 0; q < 4; ++q) {
                const int row = rb * 16 + g * 4 + q;
                float v = fmaxf(acc2[j][q] + b2s[col], 0.f);
                H2[(size_t)row * 300 + lvl * 75 + col] = v;
            }
        }
    }
}

// ---------------------------------------------------------------------------
// Final: y_pred = H2 @ w3 + b3; y_true = ytacc/30; labelled_mask
// ---------------------------------------------------------------------------
__global__ __launch_bounds__(256) void final_kernel(const float* __restrict__ H2,
                                                    const float* __restrict__ w3,
                                                    const float* __restrict__ b3,
                                                    const float* __restrict__ ytacc,
                                                    float* __restrict__ out)
{
    __shared__ float w[300];
    const int t = threadIdx.x;
    const int b = blockIdx.x * 256 + t;
    for (int i = t; i < 300; i += 256) w[i] = w3[i];
    __syncthreads();
    float acc = b3[0];
    const float4* row = (const float4*)(H2 + (size_t)b * 300);
    for (int k4 = 0; k4 < 75; ++k4) {
        float4 v = row[k4];
        acc += v.x * w[k4 * 4] + v.y * w[k4 * 4 + 1] + v.z * w[k4 * 4 + 2] + v.w * w[k4 * 4 + 3];
    }
    out[b] = acc;
    out[4096 + b] = ytacc[b] * (1.0f / 30.0f);
    out[2 * 4096 + b] = (b < 2048) ? 1.0f : 0.0f;
}

// ---------------------------------------------------------------------------
extern "C" void kernel_launch(void* const* d_in, const int* in_sizes, int n_in,
                              void* d_out, int out_size, void* d_ws, size_t ws_size,
                              hipStream_t stream)
{
    (void)in_sizes; (void)n_in; (void)out_size;

    const float* feats[4] = {(const float*)d_in[0], (const float*)d_in[1],
                             (const float*)d_in[2], (const float*)d_in[3]};
    const float* embedds = (const float*)d_in[4];
    const int* labels = (const int*)d_in[6];
    const float* lsw[4] = {(const float*)d_in[7], (const float*)d_in[9],
                           (const float*)d_in[11], (const float*)d_in[13]};
    const float* lsb[4] = {(const float*)d_in[8], (const float*)d_in[10],
                           (const float*)d_in[12], (const float*)d_in[14]};
    const float* w1 = (const float*)d_in[15];
    const float* b1 = (const float*)d_in[16];
    const float* w2 = (const float*)d_in[17];
    const float* b2 = (const float*)d_in[18];
    const float* w3 = (const float*)d_in[19];
    const float* b3 = (const float*)d_in[20];

    // fused: 5 A4 slices (40MB) + 5 A16f slices (160MB); else 1+1
    const bool fused = ws_size >= 236000000ULL;
    const size_t A4_BYTES  = fused ? 41943040ULL : 8388608ULL;
    const size_t A16_BYTES = fused ? 167772160ULL : 33554432ULL;

    char* ws = (char*)d_ws;
    uchar* A4       = (uchar*)(ws);
    __half* A16f    = (__half*)(ws + A4_BYTES);
    char* base      = ws + A4_BYTES + A16_BYTES;
    __half* N16all  = (__half*)(base);                //  8388608
    uchar* Xt8      = (uchar*)(base + 8388608);       //  2 x 327680
    float* X32      = (float*)(base + 9043968);       //  2 x 819200
    __half* Xs16f   = (__half*)(base + 10682368);     //  10485760
    float* H2       = (float*)(base + 21168128);      //  4915200
    float* ytacc    = (float*)(base + 26083328);      //  16384
    float* partials = (float*)(base + 26099712);      //  20480
    float* scal     = (float*)(base + 26120192);      //  256
    float* Scol     = (float*)(base + 26120448);      //  16384
    __half* W1f     = (__half*)(base + 26136832);     //  102400
    __half* W2f     = (__half*)(base + 26239232);     //  25600

    uchar* Xt8b[2] = {Xt8, Xt8 + 327680};
    float* X32b[2] = {X32, X32 + 204800};
    float* out = (float*)d_out;

    auto run_iters = [&](const uchar* Ab4, int pbase, int nprob) {
        init_kernel<<<1280, 256, 0, stream>>>(labels, Xt8b[0], Xt8b[1], X32b[0], Scol);
        for (int it = 0; it < 30; ++it) {
            const int i = it & 1, o = i ^ 1;
            gtg8_kernel<<<nprob * 256, 256, 0, stream>>>(
                Ab4, Xt8b[i], Xt8b[o], X32b[i], X32b[o], Xs16f, ytacc, Scol, it, pbase);
        }
    };

    wfrag_kernel<<<250, 256, 0, stream>>>(w1, w2, W1f, W2f);
    hipMemsetAsync(Xs16f, 0, 10485760, stream);

    if (fused) {
        fused_ls_kernel<<<5 * 256, 256, 0, stream>>>(
            feats[0], feats[1], feats[2], feats[3], embedds,
            lsw[0], lsb[0], lsw[1], lsb[1], lsw[2], lsb[2], lsw[3], lsb[3],
            N16all, 0);
        a_gemm_all<<<5 * 1024, 256, 0, stream>>>(N16all, A16f, partials, 0);
        mean_all_kernel<<<5, 256, 0, stream>>>(partials, scal);
        abar4_all_kernel<<<5 * 4096, 256, 0, stream>>>(A16f, A4, scal);
        run_iters(A4, 0, 5);
    } else {
        for (int p = 0; p < 5; ++p) {
            fused_ls_kernel<<<256, 256, 0, stream>>>(
                feats[0], feats[1], feats[2], feats[3], embedds,
                lsw[0], lsb[0], lsw[1], lsb[1], lsw[2], lsb[2], lsw[3], lsb[3],
                N16all, p);
            a_gemm_all<<<1024, 256, 0, stream>>>(N16all, A16f, partials, p);
            mean_all_kernel<<<1, 256, 0, stream>>>(partials, scal);
            abar4_all_kernel<<<4096, 256, 0, stream>>>(A16f, A4, scal);
            run_iters(A4, p, 1);
        }
    }

    mlp_mfma_kernel<<<256, 256, 0, stream>>>(Xs16f, W1f, W2f, b1, b2, H2);
    final_kernel<<<16, 256, 0, stream>>>(H2, w3, b3, ytacc, out);
}